// Round 5
// baseline (1023.218 us; speedup 1.0000x reference)
//
#include <hip/hip_runtime.h>
#include <math.h>

#define TSEQ 1024
#define NH 16
#define HD 64

// ---------------- fp32 GEMM: C = A[M,K] * B[N,K]^T, 128x128 tile, 8x8/thread
// BK=32, pad+1 LDS. Per-output fma chain is k-ascending -> bitwise identical
// to previous rounds for full-K use. K,N = 1024 hardcoded.
#define PBK 32

__device__ __forceinline__ void gemm128_core(
    const float* __restrict__ A, const float* __restrict__ B,
    float* __restrict__ C, const int bm, const int bn,
    const int kbeg, const int kend)
{
  const int K = 1024, N = 1024;
  __shared__ float As[PBK][128 + 1];
  __shared__ float Bs[PBK][128 + 1];
  const int tid = threadIdx.x;
  const int tm = (tid >> 4) << 3;   // 16 groups x 8 rows
  const int tn = (tid & 15) << 3;   // 16 groups x 8 cols

  float acc[8][8];
#pragma unroll
  for (int i = 0; i < 8; ++i)
#pragma unroll
    for (int j = 0; j < 8; ++j) acc[i][j] = 0.0f;

  const int lr = tid >> 3;          // 0..31
  const int lc = (tid & 7) << 2;    // 0,4,...,28
  const float* Ap = A + (size_t)(bm + lr) * K + lc;
  const float* Bp = B + (size_t)(bn + lr) * K + lc;

  for (int k0 = kbeg; k0 < kend; k0 += PBK) {
    float4 a0 = *(const float4*)(Ap + k0);
    float4 a1 = *(const float4*)(Ap + (size_t)32 * K + k0);
    float4 a2 = *(const float4*)(Ap + (size_t)64 * K + k0);
    float4 a3 = *(const float4*)(Ap + (size_t)96 * K + k0);
    float4 b0 = *(const float4*)(Bp + k0);
    float4 b1 = *(const float4*)(Bp + (size_t)32 * K + k0);
    float4 b2 = *(const float4*)(Bp + (size_t)64 * K + k0);
    float4 b3 = *(const float4*)(Bp + (size_t)96 * K + k0);
    __syncthreads();   // previous iter's LDS reads complete
    As[lc + 0][lr     ] = a0.x; As[lc + 1][lr     ] = a0.y; As[lc + 2][lr     ] = a0.z; As[lc + 3][lr     ] = a0.w;
    As[lc + 0][lr + 32] = a1.x; As[lc + 1][lr + 32] = a1.y; As[lc + 2][lr + 32] = a1.z; As[lc + 3][lr + 32] = a1.w;
    As[lc + 0][lr + 64] = a2.x; As[lc + 1][lr + 64] = a2.y; As[lc + 2][lr + 64] = a2.z; As[lc + 3][lr + 64] = a2.w;
    As[lc + 0][lr + 96] = a3.x; As[lc + 1][lr + 96] = a3.y; As[lc + 2][lr + 96] = a3.z; As[lc + 3][lr + 96] = a3.w;
    Bs[lc + 0][lr     ] = b0.x; Bs[lc + 1][lr     ] = b0.y; Bs[lc + 2][lr     ] = b0.z; Bs[lc + 3][lr     ] = b0.w;
    Bs[lc + 0][lr + 32] = b1.x; Bs[lc + 1][lr + 32] = b1.y; Bs[lc + 2][lr + 32] = b1.z; Bs[lc + 3][lr + 32] = b1.w;
    Bs[lc + 0][lr + 64] = b2.x; Bs[lc + 1][lr + 64] = b2.y; Bs[lc + 2][lr + 64] = b2.z; Bs[lc + 3][lr + 64] = b2.w;
    Bs[lc + 0][lr + 96] = b3.x; Bs[lc + 1][lr + 96] = b3.y; Bs[lc + 2][lr + 96] = b3.z; Bs[lc + 3][lr + 96] = b3.w;
    __syncthreads();
#pragma unroll 16
    for (int kk = 0; kk < PBK; ++kk) {
      float4 av0 = *(const float4*)&As[kk][tm];
      float4 av1 = *(const float4*)&As[kk][tm + 4];
      float4 bv0 = *(const float4*)&Bs[kk][tn];
      float4 bv1 = *(const float4*)&Bs[kk][tn + 4];
      float a[8] = {av0.x, av0.y, av0.z, av0.w, av1.x, av1.y, av1.z, av1.w};
      float bb[8] = {bv0.x, bv0.y, bv0.z, bv0.w, bv1.x, bv1.y, bv1.z, bv1.w};
#pragma unroll
      for (int i = 0; i < 8; ++i)
#pragma unroll
        for (int j = 0; j < 8; ++j) acc[i][j] = fmaf(a[i], bb[j], acc[i][j]);
    }
  }
#pragma unroll
  for (int i = 0; i < 8; ++i) {
    float* Cp = C + (size_t)(bm + tm + i) * N + bn + tn;
    *(float4*)Cp = make_float4(acc[i][0], acc[i][1], acc[i][2], acc[i][3]);
    *(float4*)(Cp + 4) = make_float4(acc[i][4], acc[i][5], acc[i][6], acc[i][7]);
  }
}

// fused Q/K/V: grid (24, 32); 768 blocks = 3 blocks/CU
__global__ __launch_bounds__(256) void gemm128_qkv(
    const float* __restrict__ x,
    const float* __restrict__ wq, const float* __restrict__ wk, const float* __restrict__ wv,
    float* __restrict__ qy, float* __restrict__ ky, float* __restrict__ vy)
{
  const int nb = blockIdx.x;
  const float* B; float* C;
  if (nb < 8)       { B = wq; C = qy; }
  else if (nb < 16) { B = wk; C = ky; }
  else              { B = wv; C = vy; }
  gemm128_core(x, B, C, blockIdx.y * 128, (nb & 7) * 128, 0, 1024);
}

// WO with split-K=2: grid (16, 32); z=0 -> p0 (k<512), z=1 -> p1 (k>=512)
__global__ __launch_bounds__(256) void gemm128_wo(
    const float* __restrict__ oy, const float* __restrict__ wo,
    float* __restrict__ p0, float* __restrict__ p1)
{
  const int z = blockIdx.x >> 3;
  float* C = z ? p1 : p0;
  gemm128_core(oy, wo, C, blockIdx.y * 128, (blockIdx.x & 7) * 128, z * 512, z * 512 + 512);
}

__global__ __launch_bounds__(256) void add_halves(
    const float* __restrict__ p0, const float* __restrict__ p1, float* __restrict__ out)
{
  const int i = blockIdx.x * 256 + threadIdx.x;
  const float4 a = ((const float4*)p0)[i];
  const float4 b = ((const float4*)p1)[i];
  ((float4*)out)[i] = make_float4(a.x + b.x, a.y + b.y, a.z + b.z, a.w + b.w);
}

// ---------------- top-4 |v| sparsify, fused over q/k/v, one wave per vector
__global__ __launch_bounds__(256) void sparsify_top4_3(
    float* __restrict__ qa, float* __restrict__ ka, float* __restrict__ va)
{
  int w = blockIdx.x * 4 + (threadIdx.x >> 6);   // 0..196607
  const int lane = threadIdx.x & 63;
  float* base = (w < 65536) ? qa : (w < 131072) ? ka : va;
  w &= 65535;
  float* p = base + (size_t)w * 64;
  const float v = p[lane];
  float ak = fabsf(v);
  bool sel = false;
#pragma unroll
  for (int it = 0; it < 4; ++it) {
    float bv = ak; int bl = lane;
#pragma unroll
    for (int off = 32; off > 0; off >>= 1) {
      float ov = __shfl_xor(bv, off);
      int   ol = __shfl_xor(bl, off);
      if (ov > bv || (ov == bv && ol < bl)) { bv = ov; bl = ol; }
    }
    if (lane == bl) { sel = true; ak = -1.0f; }
  }
  p[lane] = sel ? v : 0.0f;
}

// ---------------- K relayout: [b,t,h,j] -> KT [bh, j, t] --------------------
__global__ __launch_bounds__(256) void transpose_k(
    const float* __restrict__ Ky, float* __restrict__ KT)
{
  __shared__ float tile[64][65];
  const int bh = blockIdx.y;
  const int b = bh >> 4, h = bh & 15;
  const int t0 = blockIdx.x * 64;
  const int tid = threadIdx.x;
  {
    const int j = tid & 63, r = tid >> 6;
#pragma unroll
    for (int i = 0; i < 16; ++i) {
      const int tl = r * 16 + i;
      tile[tl][j] = Ky[(size_t)(b * TSEQ + t0 + tl) * 1024 + h * HD + j];
    }
  }
  __syncthreads();
  {
    const int tl = tid & 63, jr = tid >> 6;
#pragma unroll
    for (int i = 0; i < 16; ++i) {
      const int jl = jr * 16 + i;
      KT[((size_t)(bh * HD + jl)) * TSEQ + t0 + tl] = tile[tl][jl];
    }
  }
}

// ---------------- attention ---------------------------------------------------
__device__ __forceinline__ unsigned mono_key(float f) {
  unsigned b = __float_as_uint(f);
  return (b & 0x80000000u) ? ~b : (b | 0x80000000u);
}

// Exact rank-select over index-ordered allk[0..nall) (keys: hi32 = mono score,
// lo32 = k). Select hi32 > t_u plus the first need_eq (array order) == t_u;
// write (k, exp(s-m)) into sel_k/sel_p at obase... No local arrays (scratch!).
__device__ __forceinline__ void radix_sel_write(
    unsigned long long* allk, int nall, int target,
    int* hist, unsigned* p_pref, int* p_rem, int* wtot, int* wtot2,
    int* p_eqbase, int* p_wbase,
    int* sel_k, float* sel_p, int obase, bool neg, float m,
    int tid, int lane, int wid)
{
  if (tid == 0) { *p_rem = target; *p_pref = 0u; }
  __syncthreads();
  for (int pass = 0; pass < 4; ++pass) {
    const int shift = 24 - 8 * pass;
    hist[tid] = 0;
    __syncthreads();
    const unsigned pref = *p_pref;
    for (int t0 = 0; t0 < nall; t0 += 256) {
      const int t = t0 + tid;
      bool part = (t < nall);
      const unsigned u = part ? (unsigned)(allk[t] >> 32) : 0u;
      if (pass > 0) part = part && ((u >> (shift + 8)) == (pref >> (shift + 8)));
      const unsigned digit = (u >> shift) & 255u;
      if (part) {
        unsigned long long mm = __ballot(true);
#pragma unroll
        for (int bit = 0; bit < 8; ++bit) {
          unsigned long long bb = __ballot((int)((digit >> bit) & 1u));
          mm &= ((digit >> bit) & 1u) ? bb : ~bb;
        }
        if (lane == __ffsll((unsigned long long)mm) - 1)
          atomicAdd(&hist[digit], (int)__popcll(mm));
      }
    }
    __syncthreads();
    if (wid == 0) {
      const int d0 = lane << 2;
      const int c0 = hist[d0], c1 = hist[d0 + 1], c2 = hist[d0 + 2], c3 = hist[d0 + 3];
      const int sum = c0 + c1 + c2 + c3;
      int S = sum;
#pragma unroll
      for (int off = 1; off < 64; off <<= 1) {
        int t = __shfl_down(S, off);
        if (lane + off < 64) S += t;
      }
      const int above = S - sum;
      const int cg3 = above;
      const int cg2 = above + c3;
      const int cg1 = above + c3 + c2;
      const int cg0 = above + c3 + c2 + c1;
      const int rem = *p_rem;
      if (cg0 < rem && rem <= cg0 + c0) { *p_pref = pref | ((unsigned)(d0 + 0) << shift); *p_rem = rem - cg0; }
      if (cg1 < rem && rem <= cg1 + c1) { *p_pref = pref | ((unsigned)(d0 + 1) << shift); *p_rem = rem - cg1; }
      if (cg2 < rem && rem <= cg2 + c2) { *p_pref = pref | ((unsigned)(d0 + 2) << shift); *p_rem = rem - cg2; }
      if (cg3 < rem && rem <= cg3 + c3) { *p_pref = pref | ((unsigned)(d0 + 3) << shift); *p_rem = rem - cg3; }
    }
    __syncthreads();
  }
  const unsigned t_u = *p_pref;
  const int need_eq = *p_rem;
  if (tid == 0) { *p_eqbase = 0; *p_wbase = 0; }
  __syncthreads();
  for (int t0 = 0; t0 < nall; t0 += 256) {
    const int t = t0 + tid;
    const bool val = (t < nall);
    const unsigned long long kk = val ? allk[t] : 0ull;
    const unsigned u = (unsigned)(kk >> 32);
    const int eq = (val && u == t_u) ? 1 : 0;
    int ceq = eq;
#pragma unroll
    for (int off = 1; off < 64; off <<= 1) { int x = __shfl_up(ceq, off); if (lane >= off) ceq += x; }
    if (lane == 63) wtot[wid] = ceq;
    __syncthreads();
    int wo = 0;
    for (int w = 0; w < wid; ++w) wo += wtot[w];
    const int eqrank = *p_eqbase + wo + ceq - eq;
    const int sf = (val && ((u > t_u) || (eq && eqrank < need_eq))) ? 1 : 0;
    int csf = sf;
#pragma unroll
    for (int off = 1; off < 64; off <<= 1) { int x = __shfl_up(csf, off); if (lane >= off) csf += x; }
    if (lane == 63) wtot2[wid] = csf;
    __syncthreads();
    int wo2 = 0;
    for (int w = 0; w < wid; ++w) wo2 += wtot2[w];
    if (sf) {
      const int pos = *p_wbase + wo2 + csf - sf;
      const int k = (int)(kk & 0xffffffffull);
      const float sv = neg ? __uint_as_float(~u) : __uint_as_float(u & 0x7fffffffu);
      sel_k[obase + pos] = k;
      sel_p[obase + pos] = __expf(sv - m);
    }
    __syncthreads();
    if (tid == 0) {
      *p_eqbase += wtot[0] + wtot[1] + wtot[2] + wtot[3];
      *p_wbase  += wtot2[0] + wtot2[1] + wtot2[2] + wtot2[3];
    }
    __syncthreads();
  }
}

__global__ __launch_bounds__(256) void attn_sparse(
    const float* __restrict__ Qy, const float* __restrict__ KT,
    const float* __restrict__ Vy, float* __restrict__ Oy)
{
  const int q  = blockIdx.x;
  const int bh = blockIdx.y;
  const int b  = bh >> 4;
  const int h  = bh & 15;
  const int tid  = threadIdx.x;
  const int lane = tid & 63;
  const int wid  = tid >> 6;

  __shared__ unsigned long long pseg[4][256];  // per-wave compacted keys
  __shared__ unsigned long long allk[1024];    // merged, global index order
  __shared__ int   zseg[4][64];
  __shared__ int   c_pos[4], c_zst[4], c_zt[4], c_neg[4];
  __shared__ float redf[4];
  __shared__ int   hist[256];
  __shared__ float nzv[4];
  __shared__ int   nzi[4];
  __shared__ int   s_nsel;
  __shared__ unsigned s_pref;
  __shared__ int   s_rem;
  __shared__ int   wtot[4], wtot2[4];
  __shared__ int   s_eqbase, s_wbase;
  __shared__ int   sel_k[64];
  __shared__ float sel_p[64];
  __shared__ float oacc[4][64];
  __shared__ float s_z;

  // extract <=4 nonzeros of q, padded to 4 with zeros (pads contribute +-0)
  if (wid == 0) {
    if (lane < 4) { nzv[lane] = 0.0f; nzi[lane] = 0; }
    float v = Qy[((size_t)(b * TSEQ + q)) * 1024 + h * HD + lane];
    unsigned long long mk = __ballot(v != 0.0f);
    if (v != 0.0f) {
      int rk = (int)__popcll(mk & ((1ull << lane) - 1ull));
      if (rk < 4) { nzi[rk] = lane; nzv[rk] = v; }
    }
  }
  __syncthreads();
  const int nvalid = q + 1;
  const float* ktb = KT + (size_t)bh * HD * TSEQ;

  if (nvalid <= 64) {
    if (wid == 0) {
      float s = -INFINITY;
      if (lane < nvalid) {
        s = 0.0f;
#pragma unroll
        for (int j = 0; j < 4; ++j) s += nzv[j] * ktb[(size_t)nzi[j] * TSEQ + lane];
        s *= 0.125f;
      }
      float m = s;
#pragma unroll
      for (int off = 32; off; off >>= 1) m = fmaxf(m, __shfl_xor(m, off));
      if (lane < nvalid) { sel_k[lane] = lane; sel_p[lane] = __expf(s - m); }
      if (lane == 0) s_nsel = nvalid;
    }
  } else {
    const int cs = (nvalid + 3) >> 2;          // contiguous range per wave
    const int lo = wid * cs;
    const int hi = min(lo + cs, nvalid);
    const unsigned long long lml = (1ull << lane) - 1ull;

    int cp = 0, czs = 0, czt = 0;
    float mloc = -INFINITY;
    for (int k0 = lo; k0 < hi; k0 += 64) {
      const int k = k0 + lane;
      const bool val = (k < hi);
      float s = 0.0f;
      if (val) {
#pragma unroll
        for (int j = 0; j < 4; ++j) s += nzv[j] * ktb[(size_t)nzi[j] * TSEQ + k];
        s *= 0.125f;
        mloc = fmaxf(mloc, s);
      }
      unsigned u = mono_key(s);
      if (u == 0x7fffffffu) u = 0x80000000u;   // -0 -> +0 (ties with +0, idx order)
      const bool isp = val && (u > 0x80000000u);
      const bool isz = val && (u == 0x80000000u);
      unsigned long long mp = __ballot(isp);
      unsigned long long mz = __ballot(isz);
      if (isp)
        pseg[wid][cp + (int)__popcll(mp & lml)] = ((unsigned long long)u << 32) | (unsigned)k;
      if (isz) {
        const int o = czs + (int)__popcll(mz & lml);
        if (o < 64) zseg[wid][o] = k;
      }
      cp += (int)__popcll(mp);
      const int zc = (int)__popcll(mz);
      czt += zc;
      czs = min(czs + zc, 64);
    }
#pragma unroll
    for (int off = 32; off; off >>= 1) mloc = fmaxf(mloc, __shfl_xor(mloc, off));
    if (lane == 0) { c_pos[wid] = cp; c_zst[wid] = czs; c_zt[wid] = czt; redf[wid] = mloc; }
    __syncthreads();

    const int npos = c_pos[0] + c_pos[1] + c_pos[2] + c_pos[3];
    const int zt   = c_zt[0] + c_zt[1] + c_zt[2] + c_zt[3];
    const float m  = fmaxf(fmaxf(redf[0], redf[1]), fmaxf(redf[2], redf[3]));

    if (npos > 64) {
      // merge positives into allk (global index order), radix-select top-64
      int poff = 0;
      for (int w2 = 0; w2 < wid; ++w2) poff += c_pos[w2];
      for (int j = lane; j < c_pos[wid]; j += 64) allk[poff + j] = pseg[wid][j];
      if (tid == 0) s_nsel = 64;
      __syncthreads();
      radix_sel_write(allk, npos, 64, hist, &s_pref, &s_rem, wtot, wtot2,
                      &s_eqbase, &s_wbase, sel_k, sel_p, 0, false, m,
                      tid, lane, wid);
    } else {
      // all positives selected
      int poff = 0;
      for (int w2 = 0; w2 < wid; ++w2) poff += c_pos[w2];
      if (lane < c_pos[wid]) {
        const unsigned long long kk = pseg[wid][lane];
        sel_k[poff + lane] = (int)(kk & 0xffffffffull);
        sel_p[poff + lane] = __expf(__uint_as_float((unsigned)(kk >> 32) & 0x7fffffffu) - m);
      }
      const float ezm = __expf(-m);
      if (npos + zt >= 64) {
        // zeros fill the quota in global index order
        const int quota = 64 - npos;
        int zoff = 0;
        for (int w2 = 0; w2 < wid; ++w2) zoff += c_zst[w2];
        if (lane < c_zst[wid]) {
          const int r = zoff + lane;
          if (r < quota) { sel_k[npos + r] = zseg[wid][lane]; sel_p[npos + r] = ezm; }
        }
        if (tid == 0) s_nsel = 64;
      } else {
        // rare: boundary dips into negatives; all zeros stored (zt < 64)
        int zoff = 0;
        for (int w2 = 0; w2 < wid; ++w2) zoff += c_zt[w2];
        if (lane < c_zt[wid]) {
          sel_k[npos + zoff + lane] = zseg[wid][lane];
          sel_p[npos + zoff + lane] = ezm;
        }
        const int need = 64 - npos - zt;
        if (tid == 0) s_nsel = 64;
        __syncthreads();                 // positives consumed; reuse pseg
        int cn = 0;
        for (int k0 = lo; k0 < hi; k0 += 64) {
          const int k = k0 + lane;
          const bool val = (k < hi);
          float s = 0.0f;
          if (val) {
#pragma unroll
            for (int j = 0; j < 4; ++j) s += nzv[j] * ktb[(size_t)nzi[j] * TSEQ + k];
            s *= 0.125f;
          }
          unsigned u = mono_key(s);
          if (u == 0x7fffffffu) u = 0x80000000u;
          const bool isn = val && (u < 0x80000000u);
          unsigned long long mn = __ballot(isn);
          if (isn)
            pseg[wid][cn + (int)__popcll(mn & lml)] = ((unsigned long long)u << 32) | (unsigned)k;
          cn += (int)__popcll(mn);
        }
        if (lane == 0) c_neg[wid] = cn;
        __syncthreads();
        const int nneg = c_neg[0] + c_neg[1] + c_neg[2] + c_neg[3];
        int noff = 0;
        for (int w2 = 0; w2 < wid; ++w2) noff += c_neg[w2];
        for (int j = lane; j < c_neg[wid]; j += 64) allk[noff + j] = pseg[wid][j];
        __syncthreads();
        radix_sel_write(allk, nneg, need, hist, &s_pref, &s_rem, wtot, wtot2,
                        &s_eqbase, &s_wbase, sel_k, sel_p, npos + zt, true, m,
                        tid, lane, wid);
      }
    }
  }
  __syncthreads();
  const int nsel = s_nsel;
  if (wid == 0) {
    float p = (lane < nsel) ? sel_p[lane] : 0.0f;
#pragma unroll
    for (int off = 32; off; off >>= 1) p += __shfl_xor(p, off);
    if (lane == 0) s_z = p;
  }
  // epilogue: out[d] = sum_sel p * V[k][d] / Z ; 4 waves strided over entries
  float acc = 0.0f;
  const float* vb = Vy + ((size_t)b * TSEQ) * 1024 + h * HD + lane;
  for (int s2 = wid; s2 < nsel; s2 += 4)
    acc += sel_p[s2] * vb[(size_t)sel_k[s2] * 1024];
  oacc[wid][lane] = acc;
  __syncthreads();
  if (wid == 0) {
    const float r = (oacc[0][lane] + oacc[1][lane]) + (oacc[2][lane] + oacc[3][lane]);
    Oy[((size_t)(b * TSEQ + q)) * 1024 + h * HD + lane] = r / s_z;
  }
}

// ---------------- launch -----------------------------------------------------
extern "C" void kernel_launch(void* const* d_in, const int* in_sizes, int n_in,
                              void* d_out, int out_size, void* d_ws, size_t ws_size,
                              hipStream_t stream) {
  (void)in_sizes; (void)n_in; (void)out_size; (void)ws_size;
  const float* x  = (const float*)d_in[0];
  const float* wq = (const float*)d_in[1];
  const float* wk = (const float*)d_in[2];
  const float* wv = (const float*)d_in[3];
  const float* wo = (const float*)d_in[4];
  float* out = (float*)d_out;

  float* ws = (float*)d_ws;
  const size_t SZ = (size_t)4096 * 1024;   // 4M floats per buffer
  float* qy = ws;
  float* kyb = ws + SZ;
  float* vy = ws + 2 * SZ;
  float* kt = ws + 3 * SZ;
  float* oy = kyb;                         // kyb dead after transpose
  float* p0 = qy;                          // qy dead after attn
  float* p1 = kt;                          // kt dead after attn

  gemm128_qkv<<<dim3(24, 32), 256, 0, stream>>>(x, wq, wk, wv, qy, kyb, vy);

  sparsify_top4_3<<<196608 / 4, 256, 0, stream>>>(qy, kyb, vy);

  transpose_k<<<dim3(TSEQ / 64, 64), 256, 0, stream>>>(kyb, kt);

  attn_sparse<<<dim3(TSEQ, 64), 256, 0, stream>>>(qy, kt, vy, oy);

  gemm128_wo<<<dim3(16, 32), 256, 0, stream>>>(oy, wo, p0, p1);
  add_halves<<<4096, 256, 0, stream>>>(p0, p1, out);
}

// Round 6
// 931.400 us; speedup vs baseline: 1.0986x; 1.0986x over previous
//
#include <hip/hip_runtime.h>
#include <math.h>

#define TSEQ 1024
#define NH 16
#define HD 64

// ---------------- fp32 GEMM: C = A[M,K] * B[N,K]^T, 128x128 tile, 8x8/thread
// BK=32, pad+1 LDS. Wave-tiled thread map: 2x2 waves of 8x8 lanes (64x64 per
// wave) so per-wave LDS read rows/cols span {0,8,...,56} -> 2-way bank
// aliasing (free) instead of 4-way. Per-output fma chain is k-ascending ->
// bitwise identical across mappings. K,N = 1024 hardcoded.
#define PBK 32

__device__ __forceinline__ void gemm128_core(
    const float* __restrict__ A, const float* __restrict__ B,
    float* __restrict__ C, const int bm, const int bn,
    const int kbeg, const int kend)
{
  const int K = 1024, N = 1024;
  __shared__ float As[PBK][128 + 1];
  __shared__ float Bs[PBK][128 + 1];
  const int tid = threadIdx.x;
  const int wv   = tid >> 6;
  const int lane = tid & 63;
  const int tm = ((wv >> 1) << 6) + ((lane >> 3) << 3);  // 0..120
  const int tn = ((wv & 1) << 6) + ((lane & 7) << 3);    // 0..120

  float acc[8][8];
#pragma unroll
  for (int i = 0; i < 8; ++i)
#pragma unroll
    for (int j = 0; j < 8; ++j) acc[i][j] = 0.0f;

  const int lr = tid >> 3;          // 0..31
  const int lc = (tid & 7) << 2;    // 0,4,...,28
  const float* Ap = A + (size_t)(bm + lr) * K + lc;
  const float* Bp = B + (size_t)(bn + lr) * K + lc;

  for (int k0 = kbeg; k0 < kend; k0 += PBK) {
    float4 a0 = *(const float4*)(Ap + k0);
    float4 a1 = *(const float4*)(Ap + (size_t)32 * K + k0);
    float4 a2 = *(const float4*)(Ap + (size_t)64 * K + k0);
    float4 a3 = *(const float4*)(Ap + (size_t)96 * K + k0);
    float4 b0 = *(const float4*)(Bp + k0);
    float4 b1 = *(const float4*)(Bp + (size_t)32 * K + k0);
    float4 b2 = *(const float4*)(Bp + (size_t)64 * K + k0);
    float4 b3 = *(const float4*)(Bp + (size_t)96 * K + k0);
    __syncthreads();   // previous iter's LDS reads complete
    As[lc + 0][lr     ] = a0.x; As[lc + 1][lr     ] = a0.y; As[lc + 2][lr     ] = a0.z; As[lc + 3][lr     ] = a0.w;
    As[lc + 0][lr + 32] = a1.x; As[lc + 1][lr + 32] = a1.y; As[lc + 2][lr + 32] = a1.z; As[lc + 3][lr + 32] = a1.w;
    As[lc + 0][lr + 64] = a2.x; As[lc + 1][lr + 64] = a2.y; As[lc + 2][lr + 64] = a2.z; As[lc + 3][lr + 64] = a2.w;
    As[lc + 0][lr + 96] = a3.x; As[lc + 1][lr + 96] = a3.y; As[lc + 2][lr + 96] = a3.z; As[lc + 3][lr + 96] = a3.w;
    Bs[lc + 0][lr     ] = b0.x; Bs[lc + 1][lr     ] = b0.y; Bs[lc + 2][lr     ] = b0.z; Bs[lc + 3][lr     ] = b0.w;
    Bs[lc + 0][lr + 32] = b1.x; Bs[lc + 1][lr + 32] = b1.y; Bs[lc + 2][lr + 32] = b1.z; Bs[lc + 3][lr + 32] = b1.w;
    Bs[lc + 0][lr + 64] = b2.x; Bs[lc + 1][lr + 64] = b2.y; Bs[lc + 2][lr + 64] = b2.z; Bs[lc + 3][lr + 64] = b2.w;
    Bs[lc + 0][lr + 96] = b3.x; Bs[lc + 1][lr + 96] = b3.y; Bs[lc + 2][lr + 96] = b3.z; Bs[lc + 3][lr + 96] = b3.w;
    __syncthreads();
#pragma unroll 16
    for (int kk = 0; kk < PBK; ++kk) {
      float4 av0 = *(const float4*)&As[kk][tm];
      float4 av1 = *(const float4*)&As[kk][tm + 4];
      float4 bv0 = *(const float4*)&Bs[kk][tn];
      float4 bv1 = *(const float4*)&Bs[kk][tn + 4];
      float a[8] = {av0.x, av0.y, av0.z, av0.w, av1.x, av1.y, av1.z, av1.w};
      float bb[8] = {bv0.x, bv0.y, bv0.z, bv0.w, bv1.x, bv1.y, bv1.z, bv1.w};
#pragma unroll
      for (int i = 0; i < 8; ++i)
#pragma unroll
        for (int j = 0; j < 8; ++j) acc[i][j] = fmaf(a[i], bb[j], acc[i][j]);
    }
  }
#pragma unroll
  for (int i = 0; i < 8; ++i) {
    float* Cp = C + (size_t)(bm + tm + i) * N + bn + tn;
    *(float4*)Cp = make_float4(acc[i][0], acc[i][1], acc[i][2], acc[i][3]);
    *(float4*)(Cp + 4) = make_float4(acc[i][4], acc[i][5], acc[i][6], acc[i][7]);
  }
}

// fused Q/K/V: grid (24, 32); 768 blocks = 3 blocks/CU
__global__ __launch_bounds__(256) void gemm128_qkv(
    const float* __restrict__ x,
    const float* __restrict__ wq, const float* __restrict__ wk, const float* __restrict__ wv,
    float* __restrict__ qy, float* __restrict__ ky, float* __restrict__ vy)
{
  const int nb = blockIdx.x;
  const float* B; float* C;
  if (nb < 8)       { B = wq; C = qy; }
  else if (nb < 16) { B = wk; C = ky; }
  else              { B = wv; C = vy; }
  gemm128_core(x, B, C, blockIdx.y * 128, (nb & 7) * 128, 0, 1024);
}

// WO with split-K=2: grid (16, 32); z=0 -> p0 (k<512), z=1 -> p1 (k>=512)
__global__ __launch_bounds__(256) void gemm128_wo(
    const float* __restrict__ oy, const float* __restrict__ wo,
    float* __restrict__ p0, float* __restrict__ p1)
{
  const int z = blockIdx.x >> 3;
  float* C = z ? p1 : p0;
  gemm128_core(oy, wo, C, blockIdx.y * 128, (blockIdx.x & 7) * 128, z * 512, z * 512 + 512);
}

__global__ __launch_bounds__(256) void add_halves(
    const float* __restrict__ p0, const float* __restrict__ p1, float* __restrict__ out)
{
  const int i = blockIdx.x * 256 + threadIdx.x;
  const float4 a = ((const float4*)p0)[i];
  const float4 b = ((const float4*)p1)[i];
  ((float4*)out)[i] = make_float4(a.x + b.x, a.y + b.y, a.z + b.z, a.w + b.w);
}

// ---------------- top-4 |v| sparsify, fused over q/k/v, one wave per vector
__global__ __launch_bounds__(256) void sparsify_top4_3(
    float* __restrict__ qa, float* __restrict__ ka, float* __restrict__ va)
{
  int w = blockIdx.x * 4 + (threadIdx.x >> 6);   // 0..196607
  const int lane = threadIdx.x & 63;
  float* base = (w < 65536) ? qa : (w < 131072) ? ka : va;
  w &= 65535;
  float* p = base + (size_t)w * 64;
  const float v = p[lane];
  float ak = fabsf(v);
  bool sel = false;
#pragma unroll
  for (int it = 0; it < 4; ++it) {
    float bv = ak; int bl = lane;
#pragma unroll
    for (int off = 32; off > 0; off >>= 1) {
      float ov = __shfl_xor(bv, off);
      int   ol = __shfl_xor(bl, off);
      if (ov > bv || (ov == bv && ol < bl)) { bv = ov; bl = ol; }
    }
    if (lane == bl) { sel = true; ak = -1.0f; }
  }
  p[lane] = sel ? v : 0.0f;
}

// ---------------- K relayout: [b,t,h,j] -> KT [bh, j, t] --------------------
__global__ __launch_bounds__(256) void transpose_k(
    const float* __restrict__ Ky, float* __restrict__ KT)
{
  __shared__ float tile[64][65];
  const int bh = blockIdx.y;
  const int b = bh >> 4, h = bh & 15;
  const int t0 = blockIdx.x * 64;
  const int tid = threadIdx.x;
  {
    const int j = tid & 63, r = tid >> 6;
#pragma unroll
    for (int i = 0; i < 16; ++i) {
      const int tl = r * 16 + i;
      tile[tl][j] = Ky[(size_t)(b * TSEQ + t0 + tl) * 1024 + h * HD + j];
    }
  }
  __syncthreads();
  {
    const int tl = tid & 63, jr = tid >> 6;
#pragma unroll
    for (int i = 0; i < 16; ++i) {
      const int jl = jr * 16 + i;
      KT[((size_t)(bh * HD + jl)) * TSEQ + t0 + tl] = tile[tl][jl];
    }
  }
}

// ---------------- attention ---------------------------------------------------
__device__ __forceinline__ unsigned mono_key(float f) {
  unsigned b = __float_as_uint(f);
  return (b & 0x80000000u) ? ~b : (b | 0x80000000u);
}

// Exact rank-select over index-ordered allk[0..nall) (keys: hi32 = mono score,
// lo32 = k). Select hi32 > t_u plus the first need_eq (array order) == t_u;
// write (k, exp(s-m)) into sel_k/sel_p at obase... No local arrays (scratch!).
__device__ __forceinline__ void radix_sel_write(
    unsigned long long* allk, int nall, int target,
    int* hist, unsigned* p_pref, int* p_rem, int* wtot, int* wtot2,
    int* p_eqbase, int* p_wbase,
    int* sel_k, float* sel_p, int obase, bool neg, float m,
    int tid, int lane, int wid)
{
  if (tid == 0) { *p_rem = target; *p_pref = 0u; }
  __syncthreads();
  for (int pass = 0; pass < 4; ++pass) {
    const int shift = 24 - 8 * pass;
    hist[tid] = 0;
    __syncthreads();
    const unsigned pref = *p_pref;
    for (int t0 = 0; t0 < nall; t0 += 256) {
      const int t = t0 + tid;
      bool part = (t < nall);
      const unsigned u = part ? (unsigned)(allk[t] >> 32) : 0u;
      if (pass > 0) part = part && ((u >> (shift + 8)) == (pref >> (shift + 8)));
      const unsigned digit = (u >> shift) & 255u;
      if (part) {
        unsigned long long mm = __ballot(true);
#pragma unroll
        for (int bit = 0; bit < 8; ++bit) {
          unsigned long long bb = __ballot((int)((digit >> bit) & 1u));
          mm &= ((digit >> bit) & 1u) ? bb : ~bb;
        }
        if (lane == __ffsll((unsigned long long)mm) - 1)
          atomicAdd(&hist[digit], (int)__popcll(mm));
      }
    }
    __syncthreads();
    if (wid == 0) {
      const int d0 = lane << 2;
      const int c0 = hist[d0], c1 = hist[d0 + 1], c2 = hist[d0 + 2], c3 = hist[d0 + 3];
      const int sum = c0 + c1 + c2 + c3;
      int S = sum;
#pragma unroll
      for (int off = 1; off < 64; off <<= 1) {
        int t = __shfl_down(S, off);
        if (lane + off < 64) S += t;
      }
      const int above = S - sum;
      const int cg3 = above;
      const int cg2 = above + c3;
      const int cg1 = above + c3 + c2;
      const int cg0 = above + c3 + c2 + c1;
      const int rem = *p_rem;
      if (cg0 < rem && rem <= cg0 + c0) { *p_pref = pref | ((unsigned)(d0 + 0) << shift); *p_rem = rem - cg0; }
      if (cg1 < rem && rem <= cg1 + c1) { *p_pref = pref | ((unsigned)(d0 + 1) << shift); *p_rem = rem - cg1; }
      if (cg2 < rem && rem <= cg2 + c2) { *p_pref = pref | ((unsigned)(d0 + 2) << shift); *p_rem = rem - cg2; }
      if (cg3 < rem && rem <= cg3 + c3) { *p_pref = pref | ((unsigned)(d0 + 3) << shift); *p_rem = rem - cg3; }
    }
    __syncthreads();
  }
  const unsigned t_u = *p_pref;
  const int need_eq = *p_rem;
  if (tid == 0) { *p_eqbase = 0; *p_wbase = 0; }
  __syncthreads();
  for (int t0 = 0; t0 < nall; t0 += 256) {
    const int t = t0 + tid;
    const bool val = (t < nall);
    const unsigned long long kk = val ? allk[t] : 0ull;
    const unsigned u = (unsigned)(kk >> 32);
    const int eq = (val && u == t_u) ? 1 : 0;
    int ceq = eq;
#pragma unroll
    for (int off = 1; off < 64; off <<= 1) { int x = __shfl_up(ceq, off); if (lane >= off) ceq += x; }
    if (lane == 63) wtot[wid] = ceq;
    __syncthreads();
    int wo = 0;
    for (int w = 0; w < wid; ++w) wo += wtot[w];
    const int eqrank = *p_eqbase + wo + ceq - eq;
    const int sf = (val && ((u > t_u) || (eq && eqrank < need_eq))) ? 1 : 0;
    int csf = sf;
#pragma unroll
    for (int off = 1; off < 64; off <<= 1) { int x = __shfl_up(csf, off); if (lane >= off) csf += x; }
    if (lane == 63) wtot2[wid] = csf;
    __syncthreads();
    int wo2 = 0;
    for (int w = 0; w < wid; ++w) wo2 += wtot2[w];
    if (sf) {
      const int pos = *p_wbase + wo2 + csf - sf;
      const int k = (int)(kk & 0xffffffffull);
      const float sv = neg ? __uint_as_float(~u) : __uint_as_float(u & 0x7fffffffu);
      sel_k[obase + pos] = k;
      sel_p[obase + pos] = __expf(sv - m);
    }
    __syncthreads();
    if (tid == 0) {
      *p_eqbase += wtot[0] + wtot[1] + wtot[2] + wtot[3];
      *p_wbase  += wtot2[0] + wtot2[1] + wtot2[2] + wtot2[3];
    }
    __syncthreads();
  }
}

__global__ __launch_bounds__(256) void attn_sparse(
    const float* __restrict__ Qy, const float* __restrict__ KT,
    const float* __restrict__ Vy, float* __restrict__ Oy)
{
  const int q  = blockIdx.x;
  const int bh = blockIdx.y;
  const int b  = bh >> 4;
  const int h  = bh & 15;
  const int tid  = threadIdx.x;
  const int lane = tid & 63;
  const int wid  = tid >> 6;

  __shared__ unsigned long long pseg[4][256];  // per-wave compacted keys
  __shared__ unsigned long long allk[1024];    // merged, global index order
  __shared__ int   zseg[4][64];
  __shared__ int   c_pos[4], c_zst[4], c_zt[4], c_neg[4];
  __shared__ float redf[4];
  __shared__ int   hist[256];
  __shared__ float nzv[4];
  __shared__ int   nzi[4];
  __shared__ int   s_nsel;
  __shared__ unsigned s_pref;
  __shared__ int   s_rem;
  __shared__ int   wtot[4], wtot2[4];
  __shared__ int   s_eqbase, s_wbase;
  __shared__ int   sel_k[64];
  __shared__ float sel_p[64];
  __shared__ float oacc[4][64];
  __shared__ float s_z;

  // extract <=4 nonzeros of q, padded to 4 with zeros (pads contribute +-0)
  if (wid == 0) {
    if (lane < 4) { nzv[lane] = 0.0f; nzi[lane] = 0; }
    float v = Qy[((size_t)(b * TSEQ + q)) * 1024 + h * HD + lane];
    unsigned long long mk = __ballot(v != 0.0f);
    if (v != 0.0f) {
      int rk = (int)__popcll(mk & ((1ull << lane) - 1ull));
      if (rk < 4) { nzi[rk] = lane; nzv[rk] = v; }
    }
  }
  __syncthreads();
  const int nvalid = q + 1;
  const float* ktb = KT + (size_t)bh * HD * TSEQ;

  if (nvalid <= 64) {
    if (wid == 0) {
      float s = -INFINITY;
      if (lane < nvalid) {
        s = 0.0f;
#pragma unroll
        for (int j = 0; j < 4; ++j) s += nzv[j] * ktb[(size_t)nzi[j] * TSEQ + lane];
        s *= 0.125f;
      }
      float m = s;
#pragma unroll
      for (int off = 32; off; off >>= 1) m = fmaxf(m, __shfl_xor(m, off));
      if (lane < nvalid) { sel_k[lane] = lane; sel_p[lane] = __expf(s - m); }
      if (lane == 0) s_nsel = nvalid;
    }
  } else {
    const int cs = (nvalid + 3) >> 2;          // contiguous range per wave
    const int lo = wid * cs;
    const int hi = min(lo + cs, nvalid);
    const unsigned long long lml = (1ull << lane) - 1ull;

    int cp = 0, czs = 0, czt = 0;
    float mloc = -INFINITY;
    for (int k0 = lo; k0 < hi; k0 += 64) {
      const int k = k0 + lane;
      const bool val = (k < hi);
      float s = 0.0f;
      if (val) {
#pragma unroll
        for (int j = 0; j < 4; ++j) s += nzv[j] * ktb[(size_t)nzi[j] * TSEQ + k];
        s *= 0.125f;
        mloc = fmaxf(mloc, s);
      }
      unsigned u = mono_key(s);
      if (u == 0x7fffffffu) u = 0x80000000u;   // -0 -> +0 (ties with +0, idx order)
      const bool isp = val && (u > 0x80000000u);
      const bool isz = val && (u == 0x80000000u);
      unsigned long long mp = __ballot(isp);
      unsigned long long mz = __ballot(isz);
      if (isp)
        pseg[wid][cp + (int)__popcll(mp & lml)] = ((unsigned long long)u << 32) | (unsigned)k;
      if (isz) {
        const int o = czs + (int)__popcll(mz & lml);
        if (o < 64) zseg[wid][o] = k;
      }
      cp += (int)__popcll(mp);
      const int zc = (int)__popcll(mz);
      czt += zc;
      czs = min(czs + zc, 64);
    }
#pragma unroll
    for (int off = 32; off; off >>= 1) mloc = fmaxf(mloc, __shfl_xor(mloc, off));
    if (lane == 0) { c_pos[wid] = cp; c_zst[wid] = czs; c_zt[wid] = czt; redf[wid] = mloc; }
    __syncthreads();

    const int npos = c_pos[0] + c_pos[1] + c_pos[2] + c_pos[3];
    const int zt   = c_zt[0] + c_zt[1] + c_zt[2] + c_zt[3];
    const float m  = fmaxf(fmaxf(redf[0], redf[1]), fmaxf(redf[2], redf[3]));

    if (npos > 64) {
      // merge positives into allk (global index order), radix-select top-64
      int poff = 0;
      for (int w2 = 0; w2 < wid; ++w2) poff += c_pos[w2];
      for (int j = lane; j < c_pos[wid]; j += 64) allk[poff + j] = pseg[wid][j];
      if (tid == 0) s_nsel = 64;
      __syncthreads();
      radix_sel_write(allk, npos, 64, hist, &s_pref, &s_rem, wtot, wtot2,
                      &s_eqbase, &s_wbase, sel_k, sel_p, 0, false, m,
                      tid, lane, wid);
    } else {
      // all positives selected
      int poff = 0;
      for (int w2 = 0; w2 < wid; ++w2) poff += c_pos[w2];
      if (lane < c_pos[wid]) {
        const unsigned long long kk = pseg[wid][lane];
        sel_k[poff + lane] = (int)(kk & 0xffffffffull);
        sel_p[poff + lane] = __expf(__uint_as_float((unsigned)(kk >> 32) & 0x7fffffffu) - m);
      }
      const float ezm = __expf(-m);
      if (npos + zt >= 64) {
        // zeros fill the quota in global index order
        const int quota = 64 - npos;
        int zoff = 0;
        for (int w2 = 0; w2 < wid; ++w2) zoff += c_zst[w2];
        if (lane < c_zst[wid]) {
          const int r = zoff + lane;
          if (r < quota) { sel_k[npos + r] = zseg[wid][lane]; sel_p[npos + r] = ezm; }
        }
        if (tid == 0) s_nsel = 64;
      } else {
        // rare: boundary dips into negatives; all zeros stored (zt < 64)
        int zoff = 0;
        for (int w2 = 0; w2 < wid; ++w2) zoff += c_zt[w2];
        if (lane < c_zt[wid]) {
          sel_k[npos + zoff + lane] = zseg[wid][lane];
          sel_p[npos + zoff + lane] = ezm;
        }
        const int need = 64 - npos - zt;
        if (tid == 0) s_nsel = 64;
        __syncthreads();                 // positives consumed; reuse pseg
        int cn = 0;
        for (int k0 = lo; k0 < hi; k0 += 64) {
          const int k = k0 + lane;
          const bool val = (k < hi);
          float s = 0.0f;
          if (val) {
#pragma unroll
            for (int j = 0; j < 4; ++j) s += nzv[j] * ktb[(size_t)nzi[j] * TSEQ + k];
            s *= 0.125f;
          }
          unsigned u = mono_key(s);
          if (u == 0x7fffffffu) u = 0x80000000u;
          const bool isn = val && (u < 0x80000000u);
          unsigned long long mn = __ballot(isn);
          if (isn)
            pseg[wid][cn + (int)__popcll(mn & lml)] = ((unsigned long long)u << 32) | (unsigned)k;
          cn += (int)__popcll(mn);
        }
        if (lane == 0) c_neg[wid] = cn;
        __syncthreads();
        const int nneg = c_neg[0] + c_neg[1] + c_neg[2] + c_neg[3];
        int noff = 0;
        for (int w2 = 0; w2 < wid; ++w2) noff += c_neg[w2];
        for (int j = lane; j < c_neg[wid]; j += 64) allk[noff + j] = pseg[wid][j];
        __syncthreads();
        radix_sel_write(allk, nneg, need, hist, &s_pref, &s_rem, wtot, wtot2,
                        &s_eqbase, &s_wbase, sel_k, sel_p, npos + zt, true, m,
                        tid, lane, wid);
      }
    }
  }
  __syncthreads();
  const int nsel = s_nsel;
  if (wid == 0) {
    float p = (lane < nsel) ? sel_p[lane] : 0.0f;
#pragma unroll
    for (int off = 32; off; off >>= 1) p += __shfl_xor(p, off);
    if (lane == 0) s_z = p;
  }
  // epilogue: out[d] = sum_sel p * V[k][d] / Z ; 4 waves strided over entries
  float acc = 0.0f;
  const float* vb = Vy + ((size_t)b * TSEQ) * 1024 + h * HD + lane;
  for (int s2 = wid; s2 < nsel; s2 += 4)
    acc += sel_p[s2] * vb[(size_t)sel_k[s2] * 1024];
  oacc[wid][lane] = acc;
  __syncthreads();
  if (wid == 0) {
    const float r = (oacc[0][lane] + oacc[1][lane]) + (oacc[2][lane] + oacc[3][lane]);
    Oy[((size_t)(b * TSEQ + q)) * 1024 + h * HD + lane] = r / s_z;
  }
}

// ---------------- launch -----------------------------------------------------
extern "C" void kernel_launch(void* const* d_in, const int* in_sizes, int n_in,
                              void* d_out, int out_size, void* d_ws, size_t ws_size,
                              hipStream_t stream) {
  (void)in_sizes; (void)n_in; (void)out_size; (void)ws_size;
  const float* x  = (const float*)d_in[0];
  const float* wq = (const float*)d_in[1];
  const float* wk = (const float*)d_in[2];
  const float* wv = (const float*)d_in[3];
  const float* wo = (const float*)d_in[4];
  float* out = (float*)d_out;

  float* ws = (float*)d_ws;
  const size_t SZ = (size_t)4096 * 1024;   // 4M floats per buffer
  float* qy = ws;
  float* kyb = ws + SZ;
  float* vy = ws + 2 * SZ;
  float* kt = ws + 3 * SZ;
  float* oy = kyb;                         // kyb dead after transpose
  float* p0 = qy;                          // qy dead after attn
  float* p1 = kt;                          // kt dead after attn

  gemm128_qkv<<<dim3(24, 32), 256, 0, stream>>>(x, wq, wk, wv, qy, kyb, vy);

  sparsify_top4_3<<<196608 / 4, 256, 0, stream>>>(qy, kyb, vy);

  transpose_k<<<dim3(TSEQ / 64, 64), 256, 0, stream>>>(kyb, kt);

  attn_sparse<<<dim3(TSEQ, 64), 256, 0, stream>>>(qy, kt, vy, oy);

  gemm128_wo<<<dim3(16, 32), 256, 0, stream>>>(oy, wo, p0, p1);
  add_halves<<<4096, 256, 0, stream>>>(p0, p1, out);
}

// Round 7
// 664.352 us; speedup vs baseline: 1.5402x; 1.4020x over previous
//
#include <hip/hip_runtime.h>
#include <math.h>

#define TSEQ 1024
#define NH 16
#define HD 64

typedef short bf16x8 __attribute__((ext_vector_type(8)));
typedef float f32x4  __attribute__((ext_vector_type(4)));
typedef unsigned short ushort_t;

// ---------------- fp32 -> (hi, mid) bf16 split --------------------------------
__device__ __forceinline__ unsigned short rne_bf16(float a) {
  unsigned u = __float_as_uint(a);
  return (unsigned short)((u + 0x7fffu + ((u >> 16) & 1u)) >> 16);
}
__device__ __forceinline__ void split2(float a, unsigned short& h, unsigned short& m) {
  h = rne_bf16(a);
  float hf = __uint_as_float(((unsigned)h) << 16);
  m = rne_bf16(a - hf);
}

// fused conversion of x (4M) + wq/wk/wv/wo (1M each) into split buffers
__global__ __launch_bounds__(256) void conv_split(
    const float* __restrict__ x,
    const float* __restrict__ wq, const float* __restrict__ wk,
    const float* __restrict__ wv, const float* __restrict__ wo,
    ushort_t* __restrict__ xs, ushort_t* __restrict__ wsb)
{
  const int e = (blockIdx.x * 256 + threadIdx.x) * 4;
  const float* src; ushort_t *hp, *mp; int off;
  if (e < (1 << 22)) {
    src = x; off = e; hp = xs; mp = xs + (1u << 22);
  } else {
    int j = e - (1 << 22);
    int mat = j >> 20; off = j & ((1 << 20) - 1);
    src = (mat == 0) ? wq : (mat == 1) ? wk : (mat == 2) ? wv : wo;
    hp = wsb + (size_t)mat * (2u << 20); mp = hp + (1u << 20);
  }
  float4 v = *(const float4*)(src + off);
  ushort4 h, m;
  split2(v.x, h.x, m.x); split2(v.y, h.y, m.y);
  split2(v.z, h.z, m.z); split2(v.w, h.w, m.w);
  *(ushort4*)(hp + off) = h;
  *(ushort4*)(mp + off) = m;
}

// single-matrix conversion (attn output before WO)
__global__ __launch_bounds__(256) void conv1(
    const float* __restrict__ src, ushort_t* __restrict__ hp, ushort_t* __restrict__ mp)
{
  const int off = (blockIdx.x * 256 + threadIdx.x) * 4;
  float4 v = *(const float4*)(src + off);
  ushort4 h, m;
  split2(v.x, h.x, m.x); split2(v.y, h.y, m.y);
  split2(v.z, h.z, m.z); split2(v.w, h.w, m.w);
  *(ushort4*)(hp + off) = h;
  *(ushort4*)(mp + off) = m;
}

// ---------------- split-bf16 MFMA GEMM: C = A[M,K] * B[N,K]^T -----------------
// a = ah + am (bf16 each); keep all 4 products hh/hm/mh/mm -> ~8e-6 rel error.
// 128x128 block, 4 waves of 64x64 (4x4 tiles of 16x16), BK=32, K=N=1024.
// Frag layouts (m89/m120-verified): A: lane holds A[m=lane&15][k=quad*8+j];
// B: lane holds B_col[n=lane&15][k]; C/D: col=lane&15, row=quad*4+reg.
__device__ __forceinline__ void mfma_gemm_core(
    const ushort_t* __restrict__ Ah, const ushort_t* __restrict__ Am,
    const ushort_t* __restrict__ Bh, const ushort_t* __restrict__ Bm,
    float* __restrict__ C, const int bm, const int bn)
{
  __shared__ ushort_t ldsA[8192];   // [split][128][32]
  __shared__ ushort_t ldsB[8192];
  const int tid  = threadIdx.x;
  const int lane = tid & 63;
  const int w    = tid >> 6;
  const int wm = (w >> 1) << 6;
  const int wn = (w & 1) << 6;
  const int r16 = lane & 15;
  const int q   = lane >> 4;

  // staging: 4 reps x 16B cover one operand's 2 splits (128 rows x 32 k)
  const ushort_t* ga[4]; const ushort_t* gb[4]; int dst[4];
#pragma unroll
  for (int r = 0; r < 4; ++r) {
    const int linear = tid + 256 * r;
    const int s   = linear >> 9;
    const int idx = linear & 511;
    const int row = idx >> 2;
    const int kq  = (idx & 3) << 3;
    ga[r] = (s ? Am : Ah) + (size_t)(bm + row) * 1024 + kq;
    gb[r] = (s ? Bm : Bh) + (size_t)(bn + row) * 1024 + kq;
    dst[r] = linear << 3;       // ushort index == s*4096 + row*32 + kq
  }

  f32x4 acc[4][4];
#pragma unroll
  for (int mt = 0; mt < 4; ++mt)
#pragma unroll
    for (int nt = 0; nt < 4; ++nt) { f32x4 z = {0.f, 0.f, 0.f, 0.f}; acc[mt][nt] = z; }

  for (int k0 = 0; k0 < 1024; k0 += 32) {
    uint4 va0 = *(const uint4*)ga[0]; uint4 va1 = *(const uint4*)ga[1];
    uint4 va2 = *(const uint4*)ga[2]; uint4 va3 = *(const uint4*)ga[3];
    uint4 vb0 = *(const uint4*)gb[0]; uint4 vb1 = *(const uint4*)gb[1];
    uint4 vb2 = *(const uint4*)gb[2]; uint4 vb3 = *(const uint4*)gb[3];
#pragma unroll
    for (int r = 0; r < 4; ++r) { ga[r] += 32; gb[r] += 32; }
    __syncthreads();
    *(uint4*)&ldsA[dst[0]] = va0; *(uint4*)&ldsA[dst[1]] = va1;
    *(uint4*)&ldsA[dst[2]] = va2; *(uint4*)&ldsA[dst[3]] = va3;
    *(uint4*)&ldsB[dst[0]] = vb0; *(uint4*)&ldsB[dst[1]] = vb1;
    *(uint4*)&ldsB[dst[2]] = vb2; *(uint4*)&ldsB[dst[3]] = vb3;
    __syncthreads();

    bf16x8 bf[4][2];
#pragma unroll
    for (int nt = 0; nt < 4; ++nt) {
      bf[nt][0] = *(const bf16x8*)&ldsB[(wn + nt * 16 + r16) * 32 + q * 8];
      bf[nt][1] = *(const bf16x8*)&ldsB[4096 + (wn + nt * 16 + r16) * 32 + q * 8];
    }
#pragma unroll
    for (int mt = 0; mt < 4; ++mt) {
      const bf16x8 ah = *(const bf16x8*)&ldsA[(wm + mt * 16 + r16) * 32 + q * 8];
      const bf16x8 am = *(const bf16x8*)&ldsA[4096 + (wm + mt * 16 + r16) * 32 + q * 8];
#pragma unroll
      for (int nt = 0; nt < 4; ++nt) {
        f32x4 c = acc[mt][nt];
        c = __builtin_amdgcn_mfma_f32_16x16x32_bf16(am, bf[nt][1], c, 0, 0, 0); // mm
        c = __builtin_amdgcn_mfma_f32_16x16x32_bf16(am, bf[nt][0], c, 0, 0, 0); // mh
        c = __builtin_amdgcn_mfma_f32_16x16x32_bf16(ah, bf[nt][1], c, 0, 0, 0); // hm
        c = __builtin_amdgcn_mfma_f32_16x16x32_bf16(ah, bf[nt][0], c, 0, 0, 0); // hh
        acc[mt][nt] = c;
      }
    }
  }
#pragma unroll
  for (int mt = 0; mt < 4; ++mt)
#pragma unroll
    for (int nt = 0; nt < 4; ++nt)
#pragma unroll
      for (int r4 = 0; r4 < 4; ++r4)
        C[(size_t)(bm + wm + mt * 16 + q * 4 + r4) * 1024 + (bn + wn + nt * 16 + r16)] =
            acc[mt][nt][r4];
}

// fused Q/K/V: grid (24, 32) = 768 blocks
__global__ __launch_bounds__(256, 3) void mfma_qkv(
    const ushort_t* __restrict__ xs, const ushort_t* __restrict__ wsb,
    float* __restrict__ qy, float* __restrict__ ky, float* __restrict__ vy)
{
  const int nb = blockIdx.x;
  const int which = nb >> 3;
  float* C = (which == 0) ? qy : (which == 1) ? ky : vy;
  const ushort_t* Bh = wsb + (size_t)which * (2u << 20);
  mfma_gemm_core(xs, xs + (1u << 22), Bh, Bh + (1u << 20), C,
                 blockIdx.y * 128, (nb & 7) * 128);
}

// WO: grid (8, 32) = 256 blocks, writes final output directly
__global__ __launch_bounds__(256, 3) void mfma_wo(
    const ushort_t* __restrict__ oys, const ushort_t* __restrict__ wsb,
    float* __restrict__ out)
{
  const ushort_t* Bh = wsb + (size_t)3 * (2u << 20);
  mfma_gemm_core(oys, oys + (1u << 22), Bh, Bh + (1u << 20), out,
                 blockIdx.y * 128, blockIdx.x * 128);
}

// ---------------- top-4 |v| sparsify, fused over q/k/v, one wave per vector
__global__ __launch_bounds__(256) void sparsify_top4_3(
    float* __restrict__ qa, float* __restrict__ ka, float* __restrict__ va)
{
  int w = blockIdx.x * 4 + (threadIdx.x >> 6);   // 0..196607
  const int lane = threadIdx.x & 63;
  float* base = (w < 65536) ? qa : (w < 131072) ? ka : va;
  w &= 65535;
  float* p = base + (size_t)w * 64;
  const float v = p[lane];
  float ak = fabsf(v);
  bool sel = false;
#pragma unroll
  for (int it = 0; it < 4; ++it) {
    float bv = ak; int bl = lane;
#pragma unroll
    for (int off = 32; off > 0; off >>= 1) {
      float ov = __shfl_xor(bv, off);
      int   ol = __shfl_xor(bl, off);
      if (ov > bv || (ov == bv && ol < bl)) { bv = ov; bl = ol; }
    }
    if (lane == bl) { sel = true; ak = -1.0f; }
  }
  p[lane] = sel ? v : 0.0f;
}

// ---------------- K relayout: [b,t,h,j] -> KT [bh, j, t] --------------------
__global__ __launch_bounds__(256) void transpose_k(
    const float* __restrict__ Ky, float* __restrict__ KT)
{
  __shared__ float tile[64][65];
  const int bh = blockIdx.y;
  const int b = bh >> 4, h = bh & 15;
  const int t0 = blockIdx.x * 64;
  const int tid = threadIdx.x;
  {
    const int j = tid & 63, r = tid >> 6;
#pragma unroll
    for (int i = 0; i < 16; ++i) {
      const int tl = r * 16 + i;
      tile[tl][j] = Ky[(size_t)(b * TSEQ + t0 + tl) * 1024 + h * HD + j];
    }
  }
  __syncthreads();
  {
    const int tl = tid & 63, jr = tid >> 6;
#pragma unroll
    for (int i = 0; i < 16; ++i) {
      const int jl = jr * 16 + i;
      KT[((size_t)(bh * HD + jl)) * TSEQ + t0 + tl] = tile[tl][jl];
    }
  }
}

// ---------------- attention ---------------------------------------------------
__device__ __forceinline__ unsigned mono_key(float f) {
  unsigned b = __float_as_uint(f);
  return (b & 0x80000000u) ? ~b : (b | 0x80000000u);
}

__device__ __forceinline__ void radix_sel_write(
    unsigned long long* allk, int nall, int target,
    int* hist, unsigned* p_pref, int* p_rem, int* wtot, int* wtot2,
    int* p_eqbase, int* p_wbase,
    int* sel_k, float* sel_p, int obase, bool neg, float m,
    int tid, int lane, int wid)
{
  if (tid == 0) { *p_rem = target; *p_pref = 0u; }
  __syncthreads();
  for (int pass = 0; pass < 4; ++pass) {
    const int shift = 24 - 8 * pass;
    hist[tid] = 0;
    __syncthreads();
    const unsigned pref = *p_pref;
    for (int t0 = 0; t0 < nall; t0 += 256) {
      const int t = t0 + tid;
      bool part = (t < nall);
      const unsigned u = part ? (unsigned)(allk[t] >> 32) : 0u;
      if (pass > 0) part = part && ((u >> (shift + 8)) == (pref >> (shift + 8)));
      const unsigned digit = (u >> shift) & 255u;
      if (part) {
        unsigned long long mm = __ballot(true);
#pragma unroll
        for (int bit = 0; bit < 8; ++bit) {
          unsigned long long bb = __ballot((int)((digit >> bit) & 1u));
          mm &= ((digit >> bit) & 1u) ? bb : ~bb;
        }
        if (lane == __ffsll((unsigned long long)mm) - 1)
          atomicAdd(&hist[digit], (int)__popcll(mm));
      }
    }
    __syncthreads();
    if (wid == 0) {
      const int d0 = lane << 2;
      const int c0 = hist[d0], c1 = hist[d0 + 1], c2 = hist[d0 + 2], c3 = hist[d0 + 3];
      const int sum = c0 + c1 + c2 + c3;
      int S = sum;
#pragma unroll
      for (int off = 1; off < 64; off <<= 1) {
        int t = __shfl_down(S, off);
        if (lane + off < 64) S += t;
      }
      const int above = S - sum;
      const int cg3 = above;
      const int cg2 = above + c3;
      const int cg1 = above + c3 + c2;
      const int cg0 = above + c3 + c2 + c1;
      const int rem = *p_rem;
      if (cg0 < rem && rem <= cg0 + c0) { *p_pref = pref | ((unsigned)(d0 + 0) << shift); *p_rem = rem - cg0; }
      if (cg1 < rem && rem <= cg1 + c1) { *p_pref = pref | ((unsigned)(d0 + 1) << shift); *p_rem = rem - cg1; }
      if (cg2 < rem && rem <= cg2 + c2) { *p_pref = pref | ((unsigned)(d0 + 2) << shift); *p_rem = rem - cg2; }
      if (cg3 < rem && rem <= cg3 + c3) { *p_pref = pref | ((unsigned)(d0 + 3) << shift); *p_rem = rem - cg3; }
    }
    __syncthreads();
  }
  const unsigned t_u = *p_pref;
  const int need_eq = *p_rem;
  if (tid == 0) { *p_eqbase = 0; *p_wbase = 0; }
  __syncthreads();
  for (int t0 = 0; t0 < nall; t0 += 256) {
    const int t = t0 + tid;
    const bool val = (t < nall);
    const unsigned long long kk = val ? allk[t] : 0ull;
    const unsigned u = (unsigned)(kk >> 32);
    const int eq = (val && u == t_u) ? 1 : 0;
    int ceq = eq;
#pragma unroll
    for (int off = 1; off < 64; off <<= 1) { int x = __shfl_up(ceq, off); if (lane >= off) ceq += x; }
    if (lane == 63) wtot[wid] = ceq;
    __syncthreads();
    int wo = 0;
    for (int w = 0; w < wid; ++w) wo += wtot[w];
    const int eqrank = *p_eqbase + wo + ceq - eq;
    const int sf = (val && ((u > t_u) || (eq && eqrank < need_eq))) ? 1 : 0;
    int csf = sf;
#pragma unroll
    for (int off = 1; off < 64; off <<= 1) { int x = __shfl_up(csf, off); if (lane >= off) csf += x; }
    if (lane == 63) wtot2[wid] = csf;
    __syncthreads();
    int wo2 = 0;
    for (int w = 0; w < wid; ++w) wo2 += wtot2[w];
    if (sf) {
      const int pos = *p_wbase + wo2 + csf - sf;
      const int k = (int)(kk & 0xffffffffull);
      const float sv = neg ? __uint_as_float(~u) : __uint_as_float(u & 0x7fffffffu);
      sel_k[obase + pos] = k;
      sel_p[obase + pos] = __expf(sv - m);
    }
    __syncthreads();
    if (tid == 0) {
      *p_eqbase += wtot[0] + wtot[1] + wtot[2] + wtot[3];
      *p_wbase  += wtot2[0] + wtot2[1] + wtot2[2] + wtot2[3];
    }
    __syncthreads();
  }
}

__global__ __launch_bounds__(256) void attn_sparse(
    const float* __restrict__ Qy, const float* __restrict__ KT,
    const float* __restrict__ Vy, float* __restrict__ Oy)
{
  const int q  = blockIdx.x;
  const int bh = blockIdx.y;
  const int b  = bh >> 4;
  const int h  = bh & 15;
  const int tid  = threadIdx.x;
  const int lane = tid & 63;
  const int wid  = tid >> 6;

  __shared__ unsigned long long pseg[4][256];
  __shared__ unsigned long long allk[1024];
  __shared__ int   zseg[4][64];
  __shared__ int   c_pos[4], c_zst[4], c_zt[4], c_neg[4];
  __shared__ float redf[4];
  __shared__ int   hist[256];
  __shared__ float nzv[4];
  __shared__ int   nzi[4];
  __shared__ int   s_nsel;
  __shared__ unsigned s_pref;
  __shared__ int   s_rem;
  __shared__ int   wtot[4], wtot2[4];
  __shared__ int   s_eqbase, s_wbase;
  __shared__ int   sel_k[64];
  __shared__ float sel_p[64];
  __shared__ float oacc[4][64];
  __shared__ float s_z;

  if (wid == 0) {
    if (lane < 4) { nzv[lane] = 0.0f; nzi[lane] = 0; }
    float v = Qy[((size_t)(b * TSEQ + q)) * 1024 + h * HD + lane];
    unsigned long long mk = __ballot(v != 0.0f);
    if (v != 0.0f) {
      int rk = (int)__popcll(mk & ((1ull << lane) - 1ull));
      if (rk < 4) { nzi[rk] = lane; nzv[rk] = v; }
    }
  }
  __syncthreads();
  const int nvalid = q + 1;
  const float* ktb = KT + (size_t)bh * HD * TSEQ;

  if (nvalid <= 64) {
    if (wid == 0) {
      float s = -INFINITY;
      if (lane < nvalid) {
        s = 0.0f;
#pragma unroll
        for (int j = 0; j < 4; ++j) s += nzv[j] * ktb[(size_t)nzi[j] * TSEQ + lane];
        s *= 0.125f;
      }
      float m = s;
#pragma unroll
      for (int off = 32; off; off >>= 1) m = fmaxf(m, __shfl_xor(m, off));
      if (lane < nvalid) { sel_k[lane] = lane; sel_p[lane] = __expf(s - m); }
      if (lane == 0) s_nsel = nvalid;
    }
  } else {
    const int cs = (nvalid + 3) >> 2;
    const int lo = wid * cs;
    const int hi = min(lo + cs, nvalid);
    const unsigned long long lml = (1ull << lane) - 1ull;

    int cp = 0, czs = 0, czt = 0;
    float mloc = -INFINITY;
    for (int k0 = lo; k0 < hi; k0 += 64) {
      const int k = k0 + lane;
      const bool val = (k < hi);
      float s = 0.0f;
      if (val) {
#pragma unroll
        for (int j = 0; j < 4; ++j) s += nzv[j] * ktb[(size_t)nzi[j] * TSEQ + k];
        s *= 0.125f;
        mloc = fmaxf(mloc, s);
      }
      unsigned u = mono_key(s);
      if (u == 0x7fffffffu) u = 0x80000000u;
      const bool isp = val && (u > 0x80000000u);
      const bool isz = val && (u == 0x80000000u);
      unsigned long long mp = __ballot(isp);
      unsigned long long mz = __ballot(isz);
      if (isp)
        pseg[wid][cp + (int)__popcll(mp & lml)] = ((unsigned long long)u << 32) | (unsigned)k;
      if (isz) {
        const int o = czs + (int)__popcll(mz & lml);
        if (o < 64) zseg[wid][o] = k;
      }
      cp += (int)__popcll(mp);
      const int zc = (int)__popcll(mz);
      czt += zc;
      czs = min(czs + zc, 64);
    }
#pragma unroll
    for (int off = 32; off; off >>= 1) mloc = fmaxf(mloc, __shfl_xor(mloc, off));
    if (lane == 0) { c_pos[wid] = cp; c_zst[wid] = czs; c_zt[wid] = czt; redf[wid] = mloc; }
    __syncthreads();

    const int npos = c_pos[0] + c_pos[1] + c_pos[2] + c_pos[3];
    const int zt   = c_zt[0] + c_zt[1] + c_zt[2] + c_zt[3];
    const float m  = fmaxf(fmaxf(redf[0], redf[1]), fmaxf(redf[2], redf[3]));

    if (npos > 64) {
      int poff = 0;
      for (int w2 = 0; w2 < wid; ++w2) poff += c_pos[w2];
      for (int j = lane; j < c_pos[wid]; j += 64) allk[poff + j] = pseg[wid][j];
      if (tid == 0) s_nsel = 64;
      __syncthreads();
      radix_sel_write(allk, npos, 64, hist, &s_pref, &s_rem, wtot, wtot2,
                      &s_eqbase, &s_wbase, sel_k, sel_p, 0, false, m,
                      tid, lane, wid);
    } else {
      int poff = 0;
      for (int w2 = 0; w2 < wid; ++w2) poff += c_pos[w2];
      if (lane < c_pos[wid]) {
        const unsigned long long kk = pseg[wid][lane];
        sel_k[poff + lane] = (int)(kk & 0xffffffffull);
        sel_p[poff + lane] = __expf(__uint_as_float((unsigned)(kk >> 32) & 0x7fffffffu) - m);
      }
      const float ezm = __expf(-m);
      if (npos + zt >= 64) {
        const int quota = 64 - npos;
        int zoff = 0;
        for (int w2 = 0; w2 < wid; ++w2) zoff += c_zst[w2];
        if (lane < c_zst[wid]) {
          const int r = zoff + lane;
          if (r < quota) { sel_k[npos + r] = zseg[wid][lane]; sel_p[npos + r] = ezm; }
        }
        if (tid == 0) s_nsel = 64;
      } else {
        int zoff = 0;
        for (int w2 = 0; w2 < wid; ++w2) zoff += c_zt[w2];
        if (lane < c_zt[wid]) {
          sel_k[npos + zoff + lane] = zseg[wid][lane];
          sel_p[npos + zoff + lane] = ezm;
        }
        const int need = 64 - npos - zt;
        if (tid == 0) s_nsel = 64;
        __syncthreads();
        int cn = 0;
        for (int k0 = lo; k0 < hi; k0 += 64) {
          const int k = k0 + lane;
          const bool val = (k < hi);
          float s = 0.0f;
          if (val) {
#pragma unroll
            for (int j = 0; j < 4; ++j) s += nzv[j] * ktb[(size_t)nzi[j] * TSEQ + k];
            s *= 0.125f;
          }
          unsigned u = mono_key(s);
          if (u == 0x7fffffffu) u = 0x80000000u;
          const bool isn = val && (u < 0x80000000u);
          unsigned long long mn = __ballot(isn);
          if (isn)
            pseg[wid][cn + (int)__popcll(mn & lml)] = ((unsigned long long)u << 32) | (unsigned)k;
          cn += (int)__popcll(mn);
        }
        if (lane == 0) c_neg[wid] = cn;
        __syncthreads();
        const int nneg = c_neg[0] + c_neg[1] + c_neg[2] + c_neg[3];
        int noff = 0;
        for (int w2 = 0; w2 < wid; ++w2) noff += c_neg[w2];
        for (int j = lane; j < c_neg[wid]; j += 64) allk[noff + j] = pseg[wid][j];
        __syncthreads();
        radix_sel_write(allk, nneg, need, hist, &s_pref, &s_rem, wtot, wtot2,
                        &s_eqbase, &s_wbase, sel_k, sel_p, npos + zt, true, m,
                        tid, lane, wid);
      }
    }
  }
  __syncthreads();
  const int nsel = s_nsel;
  if (wid == 0) {
    float p = (lane < nsel) ? sel_p[lane] : 0.0f;
#pragma unroll
    for (int off = 32; off; off >>= 1) p += __shfl_xor(p, off);
    if (lane == 0) s_z = p;
  }
  float acc = 0.0f;
  const float* vb = Vy + ((size_t)b * TSEQ) * 1024 + h * HD + lane;
  for (int s2 = wid; s2 < nsel; s2 += 4)
    acc += sel_p[s2] * vb[(size_t)sel_k[s2] * 1024];
  oacc[wid][lane] = acc;
  __syncthreads();
  if (wid == 0) {
    const float r = (oacc[0][lane] + oacc[1][lane]) + (oacc[2][lane] + oacc[3][lane]);
    Oy[((size_t)(b * TSEQ + q)) * 1024 + h * HD + lane] = r / s_z;
  }
}

// ---------------- launch -----------------------------------------------------
extern "C" void kernel_launch(void* const* d_in, const int* in_sizes, int n_in,
                              void* d_out, int out_size, void* d_ws, size_t ws_size,
                              hipStream_t stream) {
  (void)in_sizes; (void)n_in; (void)out_size; (void)ws_size;
  const float* x  = (const float*)d_in[0];
  const float* wq = (const float*)d_in[1];
  const float* wk = (const float*)d_in[2];
  const float* wv = (const float*)d_in[3];
  const float* wo = (const float*)d_in[4];
  float* out = (float*)d_out;

  float* ws = (float*)d_ws;
  const size_t SZ = (size_t)4096 * 1024;   // 4M floats = 16MB per buffer
  float* qy  = ws;
  float* kyb = ws + SZ;
  float* vy  = ws + 2 * SZ;
  float* kt  = ws + 3 * SZ;
  ushort_t* xs  = (ushort_t*)(ws + 4 * SZ);   // 8M ushorts (x hi|mid)
  ushort_t* wsb = (ushort_t*)(ws + 5 * SZ);   // 8M ushorts (4 x (hi|mid))
  float* oy  = kyb;                           // kyb dead after transpose
  ushort_t* oys = xs;                         // xs dead after mfma_qkv

  conv_split<<<8192, 256, 0, stream>>>(x, wq, wk, wv, wo, xs, wsb);

  mfma_qkv<<<dim3(24, 32), 256, 0, stream>>>(xs, wsb, qy, kyb, vy);

  sparsify_top4_3<<<196608 / 4, 256, 0, stream>>>(qy, kyb, vy);

  transpose_k<<<dim3(TSEQ / 64, 64), 256, 0, stream>>>(kyb, kt);

  attn_sparse<<<dim3(TSEQ, 64), 256, 0, stream>>>(qy, kt, vy, oy);

  conv1<<<4096, 256, 0, stream>>>(oy, oys, oys + (1u << 22));
  mfma_wo<<<dim3(8, 32), 256, 0, stream>>>(oys, wsb, out);
}

// Round 8
// 494.835 us; speedup vs baseline: 2.0678x; 1.3426x over previous
//
#include <hip/hip_runtime.h>
#include <math.h>

#define TSEQ 1024
#define NH 16
#define HD 64

typedef short bf16x8 __attribute__((ext_vector_type(8)));
typedef float f32x4  __attribute__((ext_vector_type(4)));
typedef unsigned short ushort_t;

// ---------------- fp32 -> (hi, mid) bf16 split --------------------------------
__device__ __forceinline__ unsigned short rne_bf16(float a) {
  unsigned u = __float_as_uint(a);
  return (unsigned short)((u + 0x7fffu + ((u >> 16) & 1u)) >> 16);
}
__device__ __forceinline__ void split2(float a, unsigned short& h, unsigned short& m) {
  h = rne_bf16(a);
  float hf = __uint_as_float(((unsigned)h) << 16);
  m = rne_bf16(a - hf);
}

// fused conversion of x (4M) + wq/wk/wv/wo (1M each) into split buffers
__global__ __launch_bounds__(256) void conv_split(
    const float* __restrict__ x,
    const float* __restrict__ wq, const float* __restrict__ wk,
    const float* __restrict__ wv, const float* __restrict__ wo,
    ushort_t* __restrict__ xs, ushort_t* __restrict__ wsb)
{
  const int e = (blockIdx.x * 256 + threadIdx.x) * 4;
  const float* src; ushort_t *hp, *mp; int off;
  if (e < (1 << 22)) {
    src = x; off = e; hp = xs; mp = xs + (1u << 22);
  } else {
    int j = e - (1 << 22);
    int mat = j >> 20; off = j & ((1 << 20) - 1);
    src = (mat == 0) ? wq : (mat == 1) ? wk : (mat == 2) ? wv : wo;
    hp = wsb + (size_t)mat * (2u << 20); mp = hp + (1u << 20);
  }
  float4 v = *(const float4*)(src + off);
  ushort4 h, m;
  split2(v.x, h.x, m.x); split2(v.y, h.y, m.y);
  split2(v.z, h.z, m.z); split2(v.w, h.w, m.w);
  *(ushort4*)(hp + off) = h;
  *(ushort4*)(mp + off) = m;
}

// single-matrix conversion (attn output before WO)
__global__ __launch_bounds__(256) void conv1(
    const float* __restrict__ src, ushort_t* __restrict__ hp, ushort_t* __restrict__ mp)
{
  const int off = (blockIdx.x * 256 + threadIdx.x) * 4;
  float4 v = *(const float4*)(src + off);
  ushort4 h, m;
  split2(v.x, h.x, m.x); split2(v.y, h.y, m.y);
  split2(v.z, h.z, m.z); split2(v.w, h.w, m.w);
  *(ushort4*)(hp + off) = h;
  *(ushort4*)(mp + off) = m;
}

// ---------------- split-bf16 MFMA GEMM: C = A[M,K] * B[N,K]^T -----------------
__device__ __forceinline__ void mfma_gemm_core(
    const ushort_t* __restrict__ Ah, const ushort_t* __restrict__ Am,
    const ushort_t* __restrict__ Bh, const ushort_t* __restrict__ Bm,
    float* __restrict__ C, const int bm, const int bn)
{
  __shared__ ushort_t ldsA[8192];   // [split][128][32]
  __shared__ ushort_t ldsB[8192];
  const int tid  = threadIdx.x;
  const int lane = tid & 63;
  const int w    = tid >> 6;
  const int wm = (w >> 1) << 6;
  const int wn = (w & 1) << 6;
  const int r16 = lane & 15;
  const int q   = lane >> 4;

  const ushort_t* ga[4]; const ushort_t* gb[4]; int dst[4];
#pragma unroll
  for (int r = 0; r < 4; ++r) {
    const int linear = tid + 256 * r;
    const int s   = linear >> 9;
    const int idx = linear & 511;
    const int row = idx >> 2;
    const int kq  = (idx & 3) << 3;
    ga[r] = (s ? Am : Ah) + (size_t)(bm + row) * 1024 + kq;
    gb[r] = (s ? Bm : Bh) + (size_t)(bn + row) * 1024 + kq;
    dst[r] = linear << 3;
  }

  f32x4 acc[4][4];
#pragma unroll
  for (int mt = 0; mt < 4; ++mt)
#pragma unroll
    for (int nt = 0; nt < 4; ++nt) { f32x4 z = {0.f, 0.f, 0.f, 0.f}; acc[mt][nt] = z; }

  for (int k0 = 0; k0 < 1024; k0 += 32) {
    uint4 va0 = *(const uint4*)ga[0]; uint4 va1 = *(const uint4*)ga[1];
    uint4 va2 = *(const uint4*)ga[2]; uint4 va3 = *(const uint4*)ga[3];
    uint4 vb0 = *(const uint4*)gb[0]; uint4 vb1 = *(const uint4*)gb[1];
    uint4 vb2 = *(const uint4*)gb[2]; uint4 vb3 = *(const uint4*)gb[3];
#pragma unroll
    for (int r = 0; r < 4; ++r) { ga[r] += 32; gb[r] += 32; }
    __syncthreads();
    *(uint4*)&ldsA[dst[0]] = va0; *(uint4*)&ldsA[dst[1]] = va1;
    *(uint4*)&ldsA[dst[2]] = va2; *(uint4*)&ldsA[dst[3]] = va3;
    *(uint4*)&ldsB[dst[0]] = vb0; *(uint4*)&ldsB[dst[1]] = vb1;
    *(uint4*)&ldsB[dst[2]] = vb2; *(uint4*)&ldsB[dst[3]] = vb3;
    __syncthreads();

    bf16x8 bf[4][2];
#pragma unroll
    for (int nt = 0; nt < 4; ++nt) {
      bf[nt][0] = *(const bf16x8*)&ldsB[(wn + nt * 16 + r16) * 32 + q * 8];
      bf[nt][1] = *(const bf16x8*)&ldsB[4096 + (wn + nt * 16 + r16) * 32 + q * 8];
    }
#pragma unroll
    for (int mt = 0; mt < 4; ++mt) {
      const bf16x8 ah = *(const bf16x8*)&ldsA[(wm + mt * 16 + r16) * 32 + q * 8];
      const bf16x8 am = *(const bf16x8*)&ldsA[4096 + (wm + mt * 16 + r16) * 32 + q * 8];
#pragma unroll
      for (int nt = 0; nt < 4; ++nt) {
        f32x4 c = acc[mt][nt];
        c = __builtin_amdgcn_mfma_f32_16x16x32_bf16(am, bf[nt][1], c, 0, 0, 0); // mm
        c = __builtin_amdgcn_mfma_f32_16x16x32_bf16(am, bf[nt][0], c, 0, 0, 0); // mh
        c = __builtin_amdgcn_mfma_f32_16x16x32_bf16(ah, bf[nt][1], c, 0, 0, 0); // hm
        c = __builtin_amdgcn_mfma_f32_16x16x32_bf16(ah, bf[nt][0], c, 0, 0, 0); // hh
        acc[mt][nt] = c;
      }
    }
  }
#pragma unroll
  for (int mt = 0; mt < 4; ++mt)
#pragma unroll
    for (int nt = 0; nt < 4; ++nt)
#pragma unroll
      for (int r4 = 0; r4 < 4; ++r4)
        C[(size_t)(bm + wm + mt * 16 + q * 4 + r4) * 1024 + (bn + wn + nt * 16 + r16)] =
            acc[mt][nt][r4];
}

__global__ __launch_bounds__(256, 3) void mfma_qkv(
    const ushort_t* __restrict__ xs, const ushort_t* __restrict__ wsb,
    float* __restrict__ qy, float* __restrict__ ky, float* __restrict__ vy)
{
  const int nb = blockIdx.x;
  const int which = nb >> 3;
  float* C = (which == 0) ? qy : (which == 1) ? ky : vy;
  const ushort_t* Bh = wsb + (size_t)which * (2u << 20);
  mfma_gemm_core(xs, xs + (1u << 22), Bh, Bh + (1u << 20), C,
                 blockIdx.y * 128, (nb & 7) * 128);
}

__global__ __launch_bounds__(256, 3) void mfma_wo(
    const ushort_t* __restrict__ oys, const ushort_t* __restrict__ wsb,
    float* __restrict__ out)
{
  const ushort_t* Bh = wsb + (size_t)3 * (2u << 20);
  mfma_gemm_core(oys, oys + (1u << 22), Bh, Bh + (1u << 20), out,
                 blockIdx.y * 128, blockIdx.x * 128);
}

// ---------------- top-4 |v| sparsify, fused over q/k/v, one wave per vector
__global__ __launch_bounds__(256) void sparsify_top4_3(
    float* __restrict__ qa, float* __restrict__ ka, float* __restrict__ va)
{
  int w = blockIdx.x * 4 + (threadIdx.x >> 6);   // 0..196607
  const int lane = threadIdx.x & 63;
  float* base = (w < 65536) ? qa : (w < 131072) ? ka : va;
  w &= 65535;
  float* p = base + (size_t)w * 64;
  const float v = p[lane];
  float ak = fabsf(v);
  bool sel = false;
#pragma unroll
  for (int it = 0; it < 4; ++it) {
    float bv = ak; int bl = lane;
#pragma unroll
    for (int off = 32; off > 0; off >>= 1) {
      float ov = __shfl_xor(bv, off);
      int   ol = __shfl_xor(bl, off);
      if (ov > bv || (ov == bv && ol < bl)) { bv = ov; bl = ol; }
    }
    if (lane == bl) { sel = true; ak = -1.0f; }
  }
  p[lane] = sel ? v : 0.0f;
}

// ---------------- K relayout: [b,t,h,j] -> KT [bh, j, t] --------------------
__global__ __launch_bounds__(256) void transpose_k(
    const float* __restrict__ Ky, float* __restrict__ KT)
{
  __shared__ float tile[64][65];
  const int bh = blockIdx.y;
  const int b = bh >> 4, h = bh & 15;
  const int t0 = blockIdx.x * 64;
  const int tid = threadIdx.x;
  {
    const int j = tid & 63, r = tid >> 6;
#pragma unroll
    for (int i = 0; i < 16; ++i) {
      const int tl = r * 16 + i;
      tile[tl][j] = Ky[(size_t)(b * TSEQ + t0 + tl) * 1024 + h * HD + j];
    }
  }
  __syncthreads();
  {
    const int tl = tid & 63, jr = tid >> 6;
#pragma unroll
    for (int i = 0; i < 16; ++i) {
      const int jl = jr * 16 + i;
      KT[((size_t)(bh * HD + jl)) * TSEQ + t0 + tl] = tile[tl][jl];
    }
  }
}

// ---------------- attention: wave-synchronous, one wave per q-row -----------
__device__ __forceinline__ unsigned mono_key(float f) {
  unsigned b = __float_as_uint(f);
  return (b & 0x80000000u) ? ~b : (b | 0x80000000u);
}

// Wave-local exact rank-select over index-ordered ps[0..cnt) (hi32 = mono
// score, lo32 = k). Selects hi32 > threshold plus first `rem` (array order)
// == threshold; writes (k, exp(s-m)) at obase. No barriers; wave-synchronous.
__device__ __forceinline__ void wave_radix_sel(
    unsigned long long* ps, int cnt, int target,
    int* hr, int* skr, float* spr, int obase, bool neg, float m,
    int lane, unsigned long long lml)
{
  unsigned pref = 0u; int rem = target;
  for (int pass = 0; pass < 4; ++pass) {
    const int shift = 24 - 8 * pass;
    hr[lane] = 0; hr[lane + 64] = 0; hr[lane + 128] = 0; hr[lane + 192] = 0;
    for (int c0 = 0; c0 < cnt; c0 += 64) {
      const int t = c0 + lane;
      bool pt = (t < cnt);
      const unsigned u = pt ? (unsigned)(ps[t] >> 32) : 0u;
      if (pass > 0) pt = pt && ((u >> (shift + 8)) == (pref >> (shift + 8)));
      const unsigned digit = (u >> shift) & 255u;
      if (pt) {
        unsigned long long mm = __ballot(true);
#pragma unroll
        for (int bit = 0; bit < 8; ++bit) {
          unsigned long long bb = __ballot((int)((digit >> bit) & 1u));
          mm &= ((digit >> bit) & 1u) ? bb : ~bb;
        }
        if (lane == __ffsll(mm) - 1) atomicAdd(&hr[digit], (int)__popcll(mm));
      }
    }
    const int d0 = lane << 2;
    const int c0b = hr[d0], c1b = hr[d0 + 1], c2b = hr[d0 + 2], c3b = hr[d0 + 3];
    const int sum = c0b + c1b + c2b + c3b;
    int S = sum;
#pragma unroll
    for (int off = 1; off < 64; off <<= 1) {
      int t = __shfl_down(S, off);
      if (lane + off < 64) S += t;
    }
    const int above = S - sum;            // keys with digit in higher lanes
    const int cg3 = above;
    const int cg2 = above + c3b;
    const int cg1 = cg2 + c2b;
    const int cg0 = cg1 + c1b;
    const bool f0 = (cg0 < rem && rem <= cg0 + c0b);
    const bool f1 = (cg1 < rem && rem <= cg1 + c1b);
    const bool f2 = (cg2 < rem && rem <= cg2 + c2b);
    const bool f3 = (cg3 < rem && rem <= cg3 + c3b);
    const int fd  = f0 ? d0 : f1 ? (d0 + 1) : f2 ? (d0 + 2) : (d0 + 3);
    const int fcg = f0 ? cg0 : f1 ? cg1 : f2 ? cg2 : cg3;
    unsigned long long fm = __ballot(f0 || f1 || f2 || f3);
    const int src = __ffsll(fm) - 1;
    const int nprefl = (int)(pref | ((unsigned)fd << shift));
    const int nreml = rem - fcg;
    pref = (unsigned)__shfl(nprefl, src);
    rem  = __shfl(nreml, src);
  }
  int eqbase = 0, wbase = 0;
  for (int c0 = 0; c0 < cnt; c0 += 64) {
    const int t = c0 + lane;
    const bool valt = (t < cnt);
    const unsigned long long kk = valt ? ps[t] : 0ull;
    const unsigned u = (unsigned)(kk >> 32);
    const bool eq = valt && (u == pref);
    unsigned long long em = __ballot(eq);
    const int eqrank = eqbase + (int)__popcll(em & lml);
    const bool sf = valt && ((u > pref) || (eq && eqrank < rem));
    unsigned long long sm = __ballot(sf);
    if (sf) {
      const int pos = wbase + (int)__popcll(sm & lml);
      skr[obase + pos] = (int)(kk & 0xffffffffull);
      spr[obase + pos] =
          __expf((neg ? __uint_as_float(~u) : __uint_as_float(u & 0x7fffffffu)) - m);
    }
    eqbase += (int)__popcll(em);
    wbase  += (int)__popcll(sm);
  }
}

__global__ __launch_bounds__(256) void attn_sparse(
    const float* __restrict__ Qy, const float* __restrict__ KT,
    const float* __restrict__ Vy, float* __restrict__ Oy)
{
  const int bh = blockIdx.y;
  const int b  = bh >> 4;
  const int h  = bh & 15;
  const int tid  = threadIdx.x;
  const int lane = tid & 63;
  const int w    = tid >> 6;
  const int q    = blockIdx.x * 4 + w;

  __shared__ unsigned long long pseg[4][256];
  __shared__ int   zseg[4][64];
  __shared__ int   selk[4][64];
  __shared__ float selp[4][64];
  __shared__ int   hist[4][256];
  const unsigned long long lml = (1ull << lane) - 1ull;

  // q nonzeros: ffsll-peel the ballot mask, broadcast values via shfl
  const float qv = Qy[((size_t)(b * TSEQ + q)) * 1024 + h * HD + lane];
  unsigned long long mk = __ballot(qv != 0.0f);
  const int nnz = (int)__popcll(mk);
  unsigned long long mr = mk;
  int i0 = __ffsll(mr) - 1; if (i0 < 0) i0 = 0; mr &= mr - 1;
  int i1 = __ffsll(mr) - 1; if (i1 < 0) i1 = 0; mr &= mr - 1;
  int i2 = __ffsll(mr) - 1; if (i2 < 0) i2 = 0; mr &= mr - 1;
  int i3 = __ffsll(mr) - 1; if (i3 < 0) i3 = 0;
  float v0 = __shfl(qv, i0); if (nnz < 1) v0 = 0.0f;
  float v1 = __shfl(qv, i1); if (nnz < 2) v1 = 0.0f;
  float v2 = __shfl(qv, i2); if (nnz < 3) v2 = 0.0f;
  float v3 = __shfl(qv, i3); if (nnz < 4) v3 = 0.0f;
  const float* ktb = KT + (size_t)bh * HD * TSEQ;
  const float* kr0 = ktb + (size_t)i0 * TSEQ;
  const float* kr1 = ktb + (size_t)i1 * TSEQ;
  const float* kr2 = ktb + (size_t)i2 * TSEQ;
  const float* kr3 = ktb + (size_t)i3 * TSEQ;

  const int nvalid = q + 1;
  int cp = 0, czs = 0, czt = 0;
  float mloc = -INFINITY;
  float s0save = 0.0f;
  for (int k0 = 0; k0 < nvalid; k0 += 64) {
    const int k = k0 + lane;
    const bool val = (k < nvalid);
    float s = 0.0f;
    if (val) {
      s = v0 * kr0[k] + v1 * kr1[k] + v2 * kr2[k] + v3 * kr3[k];
      s *= 0.125f;
      mloc = fmaxf(mloc, s);
    }
    if (k0 == 0) s0save = s;
    unsigned u = mono_key(s);
    if (u == 0x7fffffffu) u = 0x80000000u;     // -0 -> +0 (ties with +0)
    const bool isp = val && (u > 0x80000000u);
    const bool isz = val && (u == 0x80000000u);
    unsigned long long mp = __ballot(isp);
    unsigned long long mz = __ballot(isz);
    if (isp) pseg[w][cp + (int)__popcll(mp & lml)] = ((unsigned long long)u << 32) | (unsigned)k;
    if (isz) { const int o = czs + (int)__popcll(mz & lml); if (o < 64) zseg[w][o] = k; }
    cp += (int)__popcll(mp);
    const int zc = (int)__popcll(mz);
    czt += zc;
    czs = min(czs + zc, 64);
  }
#pragma unroll
  for (int off = 32; off; off >>= 1) mloc = fmaxf(mloc, __shfl_xor(mloc, off));
  const float m = mloc;

  int nsel;
  if (nvalid <= 64) {
    if (lane < nvalid) { selk[w][lane] = lane; selp[w][lane] = __expf(s0save - m); }
    nsel = nvalid;
  } else if (cp <= 64 && cp + czt >= 64) {
    // fast path: boundary is exactly +0 (or smallest positive when cp==64)
    if (lane < cp) {
      const unsigned long long kk = pseg[w][lane];
      selk[w][lane] = (int)(kk & 0xffffffffull);
      selp[w][lane] = __expf(__uint_as_float((unsigned)(kk >> 32) & 0x7fffffffu) - m);
    }
    const int quota = 64 - cp;
    if (lane < quota) { selk[w][cp + lane] = zseg[w][lane]; selp[w][cp + lane] = __expf(-m); }
    nsel = 64;
  } else if (cp > 64) {
    wave_radix_sel(pseg[w], cp, 64, hist[w], selk[w], selp[w], 0, false, m, lane, lml);
    nsel = 64;
  } else {
    // rare: boundary dips into negatives (cp + czt < 64, czt == czs)
    if (lane < cp) {
      const unsigned long long kk = pseg[w][lane];
      selk[w][lane] = (int)(kk & 0xffffffffull);
      selp[w][lane] = __expf(__uint_as_float((unsigned)(kk >> 32) & 0x7fffffffu) - m);
    }
    if (lane < czt) { selk[w][cp + lane] = zseg[w][lane]; selp[w][cp + lane] = __expf(-m); }
    int cn = 0;
    for (int k0 = 0; k0 < nvalid; k0 += 64) {
      const int k = k0 + lane;
      const bool val = (k < nvalid);
      float s = 0.0f;
      if (val) {
        s = v0 * kr0[k] + v1 * kr1[k] + v2 * kr2[k] + v3 * kr3[k];
        s *= 0.125f;
      }
      unsigned u = mono_key(s);
      if (u == 0x7fffffffu) u = 0x80000000u;
      const bool isn = val && (u < 0x80000000u);
      unsigned long long mn = __ballot(isn);
      if (isn) pseg[w][cn + (int)__popcll(mn & lml)] = ((unsigned long long)u << 32) | (unsigned)k;
      cn += (int)__popcll(mn);
    }
    wave_radix_sel(pseg[w], cn, 64 - cp - czt, hist[w], selk[w], selp[w],
                   cp + czt, true, m, lane, lml);
    nsel = 64;
  }

  float Zp = (lane < nsel) ? selp[w][lane] : 0.0f;
#pragma unroll
  for (int off = 32; off; off >>= 1) Zp += __shfl_xor(Zp, off);
  const float Z = Zp;

  float acc = 0.0f;
  const float* vb = Vy + ((size_t)b * TSEQ) * 1024 + h * HD + lane;
  int s2 = 0;
  for (; s2 + 4 <= nsel; s2 += 4) {
    const float p0 = selp[w][s2],     p1 = selp[w][s2 + 1];
    const float p2 = selp[w][s2 + 2], p3 = selp[w][s2 + 3];
    const int  k0 = selk[w][s2],     k1 = selk[w][s2 + 1];
    const int  k2 = selk[w][s2 + 2], k3 = selk[w][s2 + 3];
    acc += p0 * vb[(size_t)k0 * 1024] + p1 * vb[(size_t)k1 * 1024]
         + p2 * vb[(size_t)k2 * 1024] + p3 * vb[(size_t)k3 * 1024];
  }
  for (; s2 < nsel; ++s2) acc += selp[w][s2] * vb[(size_t)selk[w][s2] * 1024];
  Oy[((size_t)(b * TSEQ + q)) * 1024 + h * HD + lane] = acc / Z;
}

// ---------------- launch -----------------------------------------------------
extern "C" void kernel_launch(void* const* d_in, const int* in_sizes, int n_in,
                              void* d_out, int out_size, void* d_ws, size_t ws_size,
                              hipStream_t stream) {
  (void)in_sizes; (void)n_in; (void)out_size; (void)ws_size;
  const float* x  = (const float*)d_in[0];
  const float* wq = (const float*)d_in[1];
  const float* wk = (const float*)d_in[2];
  const float* wv = (const float*)d_in[3];
  const float* wo = (const float*)d_in[4];
  float* out = (float*)d_out;

  float* ws = (float*)d_ws;
  const size_t SZ = (size_t)4096 * 1024;   // 4M floats = 16MB per buffer
  float* qy  = ws;
  float* kyb = ws + SZ;
  float* vy  = ws + 2 * SZ;
  float* kt  = ws + 3 * SZ;
  ushort_t* xs  = (ushort_t*)(ws + 4 * SZ);   // 8M ushorts (x hi|mid)
  ushort_t* wsb = (ushort_t*)(ws + 5 * SZ);   // 8M ushorts (4 x (hi|mid))
  float* oy  = kyb;                           // kyb dead after transpose
  ushort_t* oys = xs;                         // xs dead after mfma_qkv

  conv_split<<<8192, 256, 0, stream>>>(x, wq, wk, wv, wo, xs, wsb);

  mfma_qkv<<<dim3(24, 32), 256, 0, stream>>>(xs, wsb, qy, kyb, vy);

  sparsify_top4_3<<<196608 / 4, 256, 0, stream>>>(qy, kyb, vy);

  transpose_k<<<dim3(TSEQ / 64, 64), 256, 0, stream>>>(kyb, kt);

  attn_sparse<<<dim3(TSEQ / 4, 64), 256, 0, stream>>>(qy, kt, vy, oy);

  conv1<<<4096, 256, 0, stream>>>(oy, oys, oys + (1u << 22));
  mfma_wo<<<dim3(8, 32), 256, 0, stream>>>(oys, wsb, out);
}

// Round 9
// 435.796 us; speedup vs baseline: 2.3479x; 1.1355x over previous
//
#include <hip/hip_runtime.h>
#include <math.h>

#define TSEQ 1024
#define NH 16
#define HD 64

typedef short bf16x8 __attribute__((ext_vector_type(8)));
typedef float f32x4  __attribute__((ext_vector_type(4)));
typedef unsigned short ushort_t;

__device__ __forceinline__ int lane_rank(unsigned long long m) {
  return __builtin_amdgcn_mbcnt_hi((unsigned)(m >> 32),
         __builtin_amdgcn_mbcnt_lo((unsigned)m, 0u));
}

// ---------------- fp32 -> (hi, mid) bf16 split --------------------------------
__device__ __forceinline__ unsigned short rne_bf16(float a) {
  unsigned u = __float_as_uint(a);
  return (unsigned short)((u + 0x7fffu + ((u >> 16) & 1u)) >> 16);
}
__device__ __forceinline__ void split2(float a, unsigned short& h, unsigned short& m) {
  h = rne_bf16(a);
  float hf = __uint_as_float(((unsigned)h) << 16);
  m = rne_bf16(a - hf);
}

// fused conversion of x (4M) + wq/wk/wv/wo (1M each) into split buffers
__global__ __launch_bounds__(256) void conv_split(
    const float* __restrict__ x,
    const float* __restrict__ wq, const float* __restrict__ wk,
    const float* __restrict__ wv, const float* __restrict__ wo,
    ushort_t* __restrict__ xs, ushort_t* __restrict__ wsb)
{
  const int e = (blockIdx.x * 256 + threadIdx.x) * 4;
  const float* src; ushort_t *hp, *mp; int off;
  if (e < (1 << 22)) {
    src = x; off = e; hp = xs; mp = xs + (1u << 22);
  } else {
    int j = e - (1 << 22);
    int mat = j >> 20; off = j & ((1 << 20) - 1);
    src = (mat == 0) ? wq : (mat == 1) ? wk : (mat == 2) ? wv : wo;
    hp = wsb + (size_t)mat * (2u << 20); mp = hp + (1u << 20);
  }
  float4 v = *(const float4*)(src + off);
  ushort4 h, m;
  split2(v.x, h.x, m.x); split2(v.y, h.y, m.y);
  split2(v.z, h.z, m.z); split2(v.w, h.w, m.w);
  *(ushort4*)(hp + off) = h;
  *(ushort4*)(mp + off) = m;
}

// ---------------- split-bf16 MFMA GEMM: C = A[M,K] * B[N,K]^T -----------------
// 3-term split: hh + hm + mh (mm dropped: |am*bm| ~ 1.6e-5 relative).
__device__ __forceinline__ void mfma_gemm_core(
    const ushort_t* __restrict__ Ah, const ushort_t* __restrict__ Am,
    const ushort_t* __restrict__ Bh, const ushort_t* __restrict__ Bm,
    float* __restrict__ C, const int bm, const int bn)
{
  __shared__ ushort_t ldsA[8192];   // [split][128][32]
  __shared__ ushort_t ldsB[8192];
  const int tid  = threadIdx.x;
  const int lane = tid & 63;
  const int w    = tid >> 6;
  const int wm = (w >> 1) << 6;
  const int wn = (w & 1) << 6;
  const int r16 = lane & 15;
  const int q   = lane >> 4;

  const ushort_t* ga[4]; const ushort_t* gb[4]; int dst[4];
#pragma unroll
  for (int r = 0; r < 4; ++r) {
    const int linear = tid + 256 * r;
    const int s   = linear >> 9;
    const int idx = linear & 511;
    const int row = idx >> 2;
    const int kq  = (idx & 3) << 3;
    ga[r] = (s ? Am : Ah) + (size_t)(bm + row) * 1024 + kq;
    gb[r] = (s ? Bm : Bh) + (size_t)(bn + row) * 1024 + kq;
    dst[r] = linear << 3;
  }

  f32x4 acc[4][4];
#pragma unroll
  for (int mt = 0; mt < 4; ++mt)
#pragma unroll
    for (int nt = 0; nt < 4; ++nt) { f32x4 z = {0.f, 0.f, 0.f, 0.f}; acc[mt][nt] = z; }

  for (int k0 = 0; k0 < 1024; k0 += 32) {
    uint4 va0 = *(const uint4*)ga[0]; uint4 va1 = *(const uint4*)ga[1];
    uint4 va2 = *(const uint4*)ga[2]; uint4 va3 = *(const uint4*)ga[3];
    uint4 vb0 = *(const uint4*)gb[0]; uint4 vb1 = *(const uint4*)gb[1];
    uint4 vb2 = *(const uint4*)gb[2]; uint4 vb3 = *(const uint4*)gb[3];
#pragma unroll
    for (int r = 0; r < 4; ++r) { ga[r] += 32; gb[r] += 32; }
    __syncthreads();
    *(uint4*)&ldsA[dst[0]] = va0; *(uint4*)&ldsA[dst[1]] = va1;
    *(uint4*)&ldsA[dst[2]] = va2; *(uint4*)&ldsA[dst[3]] = va3;
    *(uint4*)&ldsB[dst[0]] = vb0; *(uint4*)&ldsB[dst[1]] = vb1;
    *(uint4*)&ldsB[dst[2]] = vb2; *(uint4*)&ldsB[dst[3]] = vb3;
    __syncthreads();

    bf16x8 bf[4][2];
#pragma unroll
    for (int nt = 0; nt < 4; ++nt) {
      bf[nt][0] = *(const bf16x8*)&ldsB[(wn + nt * 16 + r16) * 32 + q * 8];
      bf[nt][1] = *(const bf16x8*)&ldsB[4096 + (wn + nt * 16 + r16) * 32 + q * 8];
    }
#pragma unroll
    for (int mt = 0; mt < 4; ++mt) {
      const bf16x8 ah = *(const bf16x8*)&ldsA[(wm + mt * 16 + r16) * 32 + q * 8];
      const bf16x8 am = *(const bf16x8*)&ldsA[4096 + (wm + mt * 16 + r16) * 32 + q * 8];
#pragma unroll
      for (int nt = 0; nt < 4; ++nt) {
        f32x4 c = acc[mt][nt];
        c = __builtin_amdgcn_mfma_f32_16x16x32_bf16(am, bf[nt][0], c, 0, 0, 0); // mh
        c = __builtin_amdgcn_mfma_f32_16x16x32_bf16(ah, bf[nt][1], c, 0, 0, 0); // hm
        c = __builtin_amdgcn_mfma_f32_16x16x32_bf16(ah, bf[nt][0], c, 0, 0, 0); // hh
        acc[mt][nt] = c;
      }
    }
  }
#pragma unroll
  for (int mt = 0; mt < 4; ++mt)
#pragma unroll
    for (int nt = 0; nt < 4; ++nt)
#pragma unroll
      for (int r4 = 0; r4 < 4; ++r4)
        C[(size_t)(bm + wm + mt * 16 + q * 4 + r4) * 1024 + (bn + wn + nt * 16 + r16)] =
            acc[mt][nt][r4];
}

__global__ __launch_bounds__(256, 3) void mfma_qkv(
    const ushort_t* __restrict__ xs, const ushort_t* __restrict__ wsb,
    float* __restrict__ qy, float* __restrict__ ky, float* __restrict__ vy)
{
  const int nb = blockIdx.x;
  const int which = nb >> 3;
  float* C = (which == 0) ? qy : (which == 1) ? ky : vy;
  const ushort_t* Bh = wsb + (size_t)which * (2u << 20);
  mfma_gemm_core(xs, xs + (1u << 22), Bh, Bh + (1u << 20), C,
                 blockIdx.y * 128, (nb & 7) * 128);
}

__global__ __launch_bounds__(256, 3) void mfma_wo(
    const ushort_t* __restrict__ oys, const ushort_t* __restrict__ wsb,
    float* __restrict__ out)
{
  const ushort_t* Bh = wsb + (size_t)3 * (2u << 20);
  mfma_gemm_core(oys, oys + (1u << 22), Bh, Bh + (1u << 20), out,
                 blockIdx.y * 128, blockIdx.x * 128);
}

// ---------------- top-4 |v| sparsify, fused over q/k/v, one wave per vector
__global__ __launch_bounds__(256) void sparsify_top4_3(
    float* __restrict__ qa, float* __restrict__ ka, float* __restrict__ va)
{
  int w = blockIdx.x * 4 + (threadIdx.x >> 6);   // 0..196607
  const int lane = threadIdx.x & 63;
  float* base = (w < 65536) ? qa : (w < 131072) ? ka : va;
  w &= 65535;
  float* p = base + (size_t)w * 64;
  const float v = p[lane];
  float ak = fabsf(v);
  bool sel = false;
#pragma unroll
  for (int it = 0; it < 4; ++it) {
    float bv = ak; int bl = lane;
#pragma unroll
    for (int off = 32; off > 0; off >>= 1) {
      float ov = __shfl_xor(bv, off);
      int   ol = __shfl_xor(bl, off);
      if (ov > bv || (ov == bv && ol < bl)) { bv = ov; bl = ol; }
    }
    if (lane == bl) { sel = true; ak = -1.0f; }
  }
  p[lane] = sel ? v : 0.0f;
}

// ---------------- K relayout: [b,t,h,j] -> KT [bh, j, t] --------------------
__global__ __launch_bounds__(256) void transpose_k(
    const float* __restrict__ Ky, float* __restrict__ KT)
{
  __shared__ float tile[64][65];
  const int bh = blockIdx.y;
  const int b = bh >> 4, h = bh & 15;
  const int t0 = blockIdx.x * 64;
  const int tid = threadIdx.x;
  {
    const int j = tid & 63, r = tid >> 6;
#pragma unroll
    for (int i = 0; i < 16; ++i) {
      const int tl = r * 16 + i;
      tile[tl][j] = Ky[(size_t)(b * TSEQ + t0 + tl) * 1024 + h * HD + j];
    }
  }
  __syncthreads();
  {
    const int tl = tid & 63, jr = tid >> 6;
#pragma unroll
    for (int i = 0; i < 16; ++i) {
      const int jl = jr * 16 + i;
      KT[((size_t)(bh * HD + jl)) * TSEQ + t0 + tl] = tile[tl][jl];
    }
  }
}

// ---------------- attention: wave-synchronous, one wave per q-row -----------
__device__ __forceinline__ unsigned mono_key(float f) {
  unsigned b = __float_as_uint(f);
  return (b & 0x80000000u) ? ~b : (b | 0x80000000u);
}

// Wave-local exact rank-select over index-ordered ps[0..cnt) (hi32 = mono
// score, lo32 = k). Selects hi32 > threshold plus first `rem` (array order)
// == threshold; writes (k, exp(s-m)) at obase. No barriers; wave-synchronous.
__device__ __forceinline__ void wave_radix_sel(
    unsigned long long* ps, int cnt, int target,
    int* hr, int* skr, float* spr, int obase, bool neg, float m,
    int lane)
{
  unsigned pref = 0u; int rem = target;
  for (int pass = 0; pass < 4; ++pass) {
    const int shift = 24 - 8 * pass;
    hr[lane] = 0; hr[lane + 64] = 0; hr[lane + 128] = 0; hr[lane + 192] = 0;
    for (int c0 = 0; c0 < cnt; c0 += 64) {
      const int t = c0 + lane;
      bool pt = (t < cnt);
      const unsigned u = pt ? (unsigned)(ps[t] >> 32) : 0u;
      if (pass > 0) pt = pt && ((u >> (shift + 8)) == (pref >> (shift + 8)));
      const unsigned digit = (u >> shift) & 255u;
      if (pt) {
        unsigned long long mm = __ballot(true);
#pragma unroll
        for (int bit = 0; bit < 8; ++bit) {
          unsigned long long bb = __ballot((int)((digit >> bit) & 1u));
          mm &= ((digit >> bit) & 1u) ? bb : ~bb;
        }
        if (lane == __ffsll(mm) - 1) atomicAdd(&hr[digit], (int)__popcll(mm));
      }
    }
    const int d0 = lane << 2;
    const int c0b = hr[d0], c1b = hr[d0 + 1], c2b = hr[d0 + 2], c3b = hr[d0 + 3];
    const int sum = c0b + c1b + c2b + c3b;
    int S = sum;
#pragma unroll
    for (int off = 1; off < 64; off <<= 1) {
      int t = __shfl_down(S, off);
      if (lane + off < 64) S += t;
    }
    const int above = S - sum;            // keys with digit in higher lanes
    const int cg3 = above;
    const int cg2 = above + c3b;
    const int cg1 = cg2 + c2b;
    const int cg0 = cg1 + c1b;
    const bool f0 = (cg0 < rem && rem <= cg0 + c0b);
    const bool f1 = (cg1 < rem && rem <= cg1 + c1b);
    const bool f2 = (cg2 < rem && rem <= cg2 + c2b);
    const bool f3 = (cg3 < rem && rem <= cg3 + c3b);
    const int fd  = f0 ? d0 : f1 ? (d0 + 1) : f2 ? (d0 + 2) : (d0 + 3);
    const int fcg = f0 ? cg0 : f1 ? cg1 : f2 ? cg2 : cg3;
    unsigned long long fm = __ballot(f0 || f1 || f2 || f3);
    const int src = __ffsll(fm) - 1;
    const int nprefl = (int)(pref | ((unsigned)fd << shift));
    const int nreml = rem - fcg;
    pref = (unsigned)__shfl(nprefl, src);
    rem  = __shfl(nreml, src);
  }
  int eqbase = 0, wbase = 0;
  for (int c0 = 0; c0 < cnt; c0 += 64) {
    const int t = c0 + lane;
    const bool valt = (t < cnt);
    const unsigned long long kk = valt ? ps[t] : 0ull;
    const unsigned u = (unsigned)(kk >> 32);
    const bool eq = valt && (u == pref);
    unsigned long long em = __ballot(eq);
    const int eqrank = eqbase + lane_rank(em);
    const bool sf = valt && ((u > pref) || (eq && eqrank < rem));
    unsigned long long sm = __ballot(sf);
    if (sf) {
      const int pos = wbase + lane_rank(sm);
      skr[obase + pos] = (int)(kk & 0xffffffffull);
      spr[obase + pos] =
          __expf((neg ? __uint_as_float(~u) : __uint_as_float(u & 0x7fffffffu)) - m);
    }
    eqbase += (int)__popcll(em);
    wbase  += (int)__popcll(sm);
  }
}

__global__ __launch_bounds__(256) void attn_sparse(
    const float* __restrict__ Qy, const float* __restrict__ KT,
    const float* __restrict__ Vy,
    ushort_t* __restrict__ Oh, ushort_t* __restrict__ Om)
{
  const int bh = blockIdx.y;
  const int b  = bh >> 4;
  const int h  = bh & 15;
  const int tid  = threadIdx.x;
  const int lane = tid & 63;
  const int w    = tid >> 6;
  const int bi   = blockIdx.x;
  // load-balanced row map: per-block total nvalid is constant (2050)
  const int q = (w == 0) ? bi : (w == 1) ? (511 - bi) : (w == 2) ? (512 + bi) : (1023 - bi);

  __shared__ unsigned long long pseg[4][256];
  __shared__ int   zseg[4][64];
  __shared__ int   selk[4][64];
  __shared__ float selp[4][64];
  __shared__ int   hist[4][256];

  // q nonzeros: ffsll-peel the ballot mask, broadcast values via shfl
  const float qv = Qy[((size_t)(b * TSEQ + q)) * 1024 + h * HD + lane];
  unsigned long long mk = __ballot(qv != 0.0f);
  const int nnz = (int)__popcll(mk);
  unsigned long long mr = mk;
  int i0 = __ffsll(mr) - 1; if (i0 < 0) i0 = 0; mr &= mr - 1;
  int i1 = __ffsll(mr) - 1; if (i1 < 0) i1 = 0; mr &= mr - 1;
  int i2 = __ffsll(mr) - 1; if (i2 < 0) i2 = 0; mr &= mr - 1;
  int i3 = __ffsll(mr) - 1; if (i3 < 0) i3 = 0;
  float v0 = __shfl(qv, i0); if (nnz < 1) v0 = 0.0f;
  float v1 = __shfl(qv, i1); if (nnz < 2) v1 = 0.0f;
  float v2 = __shfl(qv, i2); if (nnz < 3) v2 = 0.0f;
  float v3 = __shfl(qv, i3); if (nnz < 4) v3 = 0.0f;
  const float* ktb = KT + (size_t)bh * HD * TSEQ;
  const float* kr0 = ktb + (size_t)i0 * TSEQ;
  const float* kr1 = ktb + (size_t)i1 * TSEQ;
  const float* kr2 = ktb + (size_t)i2 * TSEQ;
  const float* kr3 = ktb + (size_t)i3 * TSEQ;

  const int nvalid = q + 1;
  int cp = 0, cz = 0;
  float mloc = -INFINITY;
  float s0save = 0.0f;
  for (int k0 = 0; k0 < nvalid; k0 += 64) {
    const int k = k0 + lane;
    const bool val = (k < nvalid);
    // unguarded loads: worst-case 63 elements past row end stay inside d_ws
    float s = (v0 * kr0[k] + v1 * kr1[k] + v2 * kr2[k] + v3 * kr3[k]) * 0.125f;
    if (k0 == 0) s0save = s;
    const bool isp = val && (s > 0.0f);
    mloc = val ? fmaxf(mloc, s) : mloc;
    unsigned long long mp = __ballot(isp);
    if (isp)
      pseg[w][cp + lane_rank(mp)] =
          ((unsigned long long)(__float_as_uint(s) | 0x80000000u) << 32) | (unsigned)k;
    cp += (int)__popcll(mp);
    if (cz < 64) {                        // wave-uniform gate; stops once 64 banked
      const bool isz = val && (s == 0.0f);
      unsigned long long mz = __ballot(isz);
      if (isz) { const int o = cz + lane_rank(mz); if (o < 64) zseg[w][o] = k; }
      cz += (int)__popcll(mz);
    }
  }
#pragma unroll
  for (int off = 32; off; off >>= 1) mloc = fmaxf(mloc, __shfl_xor(mloc, off));
  const float m = mloc;
  const bool czfull = (cz >= 64);

  int nsel;
  if (nvalid <= 64) {
    if (lane < nvalid) { selk[w][lane] = lane; selp[w][lane] = __expf(s0save - m); }
    nsel = nvalid;
  } else if (cp <= 64 && (czfull || cp + cz >= 64)) {
    // fast path: boundary is exactly +0 (or smallest positive when cp==64)
    if (lane < cp) {
      const unsigned long long kk = pseg[w][lane];
      selk[w][lane] = (int)(kk & 0xffffffffull);
      selp[w][lane] = __expf(__uint_as_float((unsigned)(kk >> 32) & 0x7fffffffu) - m);
    }
    const int quota = 64 - cp;
    if (lane < quota) { selk[w][cp + lane] = zseg[w][lane]; selp[w][cp + lane] = __expf(-m); }
    nsel = 64;
  } else if (cp > 64) {
    wave_radix_sel(pseg[w], cp, 64, hist[w], selk[w], selp[w], 0, false, m, lane);
    nsel = 64;
  } else {
    // rare: boundary dips into negatives (cp + cz < 64; cz exact here)
    if (lane < cp) {
      const unsigned long long kk = pseg[w][lane];
      selk[w][lane] = (int)(kk & 0xffffffffull);
      selp[w][lane] = __expf(__uint_as_float((unsigned)(kk >> 32) & 0x7fffffffu) - m);
    }
    if (lane < cz) { selk[w][cp + lane] = zseg[w][lane]; selp[w][cp + lane] = __expf(-m); }
    int cn = 0;
    for (int k0 = 0; k0 < nvalid; k0 += 64) {
      const int k = k0 + lane;
      const bool val = (k < nvalid);
      float s = (v0 * kr0[k] + v1 * kr1[k] + v2 * kr2[k] + v3 * kr3[k]) * 0.125f;
      const bool isn = val && (s < 0.0f);
      unsigned long long mn = __ballot(isn);
      if (isn)
        pseg[w][cn + lane_rank(mn)] =
            ((unsigned long long)mono_key(s) << 32) | (unsigned)k;
      cn += (int)__popcll(mn);
    }
    wave_radix_sel(pseg[w], cn, 64 - cp - cz, hist[w], selk[w], selp[w],
                   cp + cz, true, m, lane);
    nsel = 64;
  }

  float Zp = (lane < nsel) ? selp[w][lane] : 0.0f;
#pragma unroll
  for (int off = 32; off; off >>= 1) Zp += __shfl_xor(Zp, off);
  const float Z = Zp;

  float acc = 0.0f;
  const float* vb = Vy + ((size_t)b * TSEQ) * 1024 + h * HD + lane;
  int s2 = 0;
  for (; s2 + 4 <= nsel; s2 += 4) {
    const float p0 = selp[w][s2],     p1 = selp[w][s2 + 1];
    const float p2 = selp[w][s2 + 2], p3 = selp[w][s2 + 3];
    const int  k0 = selk[w][s2],     k1 = selk[w][s2 + 1];
    const int  k2 = selk[w][s2 + 2], k3 = selk[w][s2 + 3];
    acc += p0 * vb[(size_t)k0 * 1024] + p1 * vb[(size_t)k1 * 1024]
         + p2 * vb[(size_t)k2 * 1024] + p3 * vb[(size_t)k3 * 1024];
  }
  for (; s2 < nsel; ++s2) acc += selp[w][s2] * vb[(size_t)selk[w][s2] * 1024];
  const float r = acc / Z;
  unsigned short rh, rm;
  split2(r, rh, rm);
  const size_t oidx = ((size_t)(b * TSEQ + q)) * 1024 + h * HD + lane;
  Oh[oidx] = rh;
  Om[oidx] = rm;
}

// ---------------- launch -----------------------------------------------------
extern "C" void kernel_launch(void* const* d_in, const int* in_sizes, int n_in,
                              void* d_out, int out_size, void* d_ws, size_t ws_size,
                              hipStream_t stream) {
  (void)in_sizes; (void)n_in; (void)out_size; (void)ws_size;
  const float* x  = (const float*)d_in[0];
  const float* wq = (const float*)d_in[1];
  const float* wk = (const float*)d_in[2];
  const float* wv = (const float*)d_in[3];
  const float* wo = (const float*)d_in[4];
  float* out = (float*)d_out;

  float* ws = (float*)d_ws;
  const size_t SZ = (size_t)4096 * 1024;   // 4M floats = 16MB per buffer
  float* qy  = ws;
  float* kyb = ws + SZ;
  float* vy  = ws + 2 * SZ;
  float* kt  = ws + 3 * SZ;
  ushort_t* xs  = (ushort_t*)(ws + 4 * SZ);   // 8M ushorts (x hi|mid)
  ushort_t* wsb = (ushort_t*)(ws + 5 * SZ);   // 8M ushorts (4 x (hi|mid))
  ushort_t* oys = xs;                         // xs dead after mfma_qkv

  conv_split<<<8192, 256, 0, stream>>>(x, wq, wk, wv, wo, xs, wsb);

  mfma_qkv<<<dim3(24, 32), 256, 0, stream>>>(xs, wsb, qy, kyb, vy);

  sparsify_top4_3<<<196608 / 4, 256, 0, stream>>>(qy, kyb, vy);

  transpose_k<<<dim3(TSEQ / 64, 64), 256, 0, stream>>>(kyb, kt);

  attn_sparse<<<dim3(TSEQ / 4, 64), 256, 0, stream>>>(qy, kt, vy,
                                                      oys, oys + (1u << 22));

  mfma_wo<<<dim3(8, 32), 256, 0, stream>>>(oys, wsb, out);
}

// Round 10
// 356.622 us; speedup vs baseline: 2.8692x; 1.2220x over previous
//
#include <hip/hip_runtime.h>
#include <math.h>

#define TSEQ 1024
#define NH 16
#define HD 64

typedef short bf16x8 __attribute__((ext_vector_type(8)));
typedef float f32x4  __attribute__((ext_vector_type(4)));
typedef unsigned short ushort_t;

__device__ __forceinline__ int lane_rank(unsigned long long m) {
  return __builtin_amdgcn_mbcnt_hi((unsigned)(m >> 32),
         __builtin_amdgcn_mbcnt_lo((unsigned)m, 0u));
}

// ---------------- fp32 -> (hi, mid) bf16 split --------------------------------
__device__ __forceinline__ unsigned short rne_bf16(float a) {
  unsigned u = __float_as_uint(a);
  return (unsigned short)((u + 0x7fffu + ((u >> 16) & 1u)) >> 16);
}
__device__ __forceinline__ void split2(float a, unsigned short& h, unsigned short& m) {
  h = rne_bf16(a);
  float hf = __uint_as_float(((unsigned)h) << 16);
  m = rne_bf16(a - hf);
}

// fused conversion of x (4M) + wq/wk/wv/wo (1M each) into split buffers
__global__ __launch_bounds__(256) void conv_split(
    const float* __restrict__ x,
    const float* __restrict__ wq, const float* __restrict__ wk,
    const float* __restrict__ wv, const float* __restrict__ wo,
    ushort_t* __restrict__ xs, ushort_t* __restrict__ wsb)
{
  const int e = (blockIdx.x * 256 + threadIdx.x) * 4;
  const float* src; ushort_t *hp, *mp; int off;
  if (e < (1 << 22)) {
    src = x; off = e; hp = xs; mp = xs + (1u << 22);
  } else {
    int j = e - (1 << 22);
    int mat = j >> 20; off = j & ((1 << 20) - 1);
    src = (mat == 0) ? wq : (mat == 1) ? wk : (mat == 2) ? wv : wo;
    hp = wsb + (size_t)mat * (2u << 20); mp = hp + (1u << 20);
  }
  float4 v = *(const float4*)(src + off);
  ushort4 h, m;
  split2(v.x, h.x, m.x); split2(v.y, h.y, m.y);
  split2(v.z, h.z, m.z); split2(v.w, h.w, m.w);
  *(ushort4*)(hp + off) = h;
  *(ushort4*)(mp + off) = m;
}

// ---------------- split-bf16 MFMA GEMM: C = A[M,K] * B[N,K]^T -----------------
// 3-term split: hh + hm + mh (mm dropped: |am*bm| ~ 1.6e-5 relative).
// mode 0: dense C store (WO).
// mode 1: in-register top-4 |v| sparsify per (row,head)-vector, dense C store.
// mode 2: sparsify + store transposed into KT[bh][j][t] (K path).
// Each wave's 64x64 tile = one head x 64 rows, so every head-vector is
// wave-local: 16 lanes (r16) x 4 values (nt), j = nt*16+r16.
__device__ __forceinline__ void mfma_gemm_core(
    const ushort_t* __restrict__ Ah, const ushort_t* __restrict__ Am,
    const ushort_t* __restrict__ Bh, const ushort_t* __restrict__ Bm,
    float* __restrict__ C, float* __restrict__ KTb,
    const int bm, const int bn, const int mode)
{
  __shared__ ushort_t ldsA[8192];   // [split][128][32]
  __shared__ ushort_t ldsB[8192];
  const int tid  = threadIdx.x;
  const int lane = tid & 63;
  const int w    = tid >> 6;
  const int wm = (w >> 1) << 6;
  const int wn = (w & 1) << 6;
  const int r16 = lane & 15;
  const int q   = lane >> 4;

  const ushort_t* ga[4]; const ushort_t* gb[4]; int dst[4];
#pragma unroll
  for (int r = 0; r < 4; ++r) {
    const int linear = tid + 256 * r;
    const int s   = linear >> 9;
    const int idx = linear & 511;
    const int row = idx >> 2;
    const int kq  = (idx & 3) << 3;
    ga[r] = (s ? Am : Ah) + (size_t)(bm + row) * 1024 + kq;
    gb[r] = (s ? Bm : Bh) + (size_t)(bn + row) * 1024 + kq;
    dst[r] = linear << 3;
  }

  f32x4 acc[4][4];
#pragma unroll
  for (int mt = 0; mt < 4; ++mt)
#pragma unroll
    for (int nt = 0; nt < 4; ++nt) { f32x4 z = {0.f, 0.f, 0.f, 0.f}; acc[mt][nt] = z; }

  for (int k0 = 0; k0 < 1024; k0 += 32) {
    uint4 va0 = *(const uint4*)ga[0]; uint4 va1 = *(const uint4*)ga[1];
    uint4 va2 = *(const uint4*)ga[2]; uint4 va3 = *(const uint4*)ga[3];
    uint4 vb0 = *(const uint4*)gb[0]; uint4 vb1 = *(const uint4*)gb[1];
    uint4 vb2 = *(const uint4*)gb[2]; uint4 vb3 = *(const uint4*)gb[3];
#pragma unroll
    for (int r = 0; r < 4; ++r) { ga[r] += 32; gb[r] += 32; }
    __syncthreads();
    *(uint4*)&ldsA[dst[0]] = va0; *(uint4*)&ldsA[dst[1]] = va1;
    *(uint4*)&ldsA[dst[2]] = va2; *(uint4*)&ldsA[dst[3]] = va3;
    *(uint4*)&ldsB[dst[0]] = vb0; *(uint4*)&ldsB[dst[1]] = vb1;
    *(uint4*)&ldsB[dst[2]] = vb2; *(uint4*)&ldsB[dst[3]] = vb3;
    __syncthreads();

    bf16x8 bf[4][2];
#pragma unroll
    for (int nt = 0; nt < 4; ++nt) {
      bf[nt][0] = *(const bf16x8*)&ldsB[(wn + nt * 16 + r16) * 32 + q * 8];
      bf[nt][1] = *(const bf16x8*)&ldsB[4096 + (wn + nt * 16 + r16) * 32 + q * 8];
    }
#pragma unroll
    for (int mt = 0; mt < 4; ++mt) {
      const bf16x8 ah = *(const bf16x8*)&ldsA[(wm + mt * 16 + r16) * 32 + q * 8];
      const bf16x8 am = *(const bf16x8*)&ldsA[4096 + (wm + mt * 16 + r16) * 32 + q * 8];
#pragma unroll
      for (int nt = 0; nt < 4; ++nt) {
        f32x4 c = acc[mt][nt];
        c = __builtin_amdgcn_mfma_f32_16x16x32_bf16(am, bf[nt][0], c, 0, 0, 0); // mh
        c = __builtin_amdgcn_mfma_f32_16x16x32_bf16(ah, bf[nt][1], c, 0, 0, 0); // hm
        c = __builtin_amdgcn_mfma_f32_16x16x32_bf16(ah, bf[nt][0], c, 0, 0, 0); // hh
        acc[mt][nt] = c;
      }
    }
  }

  if (mode != 0) {
    // in-register top-4 |v| sparsify: tie -> lowest j (matches jax top_k).
    // Row for (mt,r4) is owned by the lane's quad; shfl_xor<16 stays in-quad.
#pragma unroll
    for (int it = 0; it < 16; ++it) {
      const int mti = it >> 2, r4i = it & 3;
      int cons = 0;
#pragma unroll
      for (int rnd = 0; rnd < 4; ++rnd) {
        float bv = -1.0f; int bj = 1024;
#pragma unroll
        for (int nt = 0; nt < 4; ++nt) {
          const float av = ((cons >> nt) & 1) ? -1.0f : fabsf(acc[mti][nt][r4i]);
          const int jj = nt * 16 + r16;
          if (av > bv) { bv = av; bj = jj; }
        }
#pragma unroll
        for (int off = 1; off < 16; off <<= 1) {
          const float ov = __shfl_xor(bv, off);
          const int   oj = __shfl_xor(bj, off);
          if (ov > bv || (ov == bv && oj < bj)) { bv = ov; bj = oj; }
        }
        if ((bj & 15) == r16) cons |= 1 << (bj >> 4);
      }
#pragma unroll
      for (int nt = 0; nt < 4; ++nt)
        if (!((cons >> nt) & 1)) acc[mti][nt][r4i] = 0.0f;
    }
  }

  if (mode == 2) {
    // K path: store transposed into KT[bh][j][t]; acc regs are 4 consecutive t
    const int row0 = bm + wm;            // never crosses a 1024 boundary
    const int b = row0 >> 10;
    const int h = (bn + wn) >> 6;
    float* kb = KTb + ((size_t)(b * 16 + h) << 16);
    const int tb = (row0 & 1023) + q * 4;
#pragma unroll
    for (int mt = 0; mt < 4; ++mt) {
      const int t0 = tb + mt * 16;
#pragma unroll
      for (int nt = 0; nt < 4; ++nt) {
        const int j = nt * 16 + r16;
        *(float4*)(kb + (size_t)j * 1024 + t0) =
            make_float4(acc[mt][nt][0], acc[mt][nt][1], acc[mt][nt][2], acc[mt][nt][3]);
      }
    }
  } else {
#pragma unroll
    for (int mt = 0; mt < 4; ++mt)
#pragma unroll
      for (int nt = 0; nt < 4; ++nt)
#pragma unroll
        for (int r4 = 0; r4 < 4; ++r4)
          C[(size_t)(bm + wm + mt * 16 + q * 4 + r4) * 1024 + (bn + wn + nt * 16 + r16)] =
              acc[mt][nt][r4];
  }
}

// fused Q/K/V + sparsify + K-transpose: grid (24, 32)
__global__ __launch_bounds__(256, 3) void mfma_qkv(
    const ushort_t* __restrict__ xs, const ushort_t* __restrict__ wsb,
    float* __restrict__ qy, float* __restrict__ kt, float* __restrict__ vy)
{
  const int nb = blockIdx.x;
  const int which = nb >> 3;
  float* C = (which == 0) ? qy : vy;       // unused for K (mode 2)
  const int mode = (which == 1) ? 2 : 1;
  const ushort_t* Bh = wsb + (size_t)which * (2u << 20);
  mfma_gemm_core(xs, xs + (1u << 22), Bh, Bh + (1u << 20), C, kt,
                 blockIdx.y * 128, (nb & 7) * 128, mode);
}

__global__ __launch_bounds__(256, 3) void mfma_wo(
    const ushort_t* __restrict__ oys, const ushort_t* __restrict__ wsb,
    float* __restrict__ out)
{
  const ushort_t* Bh = wsb + (size_t)3 * (2u << 20);
  mfma_gemm_core(oys, oys + (1u << 22), Bh, Bh + (1u << 20), out, nullptr,
                 blockIdx.y * 128, blockIdx.x * 128, 0);
}

// ---------------- attention: wave-synchronous, one wave per q-row -----------
__device__ __forceinline__ unsigned mono_key(float f) {
  unsigned b = __float_as_uint(f);
  return (b & 0x80000000u) ? ~b : (b | 0x80000000u);
}

// Wave-local exact rank-select over index-ordered ps[0..cnt) (hi32 = mono
// score, lo32 = k). Selects hi32 > threshold plus first `rem` (array order)
// == threshold; writes (k, exp(s-m)) at obase. No barriers; wave-synchronous.
__device__ __forceinline__ void wave_radix_sel(
    unsigned long long* ps, int cnt, int target,
    int* hr, int* skr, float* spr, int obase, bool neg, float m,
    int lane)
{
  unsigned pref = 0u; int rem = target;
  for (int pass = 0; pass < 4; ++pass) {
    const int shift = 24 - 8 * pass;
    hr[lane] = 0; hr[lane + 64] = 0; hr[lane + 128] = 0; hr[lane + 192] = 0;
    for (int c0 = 0; c0 < cnt; c0 += 64) {
      const int t = c0 + lane;
      bool pt = (t < cnt);
      const unsigned u = pt ? (unsigned)(ps[t] >> 32) : 0u;
      if (pass > 0) pt = pt && ((u >> (shift + 8)) == (pref >> (shift + 8)));
      const unsigned digit = (u >> shift) & 255u;
      if (pt) {
        unsigned long long mm = __ballot(true);
#pragma unroll
        for (int bit = 0; bit < 8; ++bit) {
          unsigned long long bb = __ballot((int)((digit >> bit) & 1u));
          mm &= ((digit >> bit) & 1u) ? bb : ~bb;
        }
        if (lane == __ffsll(mm) - 1) atomicAdd(&hr[digit], (int)__popcll(mm));
      }
    }
    const int d0 = lane << 2;
    const int c0b = hr[d0], c1b = hr[d0 + 1], c2b = hr[d0 + 2], c3b = hr[d0 + 3];
    const int sum = c0b + c1b + c2b + c3b;
    int S = sum;
#pragma unroll
    for (int off = 1; off < 64; off <<= 1) {
      int t = __shfl_down(S, off);
      if (lane + off < 64) S += t;
    }
    const int above = S - sum;            // keys with digit in higher lanes
    const int cg3 = above;
    const int cg2 = above + c3b;
    const int cg1 = cg2 + c2b;
    const int cg0 = cg1 + c1b;
    const bool f0 = (cg0 < rem && rem <= cg0 + c0b);
    const bool f1 = (cg1 < rem && rem <= cg1 + c1b);
    const bool f2 = (cg2 < rem && rem <= cg2 + c2b);
    const bool f3 = (cg3 < rem && rem <= cg3 + c3b);
    const int fd  = f0 ? d0 : f1 ? (d0 + 1) : f2 ? (d0 + 2) : (d0 + 3);
    const int fcg = f0 ? cg0 : f1 ? cg1 : f2 ? cg2 : cg3;
    unsigned long long fm = __ballot(f0 || f1 || f2 || f3);
    const int src = __ffsll(fm) - 1;
    const int nprefl = (int)(pref | ((unsigned)fd << shift));
    const int nreml = rem - fcg;
    pref = (unsigned)__shfl(nprefl, src);
    rem  = __shfl(nreml, src);
  }
  int eqbase = 0, wbase = 0;
  for (int c0 = 0; c0 < cnt; c0 += 64) {
    const int t = c0 + lane;
    const bool valt = (t < cnt);
    const unsigned long long kk = valt ? ps[t] : 0ull;
    const unsigned u = (unsigned)(kk >> 32);
    const bool eq = valt && (u == pref);
    unsigned long long em = __ballot(eq);
    const int eqrank = eqbase + lane_rank(em);
    const bool sf = valt && ((u > pref) || (eq && eqrank < rem));
    unsigned long long sm = __ballot(sf);
    if (sf) {
      const int pos = wbase + lane_rank(sm);
      skr[obase + pos] = (int)(kk & 0xffffffffull);
      spr[obase + pos] =
          __expf((neg ? __uint_as_float(~u) : __uint_as_float(u & 0x7fffffffu)) - m);
    }
    eqbase += (int)__popcll(em);
    wbase  += (int)__popcll(sm);
  }
}

__global__ __launch_bounds__(256) void attn_sparse(
    const float* __restrict__ Qy, const float* __restrict__ KT,
    const float* __restrict__ Vy,
    ushort_t* __restrict__ Oh, ushort_t* __restrict__ Om)
{
  const int bh = blockIdx.y;
  const int b  = bh >> 4;
  const int h  = bh & 15;
  const int tid  = threadIdx.x;
  const int lane = tid & 63;
  const int w    = tid >> 6;
  const int bi   = blockIdx.x;
  // load-balanced row map: per-block total nvalid is constant (2050)
  const int q = (w == 0) ? bi : (w == 1) ? (511 - bi) : (w == 2) ? (512 + bi) : (1023 - bi);

  __shared__ unsigned long long pseg[4][256];
  __shared__ int   zseg[4][64];
  __shared__ int   selk[4][64];
  __shared__ float selp[4][64];
  __shared__ int   hist[4][256];

  // q nonzeros: ffsll-peel the ballot mask, broadcast values via shfl
  const float qv = Qy[((size_t)(b * TSEQ + q)) * 1024 + h * HD + lane];
  unsigned long long mk = __ballot(qv != 0.0f);
  const int nnz = (int)__popcll(mk);
  unsigned long long mr = mk;
  int i0 = __ffsll(mr) - 1; if (i0 < 0) i0 = 0; mr &= mr - 1;
  int i1 = __ffsll(mr) - 1; if (i1 < 0) i1 = 0; mr &= mr - 1;
  int i2 = __ffsll(mr) - 1; if (i2 < 0) i2 = 0; mr &= mr - 1;
  int i3 = __ffsll(mr) - 1; if (i3 < 0) i3 = 0;
  float v0 = __shfl(qv, i0); if (nnz < 1) v0 = 0.0f;
  float v1 = __shfl(qv, i1); if (nnz < 2) v1 = 0.0f;
  float v2 = __shfl(qv, i2); if (nnz < 3) v2 = 0.0f;
  float v3 = __shfl(qv, i3); if (nnz < 4) v3 = 0.0f;
  const float* ktb = KT + (size_t)bh * HD * TSEQ;
  const float* kr0 = ktb + (size_t)i0 * TSEQ;
  const float* kr1 = ktb + (size_t)i1 * TSEQ;
  const float* kr2 = ktb + (size_t)i2 * TSEQ;
  const float* kr3 = ktb + (size_t)i3 * TSEQ;

  const int nvalid = q + 1;
  int cp = 0, cz = 0;
  float mloc = -INFINITY;
  float s0save = 0.0f;
  for (int k0 = 0; k0 < nvalid; k0 += 64) {
    const int k = k0 + lane;
    const bool val = (k < nvalid);
    // unguarded loads: worst-case 63 elements past row end stay inside d_ws
    float s = (v0 * kr0[k] + v1 * kr1[k] + v2 * kr2[k] + v3 * kr3[k]) * 0.125f;
    if (k0 == 0) s0save = s;
    const bool isp = val && (s > 0.0f);
    mloc = val ? fmaxf(mloc, s) : mloc;
    unsigned long long mp = __ballot(isp);
    if (isp)
      pseg[w][cp + lane_rank(mp)] =
          ((unsigned long long)(__float_as_uint(s) | 0x80000000u) << 32) | (unsigned)k;
    cp += (int)__popcll(mp);
    if (cz < 64) {                        // wave-uniform gate; stops once 64 banked
      const bool isz = val && (s == 0.0f);
      unsigned long long mz = __ballot(isz);
      if (isz) { const int o = cz + lane_rank(mz); if (o < 64) zseg[w][o] = k; }
      cz += (int)__popcll(mz);
    }
  }
#pragma unroll
  for (int off = 32; off; off >>= 1) mloc = fmaxf(mloc, __shfl_xor(mloc, off));
  const float m = mloc;
  const bool czfull = (cz >= 64);

  int nsel;
  if (nvalid <= 64) {
    if (lane < nvalid) { selk[w][lane] = lane; selp[w][lane] = __expf(s0save - m); }
    nsel = nvalid;
  } else if (cp <= 64 && (czfull || cp + cz >= 64)) {
    // fast path: boundary is exactly +0 (or smallest positive when cp==64)
    if (lane < cp) {
      const unsigned long long kk = pseg[w][lane];
      selk[w][lane] = (int)(kk & 0xffffffffull);
      selp[w][lane] = __expf(__uint_as_float((unsigned)(kk >> 32) & 0x7fffffffu) - m);
    }
    const int quota = 64 - cp;
    if (lane < quota) { selk[w][cp + lane] = zseg[w][lane]; selp[w][cp + lane] = __expf(-m); }
    nsel = 64;
  } else if (cp > 64) {
    wave_radix_sel(pseg[w], cp, 64, hist[w], selk[w], selp[w], 0, false, m, lane);
    nsel = 64;
  } else {
    // rare: boundary dips into negatives (cp + cz < 64; cz exact here)
    if (lane < cp) {
      const unsigned long long kk = pseg[w][lane];
      selk[w][lane] = (int)(kk & 0xffffffffull);
      selp[w][lane] = __expf(__uint_as_float((unsigned)(kk >> 32) & 0x7fffffffu) - m);
    }
    if (lane < cz) { selk[w][cp + lane] = zseg[w][lane]; selp[w][cp + lane] = __expf(-m); }
    int cn = 0;
    for (int k0 = 0; k0 < nvalid; k0 += 64) {
      const int k = k0 + lane;
      const bool val = (k < nvalid);
      float s = (v0 * kr0[k] + v1 * kr1[k] + v2 * kr2[k] + v3 * kr3[k]) * 0.125f;
      const bool isn = val && (s < 0.0f);
      unsigned long long mn = __ballot(isn);
      if (isn)
        pseg[w][cn + lane_rank(mn)] =
            ((unsigned long long)mono_key(s) << 32) | (unsigned)k;
      cn += (int)__popcll(mn);
    }
    wave_radix_sel(pseg[w], cn, 64 - cp - cz, hist[w], selk[w], selp[w],
                   cp + cz, true, m, lane);
    nsel = 64;
  }

  float Zp = (lane < nsel) ? selp[w][lane] : 0.0f;
#pragma unroll
  for (int off = 32; off; off >>= 1) Zp += __shfl_xor(Zp, off);
  const float Z = Zp;

  float acc = 0.0f;
  const float* vb = Vy + ((size_t)b * TSEQ) * 1024 + h * HD + lane;
  int s2 = 0;
  for (; s2 + 4 <= nsel; s2 += 4) {
    const float p0 = selp[w][s2],     p1 = selp[w][s2 + 1];
    const float p2 = selp[w][s2 + 2], p3 = selp[w][s2 + 3];
    const int  k0 = selk[w][s2],     k1 = selk[w][s2 + 1];
    const int  k2 = selk[w][s2 + 2], k3 = selk[w][s2 + 3];
    acc += p0 * vb[(size_t)k0 * 1024] + p1 * vb[(size_t)k1 * 1024]
         + p2 * vb[(size_t)k2 * 1024] + p3 * vb[(size_t)k3 * 1024];
  }
  for (; s2 < nsel; ++s2) acc += selp[w][s2] * vb[(size_t)selk[w][s2] * 1024];
  const float r = acc / Z;
  unsigned short rh, rm;
  split2(r, rh, rm);
  const size_t oidx = ((size_t)(b * TSEQ + q)) * 1024 + h * HD + lane;
  Oh[oidx] = rh;
  Om[oidx] = rm;
}

// ---------------- launch -----------------------------------------------------
extern "C" void kernel_launch(void* const* d_in, const int* in_sizes, int n_in,
                              void* d_out, int out_size, void* d_ws, size_t ws_size,
                              hipStream_t stream) {
  (void)in_sizes; (void)n_in; (void)out_size; (void)ws_size;
  const float* x  = (const float*)d_in[0];
  const float* wq = (const float*)d_in[1];
  const float* wk = (const float*)d_in[2];
  const float* wv = (const float*)d_in[3];
  const float* wo = (const float*)d_in[4];
  float* out = (float*)d_out;

  float* ws = (float*)d_ws;
  const size_t SZ = (size_t)4096 * 1024;   // 4M floats = 16MB per buffer
  float* qy  = ws;
  float* vy  = ws + 2 * SZ;
  float* kt  = ws + 3 * SZ;
  ushort_t* xs  = (ushort_t*)(ws + 4 * SZ);   // 8M ushorts (x hi|mid)
  ushort_t* wsb = (ushort_t*)(ws + 5 * SZ);   // 8M ushorts (4 x (hi|mid))
  ushort_t* oys = xs;                         // xs dead after mfma_qkv

  conv_split<<<8192, 256, 0, stream>>>(x, wq, wk, wv, wo, xs, wsb);

  // QKV GEMM + in-register top-4 sparsify + direct transposed K write
  mfma_qkv<<<dim3(24, 32), 256, 0, stream>>>(xs, wsb, qy, kt, vy);

  attn_sparse<<<dim3(TSEQ / 4, 64), 256, 0, stream>>>(qy, kt, vy,
                                                      oys, oys + (1u << 22));

  mfma_wo<<<dim3(8, 32), 256, 0, stream>>>(oys, wsb, out);
}

// Round 11
// 347.598 us; speedup vs baseline: 2.9437x; 1.0260x over previous
//
#include <hip/hip_runtime.h>
#include <math.h>

#define TSEQ 1024
#define NH 16
#define HD 64

typedef short bf16x8 __attribute__((ext_vector_type(8)));
typedef float f32x4  __attribute__((ext_vector_type(4)));
typedef unsigned short ushort_t;
typedef unsigned long long ull_t;

__device__ __forceinline__ int lane_rank(unsigned long long m) {
  return __builtin_amdgcn_mbcnt_hi((unsigned)(m >> 32),
         __builtin_amdgcn_mbcnt_lo((unsigned)m, 0u));
}

// ---------------- fp32 -> (hi, mid) bf16 split --------------------------------
__device__ __forceinline__ unsigned short rne_bf16(float a) {
  unsigned u = __float_as_uint(a);
  return (unsigned short)((u + 0x7fffu + ((u >> 16) & 1u)) >> 16);
}
__device__ __forceinline__ void split2(float a, unsigned short& h, unsigned short& m) {
  h = rne_bf16(a);
  float hf = __uint_as_float(((unsigned)h) << 16);
  m = rne_bf16(a - hf);
}

// fused conversion of x (4M) + wq/wk/wv/wo (1M each) into split buffers
__global__ __launch_bounds__(256) void conv_split(
    const float* __restrict__ x,
    const float* __restrict__ wq, const float* __restrict__ wk,
    const float* __restrict__ wv, const float* __restrict__ wo,
    ushort_t* __restrict__ xs, ushort_t* __restrict__ wsb)
{
  const int e = (blockIdx.x * 256 + threadIdx.x) * 4;
  const float* src; ushort_t *hp, *mp; int off;
  if (e < (1 << 22)) {
    src = x; off = e; hp = xs; mp = xs + (1u << 22);
  } else {
    int j = e - (1 << 22);
    int mat = j >> 20; off = j & ((1 << 20) - 1);
    src = (mat == 0) ? wq : (mat == 1) ? wk : (mat == 2) ? wv : wo;
    hp = wsb + (size_t)mat * (2u << 20); mp = hp + (1u << 20);
  }
  float4 v = *(const float4*)(src + off);
  ushort4 h, m;
  split2(v.x, h.x, m.x); split2(v.y, h.y, m.y);
  split2(v.z, h.z, m.z); split2(v.w, h.w, m.w);
  *(ushort4*)(hp + off) = h;
  *(ushort4*)(mp + off) = m;
}

// ---------------- split-bf16 MFMA GEMM: C = A[M,K] * B[N,K]^T -----------------
// 3-term split: hh + hm + mh (mm dropped: |am*bm| ~ 1.6e-5 relative).
// mode 0: dense C store (WO).
// mode 1: in-register top-4 |v| sparsify per (row,head)-vector, dense C store.
// mode 2: sparsify + store transposed into KT[bh][j][t] (K path).
__device__ __forceinline__ void mfma_gemm_core(
    const ushort_t* __restrict__ Ah, const ushort_t* __restrict__ Am,
    const ushort_t* __restrict__ Bh, const ushort_t* __restrict__ Bm,
    float* __restrict__ C, float* __restrict__ KTb,
    const int bm, const int bn, const int mode)
{
  __shared__ ushort_t ldsA[8192];   // [split][128][32]
  __shared__ ushort_t ldsB[8192];
  const int tid  = threadIdx.x;
  const int lane = tid & 63;
  const int w    = tid >> 6;
  const int wm = (w >> 1) << 6;
  const int wn = (w & 1) << 6;
  const int r16 = lane & 15;
  const int q   = lane >> 4;

  const ushort_t* ga[4]; const ushort_t* gb[4]; int dst[4];
#pragma unroll
  for (int r = 0; r < 4; ++r) {
    const int linear = tid + 256 * r;
    const int s   = linear >> 9;
    const int idx = linear & 511;
    const int row = idx >> 2;
    const int kq  = (idx & 3) << 3;
    ga[r] = (s ? Am : Ah) + (size_t)(bm + row) * 1024 + kq;
    gb[r] = (s ? Bm : Bh) + (size_t)(bn + row) * 1024 + kq;
    dst[r] = linear << 3;
  }

  f32x4 acc[4][4];
#pragma unroll
  for (int mt = 0; mt < 4; ++mt)
#pragma unroll
    for (int nt = 0; nt < 4; ++nt) { f32x4 z = {0.f, 0.f, 0.f, 0.f}; acc[mt][nt] = z; }

  for (int k0 = 0; k0 < 1024; k0 += 32) {
    uint4 va0 = *(const uint4*)ga[0]; uint4 va1 = *(const uint4*)ga[1];
    uint4 va2 = *(const uint4*)ga[2]; uint4 va3 = *(const uint4*)ga[3];
    uint4 vb0 = *(const uint4*)gb[0]; uint4 vb1 = *(const uint4*)gb[1];
    uint4 vb2 = *(const uint4*)gb[2]; uint4 vb3 = *(const uint4*)gb[3];
#pragma unroll
    for (int r = 0; r < 4; ++r) { ga[r] += 32; gb[r] += 32; }
    __syncthreads();
    *(uint4*)&ldsA[dst[0]] = va0; *(uint4*)&ldsA[dst[1]] = va1;
    *(uint4*)&ldsA[dst[2]] = va2; *(uint4*)&ldsA[dst[3]] = va3;
    *(uint4*)&ldsB[dst[0]] = vb0; *(uint4*)&ldsB[dst[1]] = vb1;
    *(uint4*)&ldsB[dst[2]] = vb2; *(uint4*)&ldsB[dst[3]] = vb3;
    __syncthreads();

    bf16x8 bf[4][2];
#pragma unroll
    for (int nt = 0; nt < 4; ++nt) {
      bf[nt][0] = *(const bf16x8*)&ldsB[(wn + nt * 16 + r16) * 32 + q * 8];
      bf[nt][1] = *(const bf16x8*)&ldsB[4096 + (wn + nt * 16 + r16) * 32 + q * 8];
    }
#pragma unroll
    for (int mt = 0; mt < 4; ++mt) {
      const bf16x8 ah = *(const bf16x8*)&ldsA[(wm + mt * 16 + r16) * 32 + q * 8];
      const bf16x8 am = *(const bf16x8*)&ldsA[4096 + (wm + mt * 16 + r16) * 32 + q * 8];
#pragma unroll
      for (int nt = 0; nt < 4; ++nt) {
        f32x4 c = acc[mt][nt];
        c = __builtin_amdgcn_mfma_f32_16x16x32_bf16(am, bf[nt][0], c, 0, 0, 0); // mh
        c = __builtin_amdgcn_mfma_f32_16x16x32_bf16(ah, bf[nt][1], c, 0, 0, 0); // hm
        c = __builtin_amdgcn_mfma_f32_16x16x32_bf16(ah, bf[nt][0], c, 0, 0, 0); // hh
        acc[mt][nt] = c;
      }
    }
  }

  if (mode != 0) {
    // in-register top-4 |v| sparsify: tie -> lowest j (matches jax top_k).
#pragma unroll
    for (int it = 0; it < 16; ++it) {
      const int mti = it >> 2, r4i = it & 3;
      int cons = 0;
#pragma unroll
      for (int rnd = 0; rnd < 4; ++rnd) {
        float bv = -1.0f; int bj = 1024;
#pragma unroll
        for (int nt = 0; nt < 4; ++nt) {
          const float av = ((cons >> nt) & 1) ? -1.0f : fabsf(acc[mti][nt][r4i]);
          const int jj = nt * 16 + r16;
          if (av > bv) { bv = av; bj = jj; }
        }
#pragma unroll
        for (int off = 1; off < 16; off <<= 1) {
          const float ov = __shfl_xor(bv, off);
          const int   oj = __shfl_xor(bj, off);
          if (ov > bv || (ov == bv && oj < bj)) { bv = ov; bj = oj; }
        }
        if ((bj & 15) == r16) cons |= 1 << (bj >> 4);
      }
#pragma unroll
      for (int nt = 0; nt < 4; ++nt)
        if (!((cons >> nt) & 1)) acc[mti][nt][r4i] = 0.0f;
    }
  }

  if (mode == 2) {
    // K path: store transposed into KT[bh][j][t]; acc regs are 4 consecutive t
    const int row0 = bm + wm;
    const int b = row0 >> 10;
    const int h = (bn + wn) >> 6;
    float* kb = KTb + ((size_t)(b * 16 + h) << 16);
    const int tb = (row0 & 1023) + q * 4;
#pragma unroll
    for (int mt = 0; mt < 4; ++mt) {
      const int t0 = tb + mt * 16;
#pragma unroll
      for (int nt = 0; nt < 4; ++nt) {
        const int j = nt * 16 + r16;
        *(float4*)(kb + (size_t)j * 1024 + t0) =
            make_float4(acc[mt][nt][0], acc[mt][nt][1], acc[mt][nt][2], acc[mt][nt][3]);
      }
    }
  } else {
#pragma unroll
    for (int mt = 0; mt < 4; ++mt)
#pragma unroll
      for (int nt = 0; nt < 4; ++nt)
#pragma unroll
        for (int r4 = 0; r4 < 4; ++r4)
          C[(size_t)(bm + wm + mt * 16 + q * 4 + r4) * 1024 + (bn + wn + nt * 16 + r16)] =
              acc[mt][nt][r4];
  }
}

// fused Q/K/V + sparsify + K-transpose: grid (24, 32)
__global__ __launch_bounds__(256, 3) void mfma_qkv(
    const ushort_t* __restrict__ xs, const ushort_t* __restrict__ wsb,
    float* __restrict__ qy, float* __restrict__ kt, float* __restrict__ vy)
{
  const int nb = blockIdx.x;
  const int which = nb >> 3;
  float* C = (which == 0) ? qy : vy;       // unused for K (mode 2)
  const int mode = (which == 1) ? 2 : 1;
  const ushort_t* Bh = wsb + (size_t)which * (2u << 20);
  mfma_gemm_core(xs, xs + (1u << 22), Bh, Bh + (1u << 20), C, kt,
                 blockIdx.y * 128, (nb & 7) * 128, mode);
}

__global__ __launch_bounds__(256, 3) void mfma_wo(
    const ushort_t* __restrict__ oys, const ushort_t* __restrict__ wsb,
    float* __restrict__ out)
{
  const ushort_t* Bh = wsb + (size_t)3 * (2u << 20);
  mfma_gemm_core(oys, oys + (1u << 22), Bh, Bh + (1u << 20), out, nullptr,
                 blockIdx.y * 128, blockIdx.x * 128, 0);
}

// ---------------- attention: wave-synchronous, one wave per q-row -----------
__device__ __forceinline__ unsigned mono_key(float f) {
  unsigned b = __float_as_uint(f);
  return (b & 0x80000000u) ? ~b : (b | 0x80000000u);
}

// Wave-local exact rank-select over index-ordered ps[0..cnt) (hi32 = mono
// score, lo32 = k). Selects hi32 > threshold plus first `rem` (array order)
// == threshold; writes packed (expf(s-m), k) at obase into spk.
// Histogram via per-lane LDS atomicAdd (same-wave LDS ops are in-order).
// Early exit when the boundary bin holds exactly `rem` keys: all bin members
// are then selected regardless of lower bits -> prefix-level writer is exact.
__device__ __forceinline__ void wave_radix_sel(
    unsigned long long* ps, int cnt, int target,
    int* hr, unsigned long long* spk, int obase, bool neg, float m,
    int lane)
{
  unsigned pref = 0u; int rem = target; int sstop = 0;
  for (int pass = 0; pass < 4; ++pass) {
    const int shift = 24 - 8 * pass;
    sstop = shift;
    hr[lane] = 0; hr[lane + 64] = 0; hr[lane + 128] = 0; hr[lane + 192] = 0;
    for (int c0 = 0; c0 < cnt; c0 += 64) {
      const int t = c0 + lane;
      bool pt = (t < cnt);
      const unsigned u = pt ? (unsigned)(ps[t] >> 32) : 0u;
      if (pass > 0) pt = pt && ((u >> (shift + 8)) == (pref >> (shift + 8)));
      if (pt) atomicAdd(&hr[(u >> shift) & 255u], 1);
    }
    const int d0 = lane << 2;
    const int c0b = hr[d0], c1b = hr[d0 + 1], c2b = hr[d0 + 2], c3b = hr[d0 + 3];
    const int sum = c0b + c1b + c2b + c3b;
    int S = sum;
#pragma unroll
    for (int off = 1; off < 64; off <<= 1) {
      int t = __shfl_down(S, off);
      if (lane + off < 64) S += t;
    }
    const int above = S - sum;            // keys with digit in higher lanes
    const int cg3 = above;
    const int cg2 = above + c3b;
    const int cg1 = cg2 + c2b;
    const int cg0 = cg1 + c1b;
    const bool f0 = (cg0 < rem && rem <= cg0 + c0b);
    const bool f1 = (cg1 < rem && rem <= cg1 + c1b);
    const bool f2 = (cg2 < rem && rem <= cg2 + c2b);
    const bool f3 = (cg3 < rem && rem <= cg3 + c3b);
    const int fd  = f0 ? d0 : f1 ? (d0 + 1) : f2 ? (d0 + 2) : (d0 + 3);
    const int fcg = f0 ? cg0 : f1 ? cg1 : f2 ? cg2 : cg3;
    const int fcn = f0 ? c0b : f1 ? c1b : f2 ? c2b : c3b;
    unsigned long long fm = __ballot(f0 || f1 || f2 || f3);
    const int src = __ffsll(fm) - 1;
    const int nprefl = (int)(pref | ((unsigned)fd << shift));
    const int nreml = rem - fcg;
    const int done  = (fcn == nreml) ? 1 : 0;
    pref = (unsigned)__shfl(nprefl, src);
    rem  = __shfl(nreml, src);
    if (__shfl(done, src)) break;   // bin == rem: all members selected, exact
  }
  const unsigned phi = pref >> sstop;
  int eqbase = 0, wbase = 0;
  for (int c0 = 0; c0 < cnt; c0 += 64) {
    const int t = c0 + lane;
    const bool valt = (t < cnt);
    const unsigned long long kk = valt ? ps[t] : 0ull;
    const unsigned u = (unsigned)(kk >> 32);
    const unsigned upre = u >> sstop;
    const bool eq = valt && (upre == phi);
    unsigned long long em = __ballot(eq);
    const int eqrank = eqbase + lane_rank(em);
    const bool sf = valt && ((upre > phi) || (eq && eqrank < rem));
    unsigned long long sm = __ballot(sf);
    if (sf) {
      const int pos = wbase + lane_rank(sm);
      const float sv = neg ? __uint_as_float(~u) : __uint_as_float(u & 0x7fffffffu);
      spk[obase + pos] = ((unsigned long long)__float_as_uint(__expf(sv - m)) << 32)
                       | (kk & 0xffffffffull);
    }
    eqbase += (int)__popcll(em);
    wbase  += (int)__popcll(sm);
  }
}

__global__ __launch_bounds__(256) void attn_sparse(
    const float* __restrict__ Qy, const float* __restrict__ KT,
    const float* __restrict__ Vy,
    ushort_t* __restrict__ Oh, ushort_t* __restrict__ Om)
{
  const int bh = blockIdx.y;
  const int b  = bh >> 4;
  const int h  = bh & 15;
  const int tid  = threadIdx.x;
  const int lane = tid & 63;
  const int w    = tid >> 6;
  const int bi   = blockIdx.x;
  // load-balanced row map: per-block total nvalid is constant (2050)
  const int q = (w == 0) ? bi : (w == 1) ? (511 - bi) : (w == 2) ? (512 + bi) : (1023 - bi);

  __shared__ unsigned long long pseg[4][256];
  __shared__ int   zseg[4][64];
  __shared__ unsigned long long selpk[4][64];   // packed (p:f32 hi | k lo)
  __shared__ int   hist[4][256];

  // q nonzeros: ffsll-peel the ballot mask, broadcast values via shfl
  const float qv = Qy[((size_t)(b * TSEQ + q)) * 1024 + h * HD + lane];
  unsigned long long mk = __ballot(qv != 0.0f);
  const int nnz = (int)__popcll(mk);
  unsigned long long mr = mk;
  int i0 = __ffsll(mr) - 1; if (i0 < 0) i0 = 0; mr &= mr - 1;
  int i1 = __ffsll(mr) - 1; if (i1 < 0) i1 = 0; mr &= mr - 1;
  int i2 = __ffsll(mr) - 1; if (i2 < 0) i2 = 0; mr &= mr - 1;
  int i3 = __ffsll(mr) - 1; if (i3 < 0) i3 = 0;
  float v0 = __shfl(qv, i0); if (nnz < 1) v0 = 0.0f;
  float v1 = __shfl(qv, i1); if (nnz < 2) v1 = 0.0f;
  float v2 = __shfl(qv, i2); if (nnz < 3) v2 = 0.0f;
  float v3 = __shfl(qv, i3); if (nnz < 4) v3 = 0.0f;
  const float* ktb = KT + (size_t)bh * HD * TSEQ;
  const float* kr0 = ktb + (size_t)i0 * TSEQ;
  const float* kr1 = ktb + (size_t)i1 * TSEQ;
  const float* kr2 = ktb + (size_t)i2 * TSEQ;
  const float* kr3 = ktb + (size_t)i3 * TSEQ;

  const int nvalid = q + 1;
  int nsel;

  if (nvalid <= 64) {
    const bool val = (lane < nvalid);
    float s = (v0 * kr0[lane] + v1 * kr1[lane] + v2 * kr2[lane] + v3 * kr3[lane]) * 0.125f;
    float mloc = val ? s : -INFINITY;
#pragma unroll
    for (int off = 32; off; off >>= 1) mloc = fmaxf(mloc, __shfl_xor(mloc, off));
    if (val)
      selpk[w][lane] = ((unsigned long long)__float_as_uint(__expf(s - mloc)) << 32)
                     | (unsigned)lane;
    nsel = nvalid;
  } else {
    int cp = 0, cz = 0;
    float mloc = -INFINITY;
    for (int k0 = 0; k0 < nvalid; k0 += 64) {
      const int k = k0 + lane;
      const bool val = (k < nvalid);
      // unguarded loads: worst-case 63 elements past row end stay inside d_ws
      float s = (v0 * kr0[k] + v1 * kr1[k] + v2 * kr2[k] + v3 * kr3[k]) * 0.125f;
      const bool isp = val && (s > 0.0f);
      mloc = val ? fmaxf(mloc, s) : mloc;
      unsigned long long mp = __ballot(isp);
      if (isp)
        pseg[w][cp + lane_rank(mp)] =
            ((unsigned long long)(__float_as_uint(s) | 0x80000000u) << 32) | (unsigned)k;
      cp += (int)__popcll(mp);
      if (cz < 64) {                      // wave-uniform gate; stops once 64 banked
        const bool isz = val && (s == 0.0f);
        unsigned long long mz = __ballot(isz);
        if (isz) { const int o = cz + lane_rank(mz); if (o < 64) zseg[w][o] = k; }
        cz += (int)__popcll(mz);
      }
    }
#pragma unroll
    for (int off = 32; off; off >>= 1) mloc = fmaxf(mloc, __shfl_xor(mloc, off));
    const float m = mloc;
    const bool czfull = (cz >= 64);

    if (cp <= 64 && (czfull || cp + cz >= 64)) {
      // fast path: boundary is exactly +0 (or smallest positive when cp==64)
      if (lane < cp) {
        const unsigned long long kk = pseg[w][lane];
        const float p = __expf(__uint_as_float((unsigned)(kk >> 32) & 0x7fffffffu) - m);
        selpk[w][lane] = ((unsigned long long)__float_as_uint(p) << 32)
                       | (kk & 0xffffffffull);
      }
      const int quota = 64 - cp;
      if (lane < quota)
        selpk[w][cp + lane] = ((unsigned long long)__float_as_uint(__expf(-m)) << 32)
                            | (unsigned)zseg[w][lane];
      nsel = 64;
    } else if (cp > 64) {
      wave_radix_sel(pseg[w], cp, 64, hist[w], selpk[w], 0, false, m, lane);
      nsel = 64;
    } else {
      // rare: boundary dips into negatives (cp + cz < 64; cz exact here)
      if (lane < cp) {
        const unsigned long long kk = pseg[w][lane];
        const float p = __expf(__uint_as_float((unsigned)(kk >> 32) & 0x7fffffffu) - m);
        selpk[w][lane] = ((unsigned long long)__float_as_uint(p) << 32)
                       | (kk & 0xffffffffull);
      }
      if (lane < cz)
        selpk[w][cp + lane] = ((unsigned long long)__float_as_uint(__expf(-m)) << 32)
                            | (unsigned)zseg[w][lane];
      int cn = 0;
      for (int k0 = 0; k0 < nvalid; k0 += 64) {
        const int k = k0 + lane;
        const bool val = (k < nvalid);
        float s = (v0 * kr0[k] + v1 * kr1[k] + v2 * kr2[k] + v3 * kr3[k]) * 0.125f;
        const bool isn = val && (s < 0.0f);
        unsigned long long mn = __ballot(isn);
        if (isn)
          pseg[w][cn + lane_rank(mn)] =
              ((unsigned long long)mono_key(s) << 32) | (unsigned)k;
        cn += (int)__popcll(mn);
      }
      wave_radix_sel(pseg[w], cn, 64 - cp - cz, hist[w], selpk[w],
                     cp + cz, true, m, lane);
      nsel = 64;
    }
  }

  const unsigned long long eL = (lane < nsel) ? selpk[w][lane] : 0ull;
  float Zp = (lane < nsel) ? __uint_as_float((unsigned)(eL >> 32)) : 0.0f;
#pragma unroll
  for (int off = 32; off; off >>= 1) Zp += __shfl_xor(Zp, off);
  const float Z = Zp;

  float acc = 0.0f;
  const float* vb = Vy + ((size_t)b * TSEQ) * 1024 + h * HD + lane;
  int s2 = 0;
  for (; s2 + 4 <= nsel; s2 += 4) {
    const unsigned long long e0 = selpk[w][s2],     e1 = selpk[w][s2 + 1];
    const unsigned long long e2 = selpk[w][s2 + 2], e3 = selpk[w][s2 + 3];
    acc += __uint_as_float((unsigned)(e0 >> 32)) * vb[(size_t)(unsigned)(e0 & 0xffffffffull) * 1024]
         + __uint_as_float((unsigned)(e1 >> 32)) * vb[(size_t)(unsigned)(e1 & 0xffffffffull) * 1024]
         + __uint_as_float((unsigned)(e2 >> 32)) * vb[(size_t)(unsigned)(e2 & 0xffffffffull) * 1024]
         + __uint_as_float((unsigned)(e3 >> 32)) * vb[(size_t)(unsigned)(e3 & 0xffffffffull) * 1024];
  }
  for (; s2 < nsel; ++s2) {
    const unsigned long long e = selpk[w][s2];
    acc += __uint_as_float((unsigned)(e >> 32)) * vb[(size_t)(unsigned)(e & 0xffffffffull) * 1024];
  }
  const float r = acc / Z;
  unsigned short rh, rm;
  split2(r, rh, rm);
  const size_t oidx = ((size_t)(b * TSEQ + q)) * 1024 + h * HD + lane;
  Oh[oidx] = rh;
  Om[oidx] = rm;
}

// ---------------- launch -----------------------------------------------------
extern "C" void kernel_launch(void* const* d_in, const int* in_sizes, int n_in,
                              void* d_out, int out_size, void* d_ws, size_t ws_size,
                              hipStream_t stream) {
  (void)in_sizes; (void)n_in; (void)out_size; (void)ws_size;
  const float* x  = (const float*)d_in[0];
  const float* wq = (const float*)d_in[1];
  const float* wk = (const float*)d_in[2];
  const float* wv = (const float*)d_in[3];
  const float* wo = (const float*)d_in[4];
  float* out = (float*)d_out;

  float* ws = (float*)d_ws;
  const size_t SZ = (size_t)4096 * 1024;   // 4M floats = 16MB per buffer
  float* qy  = ws;
  float* vy  = ws + 2 * SZ;
  float* kt  = ws + 3 * SZ;
  ushort_t* xs  = (ushort_t*)(ws + 4 * SZ);   // 8M ushorts (x hi|mid)
  ushort_t* wsb = (ushort_t*)(ws + 5 * SZ);   // 8M ushorts (4 x (hi|mid))
  ushort_t* oys = xs;                         // xs dead after mfma_qkv

  conv_split<<<8192, 256, 0, stream>>>(x, wq, wk, wv, wo, xs, wsb);

  // QKV GEMM + in-register top-4 sparsify + direct transposed K write
  mfma_qkv<<<dim3(24, 32), 256, 0, stream>>>(xs, wsb, qy, kt, vy);

  attn_sparse<<<dim3(TSEQ / 4, 64), 256, 0, stream>>>(qy, kt, vy,
                                                      oys, oys + (1u << 22));

  mfma_wo<<<dim3(8, 32), 256, 0, stream>>>(oys, wsb, out);
}

// Round 12
// 343.561 us; speedup vs baseline: 2.9783x; 1.0118x over previous
//
#include <hip/hip_runtime.h>
#include <math.h>

#define TSEQ 1024
#define NH 16
#define HD 64

typedef short bf16x8 __attribute__((ext_vector_type(8)));
typedef float f32x4  __attribute__((ext_vector_type(4)));
typedef unsigned short ushort_t;
typedef unsigned long long ull_t;

__device__ __forceinline__ int lane_rank(unsigned long long m) {
  return __builtin_amdgcn_mbcnt_hi((unsigned)(m >> 32),
         __builtin_amdgcn_mbcnt_lo((unsigned)m, 0u));
}

// async global->LDS, 16B per lane; LDS dest must be wave-uniform base + lane*16
__device__ __forceinline__ void async_ld16(const ushort_t* gsrc, ushort_t* ldst) {
  __builtin_amdgcn_global_load_lds(
      (const __attribute__((address_space(1))) unsigned int*)gsrc,
      (__attribute__((address_space(3))) unsigned int*)ldst,
      16, 0, 0);
}

// ---------------- fp32 -> (hi, mid) bf16 split --------------------------------
__device__ __forceinline__ unsigned short rne_bf16(float a) {
  unsigned u = __float_as_uint(a);
  return (unsigned short)((u + 0x7fffu + ((u >> 16) & 1u)) >> 16);
}
__device__ __forceinline__ void split2(float a, unsigned short& h, unsigned short& m) {
  h = rne_bf16(a);
  float hf = __uint_as_float(((unsigned)h) << 16);
  m = rne_bf16(a - hf);
}

// fused conversion of x (4M) + wq/wk/wv/wo (1M each) into split buffers
__global__ __launch_bounds__(256) void conv_split(
    const float* __restrict__ x,
    const float* __restrict__ wq, const float* __restrict__ wk,
    const float* __restrict__ wv, const float* __restrict__ wo,
    ushort_t* __restrict__ xs, ushort_t* __restrict__ wsb)
{
  const int e = (blockIdx.x * 256 + threadIdx.x) * 4;
  const float* src; ushort_t *hp, *mp; int off;
  if (e < (1 << 22)) {
    src = x; off = e; hp = xs; mp = xs + (1u << 22);
  } else {
    int j = e - (1 << 22);
    int mat = j >> 20; off = j & ((1 << 20) - 1);
    src = (mat == 0) ? wq : (mat == 1) ? wk : (mat == 2) ? wv : wo;
    hp = wsb + (size_t)mat * (2u << 20); mp = hp + (1u << 20);
  }
  float4 v = *(const float4*)(src + off);
  ushort4 h, m;
  split2(v.x, h.x, m.x); split2(v.y, h.y, m.y);
  split2(v.z, h.z, m.z); split2(v.w, h.w, m.w);
  *(ushort4*)(hp + off) = h;
  *(ushort4*)(mp + off) = m;
}

// ---------------- split-bf16 MFMA GEMM: C = A[M,K] * B[N,K]^T -----------------
// 3-term split: hh + hm + mh (mm dropped: |am*bm| ~ 1.6e-5 relative).
// Staging via global_load_lds width=16 (async DMA, no VGPR round-trip).
// mode 0: dense C store (WO).
// mode 1: in-register top-4 |v| sparsify per (row,head)-vector, dense C store.
// mode 2: sparsify + store transposed into KT[bh][j][t] (K path).
__device__ __forceinline__ void mfma_gemm_core(
    const ushort_t* __restrict__ Ah, const ushort_t* __restrict__ Am,
    const ushort_t* __restrict__ Bh, const ushort_t* __restrict__ Bm,
    float* __restrict__ C, float* __restrict__ KTb,
    const int bm, const int bn, const int mode)
{
  __shared__ ushort_t ldsA[8192];   // [split][128][32]
  __shared__ ushort_t ldsB[8192];
  const int tid  = threadIdx.x;
  const int lane = tid & 63;
  const int w    = tid >> 6;
  const int wm = (w >> 1) << 6;
  const int wn = (w & 1) << 6;
  const int r16 = lane & 15;
  const int q   = lane >> 4;

  // per-lane global srcs; LDS dst = wave-uniform base + lane*16B (8 ushorts)
  const ushort_t* ga[4]; const ushort_t* gb[4]; int dst[4];
#pragma unroll
  for (int r = 0; r < 4; ++r) {
    const int linear = tid + 256 * r;
    const int s   = linear >> 9;
    const int idx = linear & 511;
    const int row = idx >> 2;
    const int kq  = (idx & 3) << 3;
    ga[r] = (s ? Am : Ah) + (size_t)(bm + row) * 1024 + kq;
    gb[r] = (s ? Bm : Bh) + (size_t)(bn + row) * 1024 + kq;
    dst[r] = linear << 3;
  }

  f32x4 acc[4][4];
#pragma unroll
  for (int mt = 0; mt < 4; ++mt)
#pragma unroll
    for (int nt = 0; nt < 4; ++nt) { f32x4 z = {0.f, 0.f, 0.f, 0.f}; acc[mt][nt] = z; }

  for (int k0 = 0; k0 < 1024; k0 += 32) {
    __syncthreads();                 // previous iter's LDS reads complete
#pragma unroll
    for (int r = 0; r < 4; ++r) {
      async_ld16(ga[r], &ldsA[dst[r]]);
      async_ld16(gb[r], &ldsB[dst[r]]);
      ga[r] += 32; gb[r] += 32;
    }
    __syncthreads();                 // implicit vmcnt(0) drains the DMA

    bf16x8 bf[4][2];
#pragma unroll
    for (int nt = 0; nt < 4; ++nt) {
      bf[nt][0] = *(const bf16x8*)&ldsB[(wn + nt * 16 + r16) * 32 + q * 8];
      bf[nt][1] = *(const bf16x8*)&ldsB[4096 + (wn + nt * 16 + r16) * 32 + q * 8];
    }
#pragma unroll
    for (int mt = 0; mt < 4; ++mt) {
      const bf16x8 ah = *(const bf16x8*)&ldsA[(wm + mt * 16 + r16) * 32 + q * 8];
      const bf16x8 am = *(const bf16x8*)&ldsA[4096 + (wm + mt * 16 + r16) * 32 + q * 8];
#pragma unroll
      for (int nt = 0; nt < 4; ++nt) {
        f32x4 c = acc[mt][nt];
        c = __builtin_amdgcn_mfma_f32_16x16x32_bf16(am, bf[nt][0], c, 0, 0, 0); // mh
        c = __builtin_amdgcn_mfma_f32_16x16x32_bf16(ah, bf[nt][1], c, 0, 0, 0); // hm
        c = __builtin_amdgcn_mfma_f32_16x16x32_bf16(ah, bf[nt][0], c, 0, 0, 0); // hh
        acc[mt][nt] = c;
      }
    }
  }

  if (mode != 0) {
    // in-register top-4 |v| sparsify: tie -> lowest j (matches jax top_k).
#pragma unroll
    for (int it = 0; it < 16; ++it) {
      const int mti = it >> 2, r4i = it & 3;
      int cons = 0;
#pragma unroll
      for (int rnd = 0; rnd < 4; ++rnd) {
        float bv = -1.0f; int bj = 1024;
#pragma unroll
        for (int nt = 0; nt < 4; ++nt) {
          const float av = ((cons >> nt) & 1) ? -1.0f : fabsf(acc[mti][nt][r4i]);
          const int jj = nt * 16 + r16;
          if (av > bv) { bv = av; bj = jj; }
        }
#pragma unroll
        for (int off = 1; off < 16; off <<= 1) {
          const float ov = __shfl_xor(bv, off);
          const int   oj = __shfl_xor(bj, off);
          if (ov > bv || (ov == bv && oj < bj)) { bv = ov; bj = oj; }
        }
        if ((bj & 15) == r16) cons |= 1 << (bj >> 4);
      }
#pragma unroll
      for (int nt = 0; nt < 4; ++nt)
        if (!((cons >> nt) & 1)) acc[mti][nt][r4i] = 0.0f;
    }
  }

  if (mode == 2) {
    // K path: store transposed into KT[bh][j][t]; acc regs are 4 consecutive t
    const int row0 = bm + wm;
    const int b = row0 >> 10;
    const int h = (bn + wn) >> 6;
    float* kb = KTb + ((size_t)(b * 16 + h) << 16);
    const int tb = (row0 & 1023) + q * 4;
#pragma unroll
    for (int mt = 0; mt < 4; ++mt) {
      const int t0 = tb + mt * 16;
#pragma unroll
      for (int nt = 0; nt < 4; ++nt) {
        const int j = nt * 16 + r16;
        *(float4*)(kb + (size_t)j * 1024 + t0) =
            make_float4(acc[mt][nt][0], acc[mt][nt][1], acc[mt][nt][2], acc[mt][nt][3]);
      }
    }
  } else {
#pragma unroll
    for (int mt = 0; mt < 4; ++mt)
#pragma unroll
      for (int nt = 0; nt < 4; ++nt)
#pragma unroll
        for (int r4 = 0; r4 < 4; ++r4)
          C[(size_t)(bm + wm + mt * 16 + q * 4 + r4) * 1024 + (bn + wn + nt * 16 + r16)] =
              acc[mt][nt][r4];
  }
}

// fused Q/K/V + sparsify + K-transpose: grid (24, 32)
__global__ __launch_bounds__(256, 3) void mfma_qkv(
    const ushort_t* __restrict__ xs, const ushort_t* __restrict__ wsb,
    float* __restrict__ qy, float* __restrict__ kt, float* __restrict__ vy)
{
  const int nb = blockIdx.x;
  const int which = nb >> 3;
  float* C = (which == 0) ? qy : vy;       // unused for K (mode 2)
  const int mode = (which == 1) ? 2 : 1;
  const ushort_t* Bh = wsb + (size_t)which * (2u << 20);
  mfma_gemm_core(xs, xs + (1u << 22), Bh, Bh + (1u << 20), C, kt,
                 blockIdx.y * 128, (nb & 7) * 128, mode);
}

__global__ __launch_bounds__(256, 3) void mfma_wo(
    const ushort_t* __restrict__ oys, const ushort_t* __restrict__ wsb,
    float* __restrict__ out)
{
  const ushort_t* Bh = wsb + (size_t)3 * (2u << 20);
  mfma_gemm_core(oys, oys + (1u << 22), Bh, Bh + (1u << 20), out, nullptr,
                 blockIdx.y * 128, blockIdx.x * 128, 0);
}

// ---------------- attention: wave-synchronous, one wave per q-row -----------
__device__ __forceinline__ unsigned mono_key(float f) {
  unsigned b = __float_as_uint(f);
  return (b & 0x80000000u) ? ~b : (b | 0x80000000u);
}

// Wave-local exact rank-select over index-ordered ps[0..cnt) (hi32 = mono
// score, lo32 = k). Selects hi32 > threshold plus first `rem` (array order)
// == threshold; writes packed (expf(s-m), k) at obase into spk.
// Early exit when the boundary bin holds exactly `rem` keys.
__device__ __forceinline__ void wave_radix_sel(
    unsigned long long* ps, int cnt, int target,
    int* hr, unsigned long long* spk, int obase, bool neg, float m,
    int lane)
{
  unsigned pref = 0u; int rem = target; int sstop = 0;
  for (int pass = 0; pass < 4; ++pass) {
    const int shift = 24 - 8 * pass;
    sstop = shift;
    hr[lane] = 0; hr[lane + 64] = 0; hr[lane + 128] = 0; hr[lane + 192] = 0;
    for (int c0 = 0; c0 < cnt; c0 += 64) {
      const int t = c0 + lane;
      bool pt = (t < cnt);
      const unsigned u = pt ? (unsigned)(ps[t] >> 32) : 0u;
      if (pass > 0) pt = pt && ((u >> (shift + 8)) == (pref >> (shift + 8)));
      if (pt) atomicAdd(&hr[(u >> shift) & 255u], 1);
    }
    const int d0 = lane << 2;
    const int c0b = hr[d0], c1b = hr[d0 + 1], c2b = hr[d0 + 2], c3b = hr[d0 + 3];
    const int sum = c0b + c1b + c2b + c3b;
    int S = sum;
#pragma unroll
    for (int off = 1; off < 64; off <<= 1) {
      int t = __shfl_down(S, off);
      if (lane + off < 64) S += t;
    }
    const int above = S - sum;            // keys with digit in higher lanes
    const int cg3 = above;
    const int cg2 = above + c3b;
    const int cg1 = cg2 + c2b;
    const int cg0 = cg1 + c1b;
    const bool f0 = (cg0 < rem && rem <= cg0 + c0b);
    const bool f1 = (cg1 < rem && rem <= cg1 + c1b);
    const bool f2 = (cg2 < rem && rem <= cg2 + c2b);
    const bool f3 = (cg3 < rem && rem <= cg3 + c3b);
    const int fd  = f0 ? d0 : f1 ? (d0 + 1) : f2 ? (d0 + 2) : (d0 + 3);
    const int fcg = f0 ? cg0 : f1 ? cg1 : f2 ? cg2 : cg3;
    const int fcn = f0 ? c0b : f1 ? c1b : f2 ? c2b : c3b;
    unsigned long long fm = __ballot(f0 || f1 || f2 || f3);
    const int src = __ffsll(fm) - 1;
    const int nprefl = (int)(pref | ((unsigned)fd << shift));
    const int nreml = rem - fcg;
    const int done  = (fcn == nreml) ? 1 : 0;
    pref = (unsigned)__shfl(nprefl, src);
    rem  = __shfl(nreml, src);
    if (__shfl(done, src)) break;   // bin == rem: all members selected, exact
  }
  const unsigned phi = pref >> sstop;
  int eqbase = 0, wbase = 0;
  for (int c0 = 0; c0 < cnt; c0 += 64) {
    const int t = c0 + lane;
    const bool valt = (t < cnt);
    const unsigned long long kk = valt ? ps[t] : 0ull;
    const unsigned u = (unsigned)(kk >> 32);
    const unsigned upre = u >> sstop;
    const bool eq = valt && (upre == phi);
    unsigned long long em = __ballot(eq);
    const int eqrank = eqbase + lane_rank(em);
    const bool sf = valt && ((upre > phi) || (eq && eqrank < rem));
    unsigned long long sm = __ballot(sf);
    if (sf) {
      const int pos = wbase + lane_rank(sm);
      const float sv = neg ? __uint_as_float(~u) : __uint_as_float(u & 0x7fffffffu);
      spk[obase + pos] = ((unsigned long long)__float_as_uint(__expf(sv - m)) << 32)
                       | (kk & 0xffffffffull);
    }
    eqbase += (int)__popcll(em);
    wbase  += (int)__popcll(sm);
  }
}

__global__ __launch_bounds__(256) void attn_sparse(
    const float* __restrict__ Qy, const float* __restrict__ KT,
    const float* __restrict__ Vy,
    ushort_t* __restrict__ Oh, ushort_t* __restrict__ Om)
{
  const int bh = blockIdx.y;
  const int b  = bh >> 4;
  const int h  = bh & 15;
  const int tid  = threadIdx.x;
  const int lane = tid & 63;
  const int w    = tid >> 6;
  const int bi   = blockIdx.x;
  // load-balanced row map: per-block total nvalid is constant (2050)
  const int q = (w == 0) ? bi : (w == 1) ? (511 - bi) : (w == 2) ? (512 + bi) : (1023 - bi);

  __shared__ unsigned long long pseg[4][256];
  __shared__ int   zseg[4][64];
  __shared__ unsigned long long selpk[4][64];   // packed (p:f32 hi | k lo)
  __shared__ int   hist[4][256];

  // q nonzeros: ffsll-peel the ballot mask, broadcast values via shfl
  const float qv = Qy[((size_t)(b * TSEQ + q)) * 1024 + h * HD + lane];
  unsigned long long mk = __ballot(qv != 0.0f);
  const int nnz = (int)__popcll(mk);
  unsigned long long mr = mk;
  int i0 = __ffsll(mr) - 1; if (i0 < 0) i0 = 0; mr &= mr - 1;
  int i1 = __ffsll(mr) - 1; if (i1 < 0) i1 = 0; mr &= mr - 1;
  int i2 = __ffsll(mr) - 1; if (i2 < 0) i2 = 0; mr &= mr - 1;
  int i3 = __ffsll(mr) - 1; if (i3 < 0) i3 = 0;
  float v0 = __shfl(qv, i0); if (nnz < 1) v0 = 0.0f;
  float v1 = __shfl(qv, i1); if (nnz < 2) v1 = 0.0f;
  float v2 = __shfl(qv, i2); if (nnz < 3) v2 = 0.0f;
  float v3 = __shfl(qv, i3); if (nnz < 4) v3 = 0.0f;
  const float* ktb = KT + (size_t)bh * HD * TSEQ;
  const float* kr0 = ktb + (size_t)i0 * TSEQ;
  const float* kr1 = ktb + (size_t)i1 * TSEQ;
  const float* kr2 = ktb + (size_t)i2 * TSEQ;
  const float* kr3 = ktb + (size_t)i3 * TSEQ;

  const int nvalid = q + 1;
  int nsel;

  if (nvalid <= 64) {
    const bool val = (lane < nvalid);
    float s = (v0 * kr0[lane] + v1 * kr1[lane] + v2 * kr2[lane] + v3 * kr3[lane]) * 0.125f;
    float mloc = val ? s : -INFINITY;
#pragma unroll
    for (int off = 32; off; off >>= 1) mloc = fmaxf(mloc, __shfl_xor(mloc, off));
    if (val)
      selpk[w][lane] = ((unsigned long long)__float_as_uint(__expf(s - mloc)) << 32)
                     | (unsigned)lane;
    nsel = nvalid;
  } else {
    int cp = 0, cz = 0;
    float mloc = -INFINITY;
    for (int k0 = 0; k0 < nvalid; k0 += 64) {
      const int k = k0 + lane;
      const bool val = (k < nvalid);
      // unguarded loads: worst-case 63 elements past row end stay inside d_ws
      float s = (v0 * kr0[k] + v1 * kr1[k] + v2 * kr2[k] + v3 * kr3[k]) * 0.125f;
      const bool isp = val && (s > 0.0f);
      mloc = val ? fmaxf(mloc, s) : mloc;
      unsigned long long mp = __ballot(isp);
      if (isp)
        pseg[w][cp + lane_rank(mp)] =
            ((unsigned long long)(__float_as_uint(s) | 0x80000000u) << 32) | (unsigned)k;
      cp += (int)__popcll(mp);
      if (cz < 64) {                      // wave-uniform gate; stops once 64 banked
        const bool isz = val && (s == 0.0f);
        unsigned long long mz = __ballot(isz);
        if (isz) { const int o = cz + lane_rank(mz); if (o < 64) zseg[w][o] = k; }
        cz += (int)__popcll(mz);
      }
    }
#pragma unroll
    for (int off = 32; off; off >>= 1) mloc = fmaxf(mloc, __shfl_xor(mloc, off));
    const float m = mloc;
    const bool czfull = (cz >= 64);

    if (cp <= 64 && (czfull || cp + cz >= 64)) {
      // fast path: boundary is exactly +0 (or smallest positive when cp==64)
      if (lane < cp) {
        const unsigned long long kk = pseg[w][lane];
        const float p = __expf(__uint_as_float((unsigned)(kk >> 32) & 0x7fffffffu) - m);
        selpk[w][lane] = ((unsigned long long)__float_as_uint(p) << 32)
                       | (kk & 0xffffffffull);
      }
      const int quota = 64 - cp;
      if (lane < quota)
        selpk[w][cp + lane] = ((unsigned long long)__float_as_uint(__expf(-m)) << 32)
                            | (unsigned)zseg[w][lane];
      nsel = 64;
    } else if (cp > 64) {
      wave_radix_sel(pseg[w], cp, 64, hist[w], selpk[w], 0, false, m, lane);
      nsel = 64;
    } else {
      // rare: boundary dips into negatives (cp + cz < 64; cz exact here)
      if (lane < cp) {
        const unsigned long long kk = pseg[w][lane];
        const float p = __expf(__uint_as_float((unsigned)(kk >> 32) & 0x7fffffffu) - m);
        selpk[w][lane] = ((unsigned long long)__float_as_uint(p) << 32)
                       | (kk & 0xffffffffull);
      }
      if (lane < cz)
        selpk[w][cp + lane] = ((unsigned long long)__float_as_uint(__expf(-m)) << 32)
                            | (unsigned)zseg[w][lane];
      int cn = 0;
      for (int k0 = 0; k0 < nvalid; k0 += 64) {
        const int k = k0 + lane;
        const bool val = (k < nvalid);
        float s = (v0 * kr0[k] + v1 * kr1[k] + v2 * kr2[k] + v3 * kr3[k]) * 0.125f;
        const bool isn = val && (s < 0.0f);
        unsigned long long mn = __ballot(isn);
        if (isn)
          pseg[w][cn + lane_rank(mn)] =
              ((unsigned long long)mono_key(s) << 32) | (unsigned)k;
        cn += (int)__popcll(mn);
      }
      wave_radix_sel(pseg[w], cn, 64 - cp - cz, hist[w], selpk[w],
                     cp + cz, true, m, lane);
      nsel = 64;
    }
  }

  const unsigned long long eL = (lane < nsel) ? selpk[w][lane] : 0ull;
  float Zp = (lane < nsel) ? __uint_as_float((unsigned)(eL >> 32)) : 0.0f;
#pragma unroll
  for (int off = 32; off; off >>= 1) Zp += __shfl_xor(Zp, off);
  const float Z = Zp;

  float acc = 0.0f;
  const float* vb = Vy + ((size_t)b * TSEQ) * 1024 + h * HD + lane;
  int s2 = 0;
  for (; s2 + 4 <= nsel; s2 += 4) {
    const unsigned long long e0 = selpk[w][s2],     e1 = selpk[w][s2 + 1];
    const unsigned long long e2 = selpk[w][s2 + 2], e3 = selpk[w][s2 + 3];
    acc += __uint_as_float((unsigned)(e0 >> 32)) * vb[(size_t)(unsigned)(e0 & 0xffffffffull) * 1024]
         + __uint_as_float((unsigned)(e1 >> 32)) * vb[(size_t)(unsigned)(e1 & 0xffffffffull) * 1024]
         + __uint_as_float((unsigned)(e2 >> 32)) * vb[(size_t)(unsigned)(e2 & 0xffffffffull) * 1024]
         + __uint_as_float((unsigned)(e3 >> 32)) * vb[(size_t)(unsigned)(e3 & 0xffffffffull) * 1024];
  }
  for (; s2 < nsel; ++s2) {
    const unsigned long long e = selpk[w][s2];
    acc += __uint_as_float((unsigned)(e >> 32)) * vb[(size_t)(unsigned)(e & 0xffffffffull) * 1024];
  }
  const float r = acc / Z;
  unsigned short rh, rm;
  split2(r, rh, rm);
  const size_t oidx = ((size_t)(b * TSEQ + q)) * 1024 + h * HD + lane;
  Oh[oidx] = rh;
  Om[oidx] = rm;
}

// ---------------- launch -----------------------------------------------------
extern "C" void kernel_launch(void* const* d_in, const int* in_sizes, int n_in,
                              void* d_out, int out_size, void* d_ws, size_t ws_size,
                              hipStream_t stream) {
  (void)in_sizes; (void)n_in; (void)out_size; (void)ws_size;
  const float* x  = (const float*)d_in[0];
  const float* wq = (const float*)d_in[1];
  const float* wk = (const float*)d_in[2];
  const float* wv = (const float*)d_in[3];
  const float* wo = (const float*)d_in[4];
  float* out = (float*)d_out;

  float* ws = (float*)d_ws;
  const size_t SZ = (size_t)4096 * 1024;   // 4M floats = 16MB per buffer
  float* qy  = ws;
  float* vy  = ws + 2 * SZ;
  float* kt  = ws + 3 * SZ;
  ushort_t* xs  = (ushort_t*)(ws + 4 * SZ);   // 8M ushorts (x hi|mid)
  ushort_t* wsb = (ushort_t*)(ws + 5 * SZ);   // 8M ushorts (4 x (hi|mid))
  ushort_t* oys = xs;                         // xs dead after mfma_qkv

  conv_split<<<8192, 256, 0, stream>>>(x, wq, wk, wv, wo, xs, wsb);

  // QKV GEMM + in-register top-4 sparsify + direct transposed K write
  mfma_qkv<<<dim3(24, 32), 256, 0, stream>>>(xs, wsb, qy, kt, vy);

  attn_sparse<<<dim3(TSEQ / 4, 64), 256, 0, stream>>>(qy, kt, vy,
                                                      oys, oys + (1u << 22));

  mfma_wo<<<dim3(8, 32), 256, 0, stream>>>(oys, wsb, out);
}

// Round 13
// 325.359 us; speedup vs baseline: 3.1449x; 1.0559x over previous
//
#include <hip/hip_runtime.h>
#include <math.h>

#define TSEQ 1024
#define NH 16
#define HD 64

typedef short bf16x8 __attribute__((ext_vector_type(8)));
typedef float f32x4  __attribute__((ext_vector_type(4)));
typedef unsigned short ushort_t;
typedef unsigned long long ull_t;

__device__ __forceinline__ int lane_rank(unsigned long long m) {
  return __builtin_amdgcn_mbcnt_hi((unsigned)(m >> 32),
         __builtin_amdgcn_mbcnt_lo((unsigned)m, 0u));
}

// async global->LDS, 16B per lane; LDS dest must be wave-uniform base + lane*16
__device__ __forceinline__ void async_ld16(const ushort_t* gsrc, ushort_t* ldst) {
  __builtin_amdgcn_global_load_lds(
      (const __attribute__((address_space(1))) unsigned int*)gsrc,
      (__attribute__((address_space(3))) unsigned int*)ldst,
      16, 0, 0);
}

// ---------------- fp32 -> (hi, mid) bf16 split --------------------------------
__device__ __forceinline__ unsigned short rne_bf16(float a) {
  unsigned u = __float_as_uint(a);
  return (unsigned short)((u + 0x7fffu + ((u >> 16) & 1u)) >> 16);
}
__device__ __forceinline__ void split2(float a, unsigned short& h, unsigned short& m) {
  h = rne_bf16(a);
  float hf = __uint_as_float(((unsigned)h) << 16);
  m = rne_bf16(a - hf);
}

// fused conversion of x (4M) + wq/wk/wv/wo (1M each) into split buffers
__global__ __launch_bounds__(256) void conv_split(
    const float* __restrict__ x,
    const float* __restrict__ wq, const float* __restrict__ wk,
    const float* __restrict__ wv, const float* __restrict__ wo,
    ushort_t* __restrict__ xs, ushort_t* __restrict__ wsb)
{
  const int e = (blockIdx.x * 256 + threadIdx.x) * 4;
  const float* src; ushort_t *hp, *mp; int off;
  if (e < (1 << 22)) {
    src = x; off = e; hp = xs; mp = xs + (1u << 22);
  } else {
    int j = e - (1 << 22);
    int mat = j >> 20; off = j & ((1 << 20) - 1);
    src = (mat == 0) ? wq : (mat == 1) ? wk : (mat == 2) ? wv : wo;
    hp = wsb + (size_t)mat * (2u << 20); mp = hp + (1u << 20);
  }
  float4 v = *(const float4*)(src + off);
  ushort4 h, m;
  split2(v.x, h.x, m.x); split2(v.y, h.y, m.y);
  split2(v.z, h.z, m.z); split2(v.w, h.w, m.w);
  *(ushort4*)(hp + off) = h;
  *(ushort4*)(mp + off) = m;
}

// ---------------- split-bf16 MFMA GEMM: C = A[M,K] * B[N,K]^T -----------------
// 3-term split: hh + hm + mh (mm dropped: |am*bm| ~ 1.6e-5 relative).
// Staging via global_load_lds width=16 (async DMA, no VGPR round-trip).
// mode 0: dense C store (WO).
// mode 1: in-register top-4 |v| sparsify per (row,head)-vector, dense C store.
// mode 2: sparsify + store transposed into KT[bh][j][t] (K path).
__device__ __forceinline__ void mfma_gemm_core(
    const ushort_t* __restrict__ Ah, const ushort_t* __restrict__ Am,
    const ushort_t* __restrict__ Bh, const ushort_t* __restrict__ Bm,
    float* __restrict__ C, float* __restrict__ KTb,
    const int bm, const int bn, const int mode)
{
  __shared__ ushort_t ldsA[8192];   // [split][128][32]
  __shared__ ushort_t ldsB[8192];
  const int tid  = threadIdx.x;
  const int lane = tid & 63;
  const int w    = tid >> 6;
  const int wm = (w >> 1) << 6;
  const int wn = (w & 1) << 6;
  const int r16 = lane & 15;
  const int q   = lane >> 4;

  // per-lane global srcs; LDS dst = wave-uniform base + lane*16B (8 ushorts)
  const ushort_t* ga[4]; const ushort_t* gb[4]; int dst[4];
#pragma unroll
  for (int r = 0; r < 4; ++r) {
    const int linear = tid + 256 * r;
    const int s   = linear >> 9;
    const int idx = linear & 511;
    const int row = idx >> 2;
    const int kq  = (idx & 3) << 3;
    ga[r] = (s ? Am : Ah) + (size_t)(bm + row) * 1024 + kq;
    gb[r] = (s ? Bm : Bh) + (size_t)(bn + row) * 1024 + kq;
    dst[r] = linear << 3;
  }

  f32x4 acc[4][4];
#pragma unroll
  for (int mt = 0; mt < 4; ++mt)
#pragma unroll
    for (int nt = 0; nt < 4; ++nt) { f32x4 z = {0.f, 0.f, 0.f, 0.f}; acc[mt][nt] = z; }

  for (int k0 = 0; k0 < 1024; k0 += 32) {
    __syncthreads();                 // previous iter's LDS reads complete
#pragma unroll
    for (int r = 0; r < 4; ++r) {
      async_ld16(ga[r], &ldsA[dst[r]]);
      async_ld16(gb[r], &ldsB[dst[r]]);
      ga[r] += 32; gb[r] += 32;
    }
    __syncthreads();                 // implicit vmcnt(0) drains the DMA

    bf16x8 bf[4][2];
#pragma unroll
    for (int nt = 0; nt < 4; ++nt) {
      bf[nt][0] = *(const bf16x8*)&ldsB[(wn + nt * 16 + r16) * 32 + q * 8];
      bf[nt][1] = *(const bf16x8*)&ldsB[4096 + (wn + nt * 16 + r16) * 32 + q * 8];
    }
#pragma unroll
    for (int mt = 0; mt < 4; ++mt) {
      const bf16x8 ah = *(const bf16x8*)&ldsA[(wm + mt * 16 + r16) * 32 + q * 8];
      const bf16x8 am = *(const bf16x8*)&ldsA[4096 + (wm + mt * 16 + r16) * 32 + q * 8];
#pragma unroll
      for (int nt = 0; nt < 4; ++nt) {
        f32x4 c = acc[mt][nt];
        c = __builtin_amdgcn_mfma_f32_16x16x32_bf16(am, bf[nt][0], c, 0, 0, 0); // mh
        c = __builtin_amdgcn_mfma_f32_16x16x32_bf16(ah, bf[nt][1], c, 0, 0, 0); // hm
        c = __builtin_amdgcn_mfma_f32_16x16x32_bf16(ah, bf[nt][0], c, 0, 0, 0); // hh
        acc[mt][nt] = c;
      }
    }
  }

  if (mode != 0) {
    // in-register top-4 |v| sparsify: tie -> lowest j (matches jax top_k).
#pragma unroll
    for (int it = 0; it < 16; ++it) {
      const int mti = it >> 2, r4i = it & 3;
      int cons = 0;
#pragma unroll
      for (int rnd = 0; rnd < 4; ++rnd) {
        float bv = -1.0f; int bj = 1024;
#pragma unroll
        for (int nt = 0; nt < 4; ++nt) {
          const float av = ((cons >> nt) & 1) ? -1.0f : fabsf(acc[mti][nt][r4i]);
          const int jj = nt * 16 + r16;
          if (av > bv) { bv = av; bj = jj; }
        }
#pragma unroll
        for (int off = 1; off < 16; off <<= 1) {
          const float ov = __shfl_xor(bv, off);
          const int   oj = __shfl_xor(bj, off);
          if (ov > bv || (ov == bv && oj < bj)) { bv = ov; bj = oj; }
        }
        if ((bj & 15) == r16) cons |= 1 << (bj >> 4);
      }
#pragma unroll
      for (int nt = 0; nt < 4; ++nt)
        if (!((cons >> nt) & 1)) acc[mti][nt][r4i] = 0.0f;
    }
  }

  if (mode == 2) {
    // K path: store transposed into KT[bh][j][t]; acc regs are 4 consecutive t
    const int row0 = bm + wm;
    const int b = row0 >> 10;
    const int h = (bn + wn) >> 6;
    float* kb = KTb + ((size_t)(b * 16 + h) << 16);
    const int tb = (row0 & 1023) + q * 4;
#pragma unroll
    for (int mt = 0; mt < 4; ++mt) {
      const int t0 = tb + mt * 16;
#pragma unroll
      for (int nt = 0; nt < 4; ++nt) {
        const int j = nt * 16 + r16;
        *(float4*)(kb + (size_t)j * 1024 + t0) =
            make_float4(acc[mt][nt][0], acc[mt][nt][1], acc[mt][nt][2], acc[mt][nt][3]);
      }
    }
  } else {
#pragma unroll
    for (int mt = 0; mt < 4; ++mt)
#pragma unroll
      for (int nt = 0; nt < 4; ++nt)
#pragma unroll
        for (int r4 = 0; r4 < 4; ++r4)
          C[(size_t)(bm + wm + mt * 16 + q * 4 + r4) * 1024 + (bn + wn + nt * 16 + r16)] =
              acc[mt][nt][r4];
  }
}

// fused Q/K/V + sparsify + K-transpose: grid (24, 32)
__global__ __launch_bounds__(256, 3) void mfma_qkv(
    const ushort_t* __restrict__ xs, const ushort_t* __restrict__ wsb,
    float* __restrict__ qy, float* __restrict__ kt, float* __restrict__ vy)
{
  const int nb = blockIdx.x;
  const int which = nb >> 3;
  float* C = (which == 0) ? qy : vy;       // unused for K (mode 2)
  const int mode = (which == 1) ? 2 : 1;
  const ushort_t* Bh = wsb + (size_t)which * (2u << 20);
  mfma_gemm_core(xs, xs + (1u << 22), Bh, Bh + (1u << 20), C, kt,
                 blockIdx.y * 128, (nb & 7) * 128, mode);
}

__global__ __launch_bounds__(256, 3) void mfma_wo(
    const ushort_t* __restrict__ oys, const ushort_t* __restrict__ wsb,
    float* __restrict__ out)
{
  const ushort_t* Bh = wsb + (size_t)3 * (2u << 20);
  mfma_gemm_core(oys, oys + (1u << 22), Bh, Bh + (1u << 20), out, nullptr,
                 blockIdx.y * 128, blockIdx.x * 128, 0);
}

// ---------------- attention: wave-synchronous, one wave per q-row -----------
__device__ __forceinline__ unsigned mono_key(float f) {
  unsigned b = __float_as_uint(f);
  return (b & 0x80000000u) ? ~b : (b | 0x80000000u);
}

// Wave-local exact rank-select over index-ordered ps[0..cnt) (hi32 = mono
// score, lo32 = k). Selects hi32 > threshold plus first `rem` (array order)
// == threshold; writes packed (expf(s-m), k*1024) at obase into spk.
// Early exit when the boundary bin holds exactly `rem` keys.
__device__ __forceinline__ void wave_radix_sel(
    unsigned long long* ps, int cnt, int target,
    int* hr, unsigned long long* spk, int obase, bool neg, float m,
    int lane)
{
  unsigned pref = 0u; int rem = target; int sstop = 0;
  for (int pass = 0; pass < 4; ++pass) {
    const int shift = 24 - 8 * pass;
    sstop = shift;
    hr[lane] = 0; hr[lane + 64] = 0; hr[lane + 128] = 0; hr[lane + 192] = 0;
    for (int c0 = 0; c0 < cnt; c0 += 64) {
      const int t = c0 + lane;
      bool pt = (t < cnt);
      const unsigned u = pt ? (unsigned)(ps[t] >> 32) : 0u;
      if (pass > 0) pt = pt && ((u >> (shift + 8)) == (pref >> (shift + 8)));
      if (pt) atomicAdd(&hr[(u >> shift) & 255u], 1);
    }
    const int d0 = lane << 2;
    const int c0b = hr[d0], c1b = hr[d0 + 1], c2b = hr[d0 + 2], c3b = hr[d0 + 3];
    const int sum = c0b + c1b + c2b + c3b;
    int S = sum;
#pragma unroll
    for (int off = 1; off < 64; off <<= 1) {
      int t = __shfl_down(S, off);
      if (lane + off < 64) S += t;
    }
    const int above = S - sum;            // keys with digit in higher lanes
    const int cg3 = above;
    const int cg2 = above + c3b;
    const int cg1 = cg2 + c2b;
    const int cg0 = cg1 + c1b;
    const bool f0 = (cg0 < rem && rem <= cg0 + c0b);
    const bool f1 = (cg1 < rem && rem <= cg1 + c1b);
    const bool f2 = (cg2 < rem && rem <= cg2 + c2b);
    const bool f3 = (cg3 < rem && rem <= cg3 + c3b);
    const int fd  = f0 ? d0 : f1 ? (d0 + 1) : f2 ? (d0 + 2) : (d0 + 3);
    const int fcg = f0 ? cg0 : f1 ? cg1 : f2 ? cg2 : cg3;
    const int fcn = f0 ? c0b : f1 ? c1b : f2 ? c2b : c3b;
    unsigned long long fm = __ballot(f0 || f1 || f2 || f3);
    const int src = __ffsll(fm) - 1;
    const int nprefl = (int)(pref | ((unsigned)fd << shift));
    const int nreml = rem - fcg;
    const int done  = (fcn == nreml) ? 1 : 0;
    pref = (unsigned)__shfl(nprefl, src);
    rem  = __shfl(nreml, src);
    if (__shfl(done, src)) break;   // bin == rem: all members selected, exact
  }
  const unsigned phi = pref >> sstop;
  int eqbase = 0, wbase = 0;
  for (int c0 = 0; c0 < cnt; c0 += 64) {
    const int t = c0 + lane;
    const bool valt = (t < cnt);
    const unsigned long long kk = valt ? ps[t] : 0ull;
    const unsigned u = (unsigned)(kk >> 32);
    const unsigned upre = u >> sstop;
    const bool eq = valt && (upre == phi);
    unsigned long long em = __ballot(eq);
    const int eqrank = eqbase + lane_rank(em);
    const bool sf = valt && ((upre > phi) || (eq && eqrank < rem));
    unsigned long long sm = __ballot(sf);
    if (sf) {
      const int pos = wbase + lane_rank(sm);
      const float sv = neg ? __uint_as_float(~u) : __uint_as_float(u & 0x7fffffffu);
      spk[obase + pos] = ((unsigned long long)__float_as_uint(__expf(sv - m)) << 32)
                       | (unsigned)(((unsigned)kk) << 10);
    }
    eqbase += (int)__popcll(em);
    wbase  += (int)__popcll(sm);
  }
}

__global__ __launch_bounds__(256) void attn_sparse(
    const float* __restrict__ Qy, const float* __restrict__ KT,
    const float* __restrict__ Vy,
    ushort_t* __restrict__ Oh, ushort_t* __restrict__ Om)
{
  const int bh = blockIdx.y;
  const int b  = bh >> 4;
  const int h  = bh & 15;
  const int tid  = threadIdx.x;
  const int lane = tid & 63;
  const int w    = tid >> 6;
  const int bi   = blockIdx.x;
  // load-balanced row map: per-block total nvalid is constant (2050)
  const int q = (w == 0) ? bi : (w == 1) ? (511 - bi) : (w == 2) ? (512 + bi) : (1023 - bi);

  __shared__ unsigned long long pseg[4][256];
  __shared__ int   zseg[4][64];
  __shared__ unsigned long long selpk[4][64];   // packed (p:f32 hi | k*1024 lo)
  __shared__ int   hist[4][256];

  // q nonzeros: ffsll-peel the ballot mask, broadcast values via shfl
  const float qv = Qy[((size_t)(b * TSEQ + q)) * 1024 + h * HD + lane];
  unsigned long long mk = __ballot(qv != 0.0f);
  const int nnz = (int)__popcll(mk);
  unsigned long long mr = mk;
  int i0 = __ffsll(mr) - 1; if (i0 < 0) i0 = 0; mr &= mr - 1;
  int i1 = __ffsll(mr) - 1; if (i1 < 0) i1 = 0; mr &= mr - 1;
  int i2 = __ffsll(mr) - 1; if (i2 < 0) i2 = 0; mr &= mr - 1;
  int i3 = __ffsll(mr) - 1; if (i3 < 0) i3 = 0;
  float v0 = __shfl(qv, i0); if (nnz < 1) v0 = 0.0f;
  float v1 = __shfl(qv, i1); if (nnz < 2) v1 = 0.0f;
  float v2 = __shfl(qv, i2); if (nnz < 3) v2 = 0.0f;
  float v3 = __shfl(qv, i3); if (nnz < 4) v3 = 0.0f;
  const float* ktb = KT + (size_t)bh * HD * TSEQ;
  const float* kr0 = ktb + (size_t)i0 * TSEQ;
  const float* kr1 = ktb + (size_t)i1 * TSEQ;
  const float* kr2 = ktb + (size_t)i2 * TSEQ;
  const float* kr3 = ktb + (size_t)i3 * TSEQ;

  const int nvalid = q + 1;
  int nsel;

  if (nvalid <= 64) {
    const bool val = (lane < nvalid);
    float s = (v0 * kr0[lane] + v1 * kr1[lane] + v2 * kr2[lane] + v3 * kr3[lane]) * 0.125f;
    float mloc = val ? s : -INFINITY;
#pragma unroll
    for (int off = 32; off; off >>= 1) mloc = fmaxf(mloc, __shfl_xor(mloc, off));
    if (val)
      selpk[w][lane] = ((unsigned long long)__float_as_uint(__expf(s - mloc)) << 32)
                     | (unsigned)(lane << 10);
    nsel = nvalid;
  } else {
    int cp = 0, cz = 0;
    float mloc = -INFINITY;
#pragma unroll 2
    for (int k0 = 0; k0 < nvalid; k0 += 64) {
      const int k = k0 + lane;
      const bool val = (k < nvalid);
      // unguarded loads: worst-case 63 elements past row end stay inside d_ws
      float s = (v0 * kr0[k] + v1 * kr1[k] + v2 * kr2[k] + v3 * kr3[k]) * 0.125f;
      const bool isp = val && (s > 0.0f);
      mloc = val ? fmaxf(mloc, s) : mloc;
      unsigned long long mp = __ballot(isp);
      if (isp)
        pseg[w][cp + lane_rank(mp)] =
            ((unsigned long long)(__float_as_uint(s) | 0x80000000u) << 32) | (unsigned)k;
      cp += (int)__popcll(mp);
      if (cz < 64) {                      // wave-uniform gate; stops once 64 banked
        const bool isz = val && (s == 0.0f);
        unsigned long long mz = __ballot(isz);
        if (isz) { const int o = cz + lane_rank(mz); if (o < 64) zseg[w][o] = k; }
        cz += (int)__popcll(mz);
      }
    }
#pragma unroll
    for (int off = 32; off; off >>= 1) mloc = fmaxf(mloc, __shfl_xor(mloc, off));
    const float m = mloc;
    const bool czfull = (cz >= 64);

    if (cp <= 64 && (czfull || cp + cz >= 64)) {
      // fast path: boundary is exactly +0 (or smallest positive when cp==64)
      if (lane < cp) {
        const unsigned long long kk = pseg[w][lane];
        const float p = __expf(__uint_as_float((unsigned)(kk >> 32) & 0x7fffffffu) - m);
        selpk[w][lane] = ((unsigned long long)__float_as_uint(p) << 32)
                       | (unsigned)(((unsigned)kk) << 10);
      }
      const int quota = 64 - cp;
      if (lane < quota)
        selpk[w][cp + lane] = ((unsigned long long)__float_as_uint(__expf(-m)) << 32)
                            | (unsigned)(zseg[w][lane] << 10);
      nsel = 64;
    } else if (cp > 64) {
      wave_radix_sel(pseg[w], cp, 64, hist[w], selpk[w], 0, false, m, lane);
      nsel = 64;
    } else {
      // rare: boundary dips into negatives (cp + cz < 64; cz exact here)
      if (lane < cp) {
        const unsigned long long kk = pseg[w][lane];
        const float p = __expf(__uint_as_float((unsigned)(kk >> 32) & 0x7fffffffu) - m);
        selpk[w][lane] = ((unsigned long long)__float_as_uint(p) << 32)
                       | (unsigned)(((unsigned)kk) << 10);
      }
      if (lane < cz)
        selpk[w][cp + lane] = ((unsigned long long)__float_as_uint(__expf(-m)) << 32)
                            | (unsigned)(zseg[w][lane] << 10);
      int cn = 0;
      for (int k0 = 0; k0 < nvalid; k0 += 64) {
        const int k = k0 + lane;
        const bool val = (k < nvalid);
        float s = (v0 * kr0[k] + v1 * kr1[k] + v2 * kr2[k] + v3 * kr3[k]) * 0.125f;
        const bool isn = val && (s < 0.0f);
        unsigned long long mn = __ballot(isn);
        if (isn)
          pseg[w][cn + lane_rank(mn)] =
              ((unsigned long long)mono_key(s) << 32) | (unsigned)k;
        cn += (int)__popcll(mn);
      }
      wave_radix_sel(pseg[w], cn, 64 - cp - cz, hist[w], selpk[w],
                     cp + cz, true, m, lane);
      nsel = 64;
    }
  }

  const unsigned long long eL = (lane < nsel) ? selpk[w][lane] : 0ull;
  float Zp = (lane < nsel) ? __uint_as_float((unsigned)(eL >> 32)) : 0.0f;
#pragma unroll
  for (int off = 32; off; off >>= 1) Zp += __shfl_xor(Zp, off);
  const float Z = Zp;

  // epilogue: vbh is wave-uniform; selpk low 32 = element offset k*1024
  float acc = 0.0f;
  const float* vbh = Vy + ((size_t)b * TSEQ) * 1024 + h * HD;
  int s2 = 0;
  for (; s2 + 4 <= nsel; s2 += 4) {
    const ulonglong2 ea = *(const ulonglong2*)&selpk[w][s2];
    const ulonglong2 eb = *(const ulonglong2*)&selpk[w][s2 + 2];
    acc += __uint_as_float((unsigned)(ea.x >> 32)) * vbh[(unsigned)ea.x + lane]
         + __uint_as_float((unsigned)(ea.y >> 32)) * vbh[(unsigned)ea.y + lane]
         + __uint_as_float((unsigned)(eb.x >> 32)) * vbh[(unsigned)eb.x + lane]
         + __uint_as_float((unsigned)(eb.y >> 32)) * vbh[(unsigned)eb.y + lane];
  }
  for (; s2 < nsel; ++s2) {
    const unsigned long long e = selpk[w][s2];
    acc += __uint_as_float((unsigned)(e >> 32)) * vbh[(unsigned)e + lane];
  }
  const float r = acc / Z;
  unsigned short rh, rm;
  split2(r, rh, rm);
  const size_t oidx = ((size_t)(b * TSEQ + q)) * 1024 + h * HD + lane;
  Oh[oidx] = rh;
  Om[oidx] = rm;
}

// ---------------- launch -----------------------------------------------------
extern "C" void kernel_launch(void* const* d_in, const int* in_sizes, int n_in,
                              void* d_out, int out_size, void* d_ws, size_t ws_size,
                              hipStream_t stream) {
  (void)in_sizes; (void)n_in; (void)out_size; (void)ws_size;
  const float* x  = (const float*)d_in[0];
  const float* wq = (const float*)d_in[1];
  const float* wk = (const float*)d_in[2];
  const float* wv = (const float*)d_in[3];
  const float* wo = (const float*)d_in[4];
  float* out = (float*)d_out;

  float* ws = (float*)d_ws;
  const size_t SZ = (size_t)4096 * 1024;   // 4M floats = 16MB per buffer
  float* qy  = ws;
  float* vy  = ws + 2 * SZ;
  float* kt  = ws + 3 * SZ;
  ushort_t* xs  = (ushort_t*)(ws + 4 * SZ);   // 8M ushorts (x hi|mid)
  ushort_t* wsb = (ushort_t*)(ws + 5 * SZ);   // 8M ushorts (4 x (hi|mid))
  ushort_t* oys = xs;                         // xs dead after mfma_qkv

  conv_split<<<8192, 256, 0, stream>>>(x, wq, wk, wv, wo, xs, wsb);

  // QKV GEMM + in-register top-4 sparsify + direct transposed K write
  mfma_qkv<<<dim3(24, 32), 256, 0, stream>>>(xs, wsb, qy, kt, vy);

  attn_sparse<<<dim3(TSEQ / 4, 64), 256, 0, stream>>>(qy, kt, vy,
                                                      oys, oys + (1u << 22));

  mfma_wo<<<dim3(8, 32), 256, 0, stream>>>(oys, wsb, out);
}